// Round 1
// baseline (3518.885 us; speedup 1.0000x reference)
//
#include <hip/hip_runtime.h>
#include <cstdint>
#include <cstddef>

// ---------------------------------------------------------------------------
// GatedDeltaNet forward, MI355X/gfx950.
// Pipeline:
//  1. cast hs -> bf16
//  2. transpose W_qkv|W_z|W_b|W_a -> WT[12416][2048] bf16 ; W_out -> WoT[2048][4096]
//  3. GEMM1: C1[4096][12416] = hs @ [W_qkv|W_z|W_b|W_a]   (bf16 MFMA)
//  4. causal conv(K=4)+SiLU over C1[:, :8192] -> QKV bf16
//  5. beta/g from C1[:, 12288:12352]
//  6. chunked gated delta rule core (128 WGs: b x head x dv-half), state in LDS
//  7. gate (core * silu(z)) + RMS-norm -> NRM bf16
//  8. GEMM2: out = NRM @ W_out  (fp32 out)
// ---------------------------------------------------------------------------

#define ROWS  4096      // B*S
#define SEQ   2048
#define HIDN  2048
#define CONVD 8192
#define NWP   12416     // 8192 (qkv) + 4096 (z) + 32 (b) + 32 (a) + 64 pad
#define NUMV  32
#define DVH   64        // DV/2, per-workgroup value-half

using bf16x8 = __attribute__((ext_vector_type(8))) short;
using f32x4v = __attribute__((ext_vector_type(4))) float;

__device__ __forceinline__ float bf2f(unsigned short u) {
  union { unsigned int i; float f; } x; x.i = ((unsigned int)u) << 16; return x.f;
}
__device__ __forceinline__ unsigned short f2bf(float f) {
  union { float f; unsigned int u; } x; x.f = f;
  unsigned int u = x.u;
  unsigned int r = (u + 0x7FFFu + ((u >> 16) & 1u)) >> 16;  // RNE
  return (unsigned short)r;
}

// ---------------------------------------------------------------- cast fp32->bf16
__global__ __launch_bounds__(256) void cast_kernel(const float* __restrict__ in,
                                                   unsigned short* __restrict__ out, int n4) {
  int i = blockIdx.x * 256 + threadIdx.x;
  if (i >= n4) return;
  float4 v = ((const float4*)in)[i];
  ushort4 o;
  o.x = f2bf(v.x); o.y = f2bf(v.y); o.z = f2bf(v.z); o.w = f2bf(v.w);
  ((ushort4*)out)[i] = o;
}

// ------------------------------------------------- transpose W[K][N] -> WT[roff+N][K] bf16
__global__ __launch_bounds__(256) void transpose_kernel(const float* __restrict__ W,
                                                        unsigned short* __restrict__ WT,
                                                        int K, int N, int ld, int roff) {
  __shared__ float tile[64][65];
  const int t = threadIdx.x;
  const int kb = blockIdx.y * 64, nb = blockIdx.x * 64;
  const int r = t >> 2, c0 = (t & 3) * 16;
#pragma unroll
  for (int i = 0; i < 16; ++i) {
    int c = c0 + i;
    float v = 0.f;
    if (nb + c < N) v = W[(size_t)(kb + r) * N + nb + c];  // K is a multiple of 64
    tile[r][c] = v;
  }
  __syncthreads();
  const int bn = t >> 2;
  if (nb + bn < N) {
#pragma unroll
    for (int i = 0; i < 16; ++i)
      WT[(size_t)(roff + nb + bn) * ld + kb + c0 + i] = f2bf(tile[c0 + i][bn]);
  }
}

// ---------------------------------------------------------------- bf16 MFMA GEMM (B^T input)
// C[M][N] = A[M][K] @ B^T ; Bg is [N][K]. 128x128 tile, 4 waves (2x2), 4x4 frags of 16x16x32.
template <int OUT_BF16>
__global__ __launch_bounds__(256) void gemm_bt_kernel(const unsigned short* __restrict__ Ag,
                                                      const unsigned short* __restrict__ Bg,
                                                      void* __restrict__ Cg, int M, int N, int K) {
  __shared__ unsigned short As[128 * 32];
  __shared__ unsigned short Bs[128 * 32];
  const int t = threadIdx.x;
  const int lane = t & 63, w = t >> 6;
  const int wm = w >> 1, wn = w & 1;
  const int m0 = blockIdx.y * 128, n0 = blockIdx.x * 128;

  f32x4v acc[4][4];
#pragma unroll
  for (int i = 0; i < 4; ++i)
#pragma unroll
    for (int j = 0; j < 4; ++j) acc[i][j] = (f32x4v){0.f, 0.f, 0.f, 0.f};

  // staging: thread t owns LDS bytes [16t,16t+16) of each 8KB tile-half (linear, conflict-free)
  const int sr = t >> 2;            // row within 64-row half
  const int sk = (t & 3) * 8;       // k element offset
  const unsigned short* ap0 = Ag + (size_t)(m0 + sr) * K + sk;
  const unsigned short* ap1 = Ag + (size_t)(m0 + 64 + sr) * K + sk;
  const unsigned short* bp0 = Bg + (size_t)(n0 + sr) * K + sk;
  const unsigned short* bp1 = Bg + (size_t)(n0 + 64 + sr) * K + sk;
  uint4* asd0 = (uint4*)&As[sr * 32 + sk];
  uint4* asd1 = (uint4*)&As[(64 + sr) * 32 + sk];
  uint4* bsd0 = (uint4*)&Bs[sr * 32 + sk];
  uint4* bsd1 = (uint4*)&Bs[(64 + sr) * 32 + sk];

  uint4 a0 = *(const uint4*)(ap0);
  uint4 a1 = *(const uint4*)(ap1);
  uint4 b0 = *(const uint4*)(bp0);
  uint4 b1 = *(const uint4*)(bp1);

  const int rlo = lane & 15;
  const int kh8 = (lane >> 4) * 8;

  for (int k0 = 0; k0 < K; k0 += 32) {
    __syncthreads();
    *asd0 = a0; *asd1 = a1; *bsd0 = b0; *bsd1 = b1;
    __syncthreads();
    if (k0 + 32 < K) {  // prefetch next tile (issue early, consumed next iter)
      a0 = *(const uint4*)(ap0 + k0 + 32);
      a1 = *(const uint4*)(ap1 + k0 + 32);
      b0 = *(const uint4*)(bp0 + k0 + 32);
      b1 = *(const uint4*)(bp1 + k0 + 32);
    }
    bf16x8 af[4], bfv[4];
#pragma unroll
    for (int i = 0; i < 4; ++i) af[i] = *(const bf16x8*)&As[(wm * 64 + i * 16 + rlo) * 32 + kh8];
#pragma unroll
    for (int j = 0; j < 4; ++j) bfv[j] = *(const bf16x8*)&Bs[(wn * 64 + j * 16 + rlo) * 32 + kh8];
#pragma unroll
    for (int i = 0; i < 4; ++i)
#pragma unroll
      for (int j = 0; j < 4; ++j)
        acc[i][j] = __builtin_amdgcn_mfma_f32_16x16x32_bf16(af[i], bfv[j], acc[i][j], 0, 0, 0);
  }

  // epilogue: C/D layout col=lane&15 (N), row=4*(lane>>4)+reg (M)   [m89-verified]
  const int mrb = (lane >> 4) * 4;
  const int ncc = lane & 15;
#pragma unroll
  for (int i = 0; i < 4; ++i)
#pragma unroll
    for (int j = 0; j < 4; ++j)
#pragma unroll
      for (int r = 0; r < 4; ++r) {
        int mm = m0 + wm * 64 + i * 16 + mrb + r;
        int nn = n0 + wn * 64 + j * 16 + ncc;
        float v = acc[i][j][r];
        if (OUT_BF16) ((unsigned short*)Cg)[(size_t)mm * N + nn] = f2bf(v);
        else          ((float*)Cg)[(size_t)mm * N + nn] = v;
      }
}

// ---------------------------------------------------------------- causal conv K=4 + SiLU
__global__ __launch_bounds__(256) void conv_silu_kernel(const unsigned short* __restrict__ C1,
                                                        const float* __restrict__ conv_w,
                                                        unsigned short* __restrict__ QKV) {
  int idx = blockIdx.x * 256 + threadIdx.x;       // ROWS * CONVD/4
  int row = idx >> 11;
  int c4 = (idx & 2047) << 2;
  int s = row & 2047;
  float4 w0 = *(const float4*)(conv_w + (size_t)(c4 + 0) * 4);
  float4 w1 = *(const float4*)(conv_w + (size_t)(c4 + 1) * 4);
  float4 w2 = *(const float4*)(conv_w + (size_t)(c4 + 2) * 4);
  float4 w3 = *(const float4*)(conv_w + (size_t)(c4 + 3) * 4);
  const float* pw0 = (const float*)&w0;
  const float* pw1 = (const float*)&w1;
  const float* pw2 = (const float*)&w2;
  const float* pw3 = (const float*)&w3;
  float a0 = 0.f, a1 = 0.f, a2 = 0.f, a3 = 0.f;
#pragma unroll
  for (int j = 0; j < 4; ++j) {
    int sr = s - 3 + j;
    if (sr < 0) continue;
    ushort4 mv = *(const ushort4*)(C1 + (size_t)(row - 3 + j) * NWP + c4);
    a0 += bf2f(mv.x) * pw0[j];
    a1 += bf2f(mv.y) * pw1[j];
    a2 += bf2f(mv.z) * pw2[j];
    a3 += bf2f(mv.w) * pw3[j];
  }
  ushort4 o;
  o.x = f2bf(a0 / (1.f + __expf(-a0)));
  o.y = f2bf(a1 / (1.f + __expf(-a1)));
  o.z = f2bf(a2 / (1.f + __expf(-a2)));
  o.w = f2bf(a3 / (1.f + __expf(-a3)));
  *(ushort4*)(QKV + (size_t)row * CONVD + c4) = o;
}

// ---------------------------------------------------------------- beta / g
__global__ __launch_bounds__(256) void gbeta_kernel(const unsigned short* __restrict__ C1,
                                                    const float* __restrict__ dt_bias,
                                                    const float* __restrict__ A_log,
                                                    float* __restrict__ G, float* __restrict__ BETA) {
  int idx = blockIdx.x * 256 + threadIdx.x;   // ROWS*32
  int row = idx >> 5, h = idx & 31;
  float bp = bf2f(C1[(size_t)row * NWP + 12288 + h]);
  float ap = bf2f(C1[(size_t)row * NWP + 12320 + h]);
  BETA[idx] = 1.f / (1.f + __expf(-bp));
  float x = ap + dt_bias[h];
  float sp = (x > 15.f) ? x : log1pf(__expf(x));
  G[idx] = -__expf(A_log[h]) * sp;
}

// ---------------------------------------------------------------- chunked gated delta rule core
// grid: 128 = b(2) x head(32) x vhalf(2). 256 threads. Dynamic LDS 153344 B.
#define CORE_SMEM_BYTES 153344
__global__ __launch_bounds__(256) void core_kernel(const unsigned short* __restrict__ QKV,
                                                   const float* __restrict__ G,
                                                   const float* __restrict__ BETA,
                                                   unsigned short* __restrict__ CORE) {
  extern __shared__ char smem[];
  float* state = (float*)smem;                        // [128][68]
  float* ktf   = state + 128 * 68;                    // [64][132] l2-normed k
  float* XK    = ktf + 64 * 132;                      // [64][132] kcd rhs -> kcd
  float* Amat  = XK + 64 * 132;                       // [64][64]  A, later attn
  float* XV    = Amat + 64 * 64;                      // [64][64]  v_beta -> v_c -> v_new
  unsigned short* qt = (unsigned short*)(XV + 64 * 64);  // [64][128] bf16 q (normed*dk^-.5)
  float* gc   = (float*)(qt + 64 * 128);              // [64] cumsum g
  float* bet  = gc + 64;                              // [64]
  float* edec = bet + 64;                             // [64] exp(g_last - gc[i])
  float* red  = edec + 64;                            // [256] scratch

  const int t = threadIdx.x;
  const int b  = blockIdx.x >> 6;
  const int h  = (blockIdx.x >> 1) & 31;
  const int vh = blockIdx.x & 1;
  const int hq = h >> 1;                              // GQA: repeat=2
  const size_t rowbase = (size_t)b * SEQ;

  for (int i = t; i < 128 * 68; i += 256) state[i] = 0.f;
  __syncthreads();

#pragma unroll 1
  for (int ncb = 0; ncb < 32; ++ncb) {
    const int row0 = ncb * 64;
    if (t < 64) {
      gc[t]  = G[(rowbase + row0 + t) * NUMV + h];
      bet[t] = BETA[(rowbase + row0 + t) * NUMV + h];
    }
    __syncthreads();
    if (t == 0) {
      float cacc = 0.f;
      for (int r = 0; r < 64; ++r) { cacc += gc[r]; gc[r] = cacc; }
    }
    __syncthreads();
    if (t < 64) edec[t] = __expf(gc[63] - gc[t]);

    // ---- load q,k (l2norm) and v; fill XK (k_beta*exp(gc)) and XV (v_beta) ----
    {
      const int r = t >> 2, q4 = t & 3;
      const size_t grow = (rowbase + row0 + r) * (size_t)CONVD;
      const unsigned short* kp = QKV + grow + 2048 + hq * 128 + q4 * 32;
      const unsigned short* qp = QKV + grow + hq * 128 + q4 * 32;
      float kv[32], qv[32];
      float ssk = 0.f, ssq = 0.f;
#pragma unroll
      for (int j = 0; j < 32; j += 4) {
        ushort4 km = *(const ushort4*)(kp + j);
        ushort4 qm = *(const ushort4*)(qp + j);
        kv[j] = bf2f(km.x); kv[j + 1] = bf2f(km.y); kv[j + 2] = bf2f(km.z); kv[j + 3] = bf2f(km.w);
        qv[j] = bf2f(qm.x); qv[j + 1] = bf2f(qm.y); qv[j + 2] = bf2f(qm.z); qv[j + 3] = bf2f(qm.w);
        ssk += kv[j]*kv[j] + kv[j+1]*kv[j+1] + kv[j+2]*kv[j+2] + kv[j+3]*kv[j+3];
        ssq += qv[j]*qv[j] + qv[j+1]*qv[j+1] + qv[j+2]*qv[j+2] + qv[j+3]*qv[j+3];
      }
      red[t] = ssk;
      __syncthreads();
      float sk = red[r * 4 + 0] + red[r * 4 + 1] + red[r * 4 + 2] + red[r * 4 + 3];
      __syncthreads();
      red[t] = ssq;
      __syncthreads();
      float sq = red[r * 4 + 0] + red[r * 4 + 1] + red[r * 4 + 2] + red[r * 4 + 3];
      const float rk = rsqrtf(sk + 1e-6f);
      const float rq = rsqrtf(sq + 1e-6f) * 0.08838834764831845f;  // * DK^-0.5
      const float brow = bet[r];
      const float ekr = __expf(gc[r]) * brow;
#pragma unroll
      for (int j = 0; j < 32; ++j) {
        float kn = kv[j] * rk;
        ktf[r * 132 + q4 * 32 + j] = kn;
        XK[r * 132 + q4 * 32 + j] = kn * ekr;
        qt[r * 128 + q4 * 32 + j] = f2bf(qv[j] * rq);
      }
      const unsigned short* vp = QKV + grow + 4096 + h * 128 + vh * 64 + q4 * 16;
#pragma unroll
      for (int j = 0; j < 16; j += 4) {
        ushort4 vm = *(const ushort4*)(vp + j);
        XV[r * 64 + q4 * 16 + j]     = bf2f(vm.x) * brow;
        XV[r * 64 + q4 * 16 + j + 1] = bf2f(vm.y) * brow;
        XV[r * 64 + q4 * 16 + j + 2] = bf2f(vm.z) * brow;
        XV[r * 64 + q4 * 16 + j + 3] = bf2f(vm.w) * brow;
      }
    }
    __syncthreads();

    // ---- A = -(k_beta @ k^T) * exp(gc_i - gc_j) strictly-lower ----
    {
      const int bi = t >> 4, bj = t & 15;
#pragma unroll
      for (int ii = 0; ii < 4; ++ii) {
        const int i = bi * 4 + ii;
        const float nbi = -bet[i];
#pragma unroll
        for (int jj = 0; jj < 4; ++jj) {
          const int j = bj * 4 + jj;
          float val = 0.f;
          if (j < i) {
            const float* ki = ktf + i * 132;
            const float* kj = ktf + j * 132;
            float s0 = 0, s1 = 0, s2 = 0, s3 = 0;
#pragma unroll 8
            for (int d = 0; d < 128; d += 4) {
              f32x4v x = *(const f32x4v*)(ki + d);
              f32x4v y = *(const f32x4v*)(kj + d);
              s0 += x[0] * y[0]; s1 += x[1] * y[1]; s2 += x[2] * y[2]; s3 += x[3] * y[3];
            }
            val = nbi * __expf(gc[i] - gc[j]) * (s0 + s1 + s2 + s3);
          }
          Amat[i * 64 + j] = val;
        }
      }
    }
    __syncthreads();

    // ---- forward substitution (I - A) X = rhs, in place; 192 cols (128 kcd | 64 v) ----
#pragma unroll 1
    for (int ib = 0; ib < 8; ++ib) {
      const int i0 = ib * 8;
      if (t < 192) {
        float* Xc; int st;
        if (t < 128) { Xc = XK + t; st = 132; }
        else         { Xc = XV + (t - 128); st = 64; }
        float p[8] = {0, 0, 0, 0, 0, 0, 0, 0};
        for (int j = 0; j < i0; ++j) {
          float xj = Xc[(size_t)j * st];
#pragma unroll
          for (int r2 = 0; r2 < 8; ++r2) p[r2] += Amat[(i0 + r2) * 64 + j] * xj;
        }
        float xi[8];
#pragma unroll
        for (int r2 = 0; r2 < 8; ++r2) {
          float v = Xc[(size_t)(i0 + r2) * st] + p[r2];
#pragma unroll
          for (int r3 = 0; r3 < r2; ++r3) v += Amat[(i0 + r2) * 64 + i0 + r3] * xi[r3];
          xi[r2] = v;
          Xc[(size_t)(i0 + r2) * st] = v;
        }
      }
      __syncthreads();
    }

    // ---- v_new = v_c - kcd @ state (own 4x4 block, in place) ; attn into Amat ----
    {
      const int bi = t >> 4, bj = t & 15;
      float vn[4][4];
#pragma unroll
      for (int ii = 0; ii < 4; ++ii)
#pragma unroll
        for (int cc = 0; cc < 4; ++cc) vn[ii][cc] = XV[(bi * 4 + ii) * 64 + bj * 4 + cc];
#pragma unroll 4
      for (int d = 0; d < 128; ++d) {
        f32x4v sv = *(const f32x4v*)(state + d * 68 + bj * 4);
#pragma unroll
        for (int ii = 0; ii < 4; ++ii) {
          float kc = XK[(bi * 4 + ii) * 132 + d];
          vn[ii][0] -= kc * sv[0]; vn[ii][1] -= kc * sv[1];
          vn[ii][2] -= kc * sv[2]; vn[ii][3] -= kc * sv[3];
        }
      }
#pragma unroll
      for (int ii = 0; ii < 4; ++ii)
#pragma unroll
        for (int cc = 0; cc < 4; ++cc) XV[(bi * 4 + ii) * 64 + bj * 4 + cc] = vn[ii][cc];

      // attn = (q @ k^T) * exp(gc_i - gc_j), j<=i  (overwrites Amat; solve is done)
#pragma unroll
      for (int ii = 0; ii < 4; ++ii) {
        const int i = bi * 4 + ii;
        const unsigned short* qi = qt + i * 128;
#pragma unroll
        for (int jj = 0; jj < 4; ++jj) {
          const int j = bj * 4 + jj;
          float val = 0.f;
          if (j <= i) {
            const float* kj = ktf + j * 132;
            float s0 = 0, s1 = 0, s2 = 0, s3 = 0;
#pragma unroll 8
            for (int d = 0; d < 128; d += 4) {
              ushort4 qm = *(const ushort4*)(qi + d);
              f32x4v y = *(const f32x4v*)(kj + d);
              s0 += bf2f(qm.x) * y[0]; s1 += bf2f(qm.y) * y[1];
              s2 += bf2f(qm.z) * y[2]; s3 += bf2f(qm.w) * y[3];
            }
            val = __expf(gc[i] - gc[j]) * (s0 + s1 + s2 + s3);
          }
          Amat[i * 64 + j] = val;
        }
      }
    }
    __syncthreads();

    // ---- out = (q*exp(gc)) @ state + attn @ v_new -> CORE ----
    {
      const int bi = t >> 4, bj = t & 15;
      float o[4][4];
#pragma unroll
      for (int ii = 0; ii < 4; ++ii)
#pragma unroll
        for (int cc = 0; cc < 4; ++cc) o[ii][cc] = 0.f;
#pragma unroll 4
      for (int j = 0; j < 64; ++j) {
        f32x4v vv = *(const f32x4v*)(XV + j * 64 + bj * 4);
#pragma unroll
        for (int ii = 0; ii < 4; ++ii) {
          float aij = Amat[(bi * 4 + ii) * 64 + j];
          o[ii][0] += aij * vv[0]; o[ii][1] += aij * vv[1];
          o[ii][2] += aij * vv[2]; o[ii][3] += aij * vv[3];
        }
      }
      float eg[4];
#pragma unroll
      for (int ii = 0; ii < 4; ++ii) eg[ii] = __expf(gc[bi * 4 + ii]);
#pragma unroll 4
      for (int d = 0; d < 128; ++d) {
        f32x4v sv = *(const f32x4v*)(state + d * 68 + bj * 4);
#pragma unroll
        for (int ii = 0; ii < 4; ++ii) {
          float qd = bf2f(qt[(bi * 4 + ii) * 128 + d]) * eg[ii];
          o[ii][0] += qd * sv[0]; o[ii][1] += qd * sv[1];
          o[ii][2] += qd * sv[2]; o[ii][3] += qd * sv[3];
        }
      }
#pragma unroll
      for (int ii = 0; ii < 4; ++ii) {
        const size_t orow = (rowbase + row0 + bi * 4 + ii) * (size_t)4096 + h * 128 + vh * 64 + bj * 4;
        ushort4 ov;
        ov.x = f2bf(o[ii][0]); ov.y = f2bf(o[ii][1]);
        ov.z = f2bf(o[ii][2]); ov.w = f2bf(o[ii][3]);
        *(ushort4*)(CORE + orow) = ov;
      }
    }
    __syncthreads();

    // ---- state = state*exp(g_last) + k_dec^T @ v_new ----
    {
      const int d = t >> 1, ch = (t & 1) * 32;
      float acc[32];
#pragma unroll
      for (int c = 0; c < 32; ++c) acc[c] = 0.f;
#pragma unroll 2
      for (int i = 0; i < 64; ++i) {
        float kd = ktf[i * 132 + d] * edec[i];
        const float* xv = XV + i * 64 + ch;
#pragma unroll
        for (int c = 0; c < 32; c += 4) {
          f32x4v vv = *(const f32x4v*)(xv + c);
          acc[c] += kd * vv[0]; acc[c + 1] += kd * vv[1];
          acc[c + 2] += kd * vv[2]; acc[c + 3] += kd * vv[3];
        }
      }
      const float egl = __expf(gc[63]);
      float* srow = state + d * 68 + ch;
#pragma unroll
      for (int c = 0; c < 32; ++c) srow[c] = srow[c] * egl + acc[c];
    }
    __syncthreads();
  }
}

// ---------------------------------------------------------------- gate * silu(z) + RMS-norm
__global__ __launch_bounds__(256) void gatenorm_kernel(const unsigned short* __restrict__ CORE,
                                                       const unsigned short* __restrict__ C1,
                                                       const float* __restrict__ norm_w,
                                                       unsigned short* __restrict__ NRM) {
  const int wid = blockIdx.x * 4 + (threadIdx.x >> 6);
  const int lane = threadIdx.x & 63;
  const int row = wid >> 5, h = wid & 31;
  const int c = lane * 2;
  const size_t cidx = (size_t)row * 4096 + h * 128 + c;
  const size_t zidx = (size_t)row * NWP + 8192 + h * 128 + c;
  float g0 = bf2f(CORE[cidx]), g1 = bf2f(CORE[cidx + 1]);
  float z0 = bf2f(C1[zidx]), z1 = bf2f(C1[zidx + 1]);
  g0 *= z0 / (1.f + __expf(-z0));
  g1 *= z1 / (1.f + __expf(-z1));
  float ss = g0 * g0 + g1 * g1;
#pragma unroll
  for (int m = 1; m < 64; m <<= 1) ss += __shfl_xor(ss, m, 64);
  const float rr = rsqrtf(ss * (1.f / 128.f) + 1e-6f);
  unsigned int o = ((unsigned int)f2bf(g1 * rr * norm_w[c + 1]) << 16) | (unsigned int)f2bf(g0 * rr * norm_w[c]);
  *(unsigned int*)(NRM + cidx) = o;
}

// ---------------------------------------------------------------------------
extern "C" void kernel_launch(void* const* d_in, const int* in_sizes, int n_in,
                              void* d_out, int out_size, void* d_ws, size_t ws_size,
                              hipStream_t stream) {
  const float* hs      = (const float*)d_in[0];
  const float* W_qkv   = (const float*)d_in[1];
  const float* W_z     = (const float*)d_in[2];
  const float* W_b     = (const float*)d_in[3];
  const float* W_a     = (const float*)d_in[4];
  const float* conv_w  = (const float*)d_in[5];
  const float* dt_bias = (const float*)d_in[6];
  const float* A_log   = (const float*)d_in[7];
  const float* norm_w  = (const float*)d_in[8];
  const float* W_out   = (const float*)d_in[9];
  float* out = (float*)d_out;
  char* ws = (char*)d_ws;

  const size_t OFF_HSB = 0;                                     // bf16 hs        16.8 MB
  const size_t OFF_WT  = OFF_HSB + (size_t)ROWS * HIDN * 2;     // WT[12416][2048] 50.9 MB
  const size_t OFF_WOT = OFF_WT + (size_t)NWP * HIDN * 2;       // WoT[2048][4096] 16.8 MB
  const size_t OFF_C1  = OFF_WOT + (size_t)HIDN * 4096 * 2;     // C1[4096][12416] 101.7 MB
  const size_t OFF_QKV = OFF_C1 + (size_t)ROWS * NWP * 2;       // QKV bf16        67.1 MB
  const size_t OFF_G   = OFF_QKV + (size_t)ROWS * CONVD * 2;    // g fp32
  const size_t OFF_B   = OFF_G + (size_t)ROWS * NUMV * 4;       // beta fp32
  const size_t OFF_CORE = OFF_WT;    // alias: WT dead after GEMM1
  const size_t OFF_NRM  = OFF_QKV;   // alias: QKV dead after core

  unsigned short* hsb = (unsigned short*)(ws + OFF_HSB);
  unsigned short* WT  = (unsigned short*)(ws + OFF_WT);
  unsigned short* WoT = (unsigned short*)(ws + OFF_WOT);
  unsigned short* C1  = (unsigned short*)(ws + OFF_C1);
  unsigned short* QKV = (unsigned short*)(ws + OFF_QKV);
  float* Gb = (float*)(ws + OFF_G);
  float* Bb = (float*)(ws + OFF_B);
  unsigned short* COREb = (unsigned short*)(ws + OFF_CORE);
  unsigned short* NRMb  = (unsigned short*)(ws + OFF_NRM);

  cast_kernel<<<ROWS * HIDN / 4 / 256, 256, 0, stream>>>(hs, hsb, ROWS * HIDN / 4);
  transpose_kernel<<<dim3(8192 / 64, 2048 / 64), 256, 0, stream>>>(W_qkv, WT, 2048, 8192, HIDN, 0);
  transpose_kernel<<<dim3(4096 / 64, 2048 / 64), 256, 0, stream>>>(W_z, WT, 2048, 4096, HIDN, 8192);
  transpose_kernel<<<dim3(1, 2048 / 64), 256, 0, stream>>>(W_b, WT, 2048, 32, HIDN, 12288);
  transpose_kernel<<<dim3(1, 2048 / 64), 256, 0, stream>>>(W_a, WT, 2048, 32, HIDN, 12320);
  hipMemsetAsync(ws + OFF_WT + (size_t)12352 * HIDN * 2, 0, (size_t)64 * HIDN * 2, stream);
  transpose_kernel<<<dim3(2048 / 64, 4096 / 64), 256, 0, stream>>>(W_out, WoT, 4096, 2048, 4096, 0);

  gemm_bt_kernel<1><<<dim3(NWP / 128, ROWS / 128), 256, 0, stream>>>(hsb, WT, C1, ROWS, NWP, HIDN);
  conv_silu_kernel<<<ROWS * (CONVD / 4) / 256, 256, 0, stream>>>(C1, conv_w, QKV);
  gbeta_kernel<<<ROWS * NUMV / 256, 256, 0, stream>>>(C1, dt_bias, A_log, Gb, Bb);

  hipFuncSetAttribute((const void*)core_kernel, hipFuncAttributeMaxDynamicSharedMemorySize,
                      CORE_SMEM_BYTES);
  core_kernel<<<128, 256, CORE_SMEM_BYTES, stream>>>(QKV, Gb, Bb, COREb);

  gatenorm_kernel<<<ROWS * NUMV / 4, 256, 0, stream>>>(COREb, C1, norm_w, NRMb);
  gemm_bt_kernel<0><<<dim3(2048 / 128, ROWS / 128), 256, 0, stream>>>(NRMb, WoT, out, ROWS, 2048, 4096);
}

// Round 2
// 1637.509 us; speedup vs baseline: 2.1489x; 2.1489x over previous
//
#include <hip/hip_runtime.h>
#include <cstdint>
#include <cstddef>

// ---------------------------------------------------------------------------
// GatedDeltaNet forward, MI355X/gfx950.
//  1. cast hs -> bf16
//  2. transpose weights -> bf16 [N][K]
//  3. GEMM1: C1[4096][12416] = hs @ [W_qkv|W_z|W_b|W_a]   (bf16 MFMA)
//  4. causal conv(K=4)+SiLU -> QKV bf16
//  5. beta/g
//  6. MFMA chunked gated delta rule core (256 WGs: b x head x dv-quarter)
//  7. gate + RMS-norm -> NRM bf16
//  8. GEMM2: out = NRM @ W_out  (fp32 out)
// ---------------------------------------------------------------------------

#define ROWS  4096      // B*S
#define SEQ   2048
#define HIDN  2048
#define CONVD 8192
#define NWP   12416     // 8192 qkv + 4096 z + 32 b + 32 a + 64 pad
#define NUMV  32

using bf16x8 = __attribute__((ext_vector_type(8))) short;
using f32x4v = __attribute__((ext_vector_type(4))) float;

__device__ __forceinline__ float bf2f(unsigned short u) {
  union { unsigned int i; float f; } x; x.i = ((unsigned int)u) << 16; return x.f;
}
__device__ __forceinline__ unsigned short f2bf(float f) {
  union { float f; unsigned int u; } x; x.f = f;
  unsigned int u = x.u;
  unsigned int r = (u + 0x7FFFu + ((u >> 16) & 1u)) >> 16;  // RNE
  return (unsigned short)r;
}

// ---------------------------------------------------------------- cast fp32->bf16
__global__ __launch_bounds__(256) void cast_kernel(const float* __restrict__ in,
                                                   unsigned short* __restrict__ out, int n4) {
  int i = blockIdx.x * 256 + threadIdx.x;
  if (i >= n4) return;
  float4 v = ((const float4*)in)[i];
  ushort4 o;
  o.x = f2bf(v.x); o.y = f2bf(v.y); o.z = f2bf(v.z); o.w = f2bf(v.w);
  ((ushort4*)out)[i] = o;
}

// ------------------------------------------------- transpose W[K][N] -> WT[roff+N][K] bf16
__global__ __launch_bounds__(256) void transpose_kernel(const float* __restrict__ W,
                                                        unsigned short* __restrict__ WT,
                                                        int K, int N, int ld, int roff) {
  __shared__ float tile[64][65];
  const int t = threadIdx.x;
  const int kb = blockIdx.y * 64, nb = blockIdx.x * 64;
  const int r = t >> 2, c0 = (t & 3) * 16;
#pragma unroll
  for (int i = 0; i < 16; ++i) {
    int c = c0 + i;
    float v = 0.f;
    if (nb + c < N) v = W[(size_t)(kb + r) * N + nb + c];
    tile[r][c] = v;
  }
  __syncthreads();
  const int bn = t >> 2;
  if (nb + bn < N) {
#pragma unroll
    for (int i = 0; i < 16; ++i)
      WT[(size_t)(roff + nb + bn) * ld + kb + c0 + i] = f2bf(tile[c0 + i][bn]);
  }
}

// ---------------------------------------------------------------- bf16 MFMA GEMM (B^T input)
template <int OUT_BF16>
__global__ __launch_bounds__(256) void gemm_bt_kernel(const unsigned short* __restrict__ Ag,
                                                      const unsigned short* __restrict__ Bg,
                                                      void* __restrict__ Cg, int M, int N, int K) {
  __shared__ unsigned short As[128 * 32];
  __shared__ unsigned short Bs[128 * 32];
  const int t = threadIdx.x;
  const int lane = t & 63, w = t >> 6;
  const int wm = w >> 1, wn = w & 1;
  const int m0 = blockIdx.y * 128, n0 = blockIdx.x * 128;

  f32x4v acc[4][4];
#pragma unroll
  for (int i = 0; i < 4; ++i)
#pragma unroll
    for (int j = 0; j < 4; ++j) acc[i][j] = (f32x4v){0.f, 0.f, 0.f, 0.f};

  const int sr = t >> 2;
  const int sk = (t & 3) * 8;
  const unsigned short* ap0 = Ag + (size_t)(m0 + sr) * K + sk;
  const unsigned short* ap1 = Ag + (size_t)(m0 + 64 + sr) * K + sk;
  const unsigned short* bp0 = Bg + (size_t)(n0 + sr) * K + sk;
  const unsigned short* bp1 = Bg + (size_t)(n0 + 64 + sr) * K + sk;
  uint4* asd0 = (uint4*)&As[sr * 32 + sk];
  uint4* asd1 = (uint4*)&As[(64 + sr) * 32 + sk];
  uint4* bsd0 = (uint4*)&Bs[sr * 32 + sk];
  uint4* bsd1 = (uint4*)&Bs[(64 + sr) * 32 + sk];

  uint4 a0 = *(const uint4*)(ap0);
  uint4 a1 = *(const uint4*)(ap1);
  uint4 b0 = *(const uint4*)(bp0);
  uint4 b1 = *(const uint4*)(bp1);

  const int rlo = lane & 15;
  const int kh8 = (lane >> 4) * 8;

  for (int k0 = 0; k0 < K; k0 += 32) {
    __syncthreads();
    *asd0 = a0; *asd1 = a1; *bsd0 = b0; *bsd1 = b1;
    __syncthreads();
    if (k0 + 32 < K) {
      a0 = *(const uint4*)(ap0 + k0 + 32);
      a1 = *(const uint4*)(ap1 + k0 + 32);
      b0 = *(const uint4*)(bp0 + k0 + 32);
      b1 = *(const uint4*)(bp1 + k0 + 32);
    }
    bf16x8 af[4], bfv[4];
#pragma unroll
    for (int i = 0; i < 4; ++i) af[i] = *(const bf16x8*)&As[(wm * 64 + i * 16 + rlo) * 32 + kh8];
#pragma unroll
    for (int j = 0; j < 4; ++j) bfv[j] = *(const bf16x8*)&Bs[(wn * 64 + j * 16 + rlo) * 32 + kh8];
#pragma unroll
    for (int i = 0; i < 4; ++i)
#pragma unroll
      for (int j = 0; j < 4; ++j)
        acc[i][j] = __builtin_amdgcn_mfma_f32_16x16x32_bf16(af[i], bfv[j], acc[i][j], 0, 0, 0);
  }

  const int mrb = (lane >> 4) * 4;
  const int ncc = lane & 15;
#pragma unroll
  for (int i = 0; i < 4; ++i)
#pragma unroll
    for (int j = 0; j < 4; ++j)
#pragma unroll
      for (int r = 0; r < 4; ++r) {
        int mm = m0 + wm * 64 + i * 16 + mrb + r;
        int nn = n0 + wn * 64 + j * 16 + ncc;
        float v = acc[i][j][r];
        if (OUT_BF16) ((unsigned short*)Cg)[(size_t)mm * N + nn] = f2bf(v);
        else          ((float*)Cg)[(size_t)mm * N + nn] = v;
      }
}

// ---------------------------------------------------------------- causal conv K=4 + SiLU
__global__ __launch_bounds__(256) void conv_silu_kernel(const unsigned short* __restrict__ C1,
                                                        const float* __restrict__ conv_w,
                                                        unsigned short* __restrict__ QKV) {
  int idx = blockIdx.x * 256 + threadIdx.x;
  int row = idx >> 11;
  int c4 = (idx & 2047) << 2;
  int s = row & 2047;
  float4 w0 = *(const float4*)(conv_w + (size_t)(c4 + 0) * 4);
  float4 w1 = *(const float4*)(conv_w + (size_t)(c4 + 1) * 4);
  float4 w2 = *(const float4*)(conv_w + (size_t)(c4 + 2) * 4);
  float4 w3 = *(const float4*)(conv_w + (size_t)(c4 + 3) * 4);
  const float* pw0 = (const float*)&w0;
  const float* pw1 = (const float*)&w1;
  const float* pw2 = (const float*)&w2;
  const float* pw3 = (const float*)&w3;
  float a0 = 0.f, a1 = 0.f, a2 = 0.f, a3 = 0.f;
#pragma unroll
  for (int j = 0; j < 4; ++j) {
    int sr = s - 3 + j;
    if (sr < 0) continue;
    ushort4 mv = *(const ushort4*)(C1 + (size_t)(row - 3 + j) * NWP + c4);
    a0 += bf2f(mv.x) * pw0[j];
    a1 += bf2f(mv.y) * pw1[j];
    a2 += bf2f(mv.z) * pw2[j];
    a3 += bf2f(mv.w) * pw3[j];
  }
  ushort4 o;
  o.x = f2bf(a0 / (1.f + __expf(-a0)));
  o.y = f2bf(a1 / (1.f + __expf(-a1)));
  o.z = f2bf(a2 / (1.f + __expf(-a2)));
  o.w = f2bf(a3 / (1.f + __expf(-a3)));
  *(ushort4*)(QKV + (size_t)row * CONVD + c4) = o;
}

// ---------------------------------------------------------------- beta / g
__global__ __launch_bounds__(256) void gbeta_kernel(const unsigned short* __restrict__ C1,
                                                    const float* __restrict__ dt_bias,
                                                    const float* __restrict__ A_log,
                                                    float* __restrict__ G, float* __restrict__ BETA) {
  int idx = blockIdx.x * 256 + threadIdx.x;
  int row = idx >> 5, h = idx & 31;
  float bp = bf2f(C1[(size_t)row * NWP + 12288 + h]);
  float ap = bf2f(C1[(size_t)row * NWP + 12320 + h]);
  BETA[idx] = 1.f / (1.f + __expf(-bp));
  float x = ap + dt_bias[h];
  float sp = (x > 15.f) ? x : log1pf(__expf(x));
  G[idx] = -__expf(A_log[h]) * sp;
}

// ---------------------------------------------------------------- MFMA chunked gated delta core
// grid: 256 = b(2) x head(32) x vquarter(4). 256 threads (4 waves). DVH=32.
// LDS plan (bytes):
//   stateT   [32][136] f32   17408   state transposed [v][d]
//   stateTb  [32][136] bf16   8704   bf16 shadow (MFMA B-operand)
//   ktb      [64][136] bf16  17408   l2-normed k, row-major [i][d]
//   ktT     [128][88]  bf16  22528   k transposed [d][i] (state-update B-operand)
//   Amat     [64][68]  f32   17408   A for solve; reused as wvb [64][136] bf16 (kcd)
//   attnb    [64][88]  bf16  11264   masked attn (out2 A-operand)
//   XK       [64][132] f32   33792   solve rhs/result (kcd fp32)
//   XV       [64][36]  f32    9216   solve rhs/result (v_c fp32)
//   vnTb     [32][88]  bf16   5632   v_new^T
//   vdTb     [32][88]  bf16   5632   (v_new * edec)^T
//   gc/bet/edec 3*64   f32     768
#define CORE_SMEM_BYTES 149760
__global__ __launch_bounds__(256) void core_kernel(const unsigned short* __restrict__ QKV,
                                                   const float* __restrict__ G,
                                                   const float* __restrict__ BETA,
                                                   unsigned short* __restrict__ CORE) {
  extern __shared__ char smem[];
  float* stateT = (float*)smem;                                    // [32][136]
  unsigned short* stateTb = (unsigned short*)(stateT + 32 * 136);  // [32][136]
  unsigned short* ktb = stateTb + 32 * 136;                        // [64][136]
  unsigned short* ktT = ktb + 64 * 136;                            // [128][88]
  float* Amat = (float*)(ktT + 128 * 88);                          // [64][68]
  unsigned short* wvb = (unsigned short*)Amat;                     // [64][136] (reuse)
  unsigned short* attnb = (unsigned short*)(Amat + 64 * 68);       // [64][88]
  float* XK = (float*)(attnb + 64 * 88);                           // [64][132]
  float* XV = XK + 64 * 132;                                       // [64][36]
  unsigned short* vnTb = (unsigned short*)(XV + 64 * 36);          // [32][88]
  unsigned short* vdTb = vnTb + 32 * 88;                           // [32][88]
  float* gc = (float*)(vdTb + 32 * 88);                            // [64]
  float* bet = gc + 64;                                            // [64]
  float* edec = bet + 64;                                          // [64]

  const int t = threadIdx.x;
  const int lane = t & 63, w = t >> 6;
  const int rlo = lane & 15, khi = lane >> 4;
  const int b = blockIdx.x >> 7;
  const int h = (blockIdx.x >> 2) & 31;
  const int vq = blockIdx.x & 3;
  const int hq = h >> 1;
  const size_t rowbase = (size_t)b * SEQ;

  for (int i = t; i < 32 * 136; i += 256) { stateT[i] = 0.f; stateTb[i] = 0; }
  __syncthreads();

  bf16x8 qf[4];

#pragma unroll 1
  for (int ncb = 0; ncb < 32; ++ncb) {
    const int row0 = ncb * 64;

    // ---- P0: g scan (wave 0) ----
    if (t < 64) {
      float gv = G[(rowbase + row0 + t) * NUMV + h];
      bet[t] = BETA[(rowbase + row0 + t) * NUMV + h];
#pragma unroll
      for (int off = 1; off < 64; off <<= 1) {
        float u = __shfl_up(gv, off, 64);
        if (t >= off) gv += u;
      }
      gc[t] = gv;
      float tot = __shfl(gv, 63, 64);
      edec[t] = __expf(tot - gv);
    }
    __syncthreads();

    // ---- P1: load k,v (row layout) + q (frag layout, regs) ----
    {
      const int r = t >> 2, q4 = t & 3;
      const size_t grow = (rowbase + row0 + r) * (size_t)CONVD;
      const unsigned short* kp = QKV + grow + 2048 + hq * 128 + q4 * 32;
      float kv[32]; float ssk = 0.f;
#pragma unroll
      for (int j = 0; j < 32; j += 4) {
        ushort4 km = *(const ushort4*)(kp + j);
        kv[j] = bf2f(km.x); kv[j + 1] = bf2f(km.y); kv[j + 2] = bf2f(km.z); kv[j + 3] = bf2f(km.w);
        ssk += kv[j]*kv[j] + kv[j+1]*kv[j+1] + kv[j+2]*kv[j+2] + kv[j+3]*kv[j+3];
      }
      ssk += __shfl_xor(ssk, 1, 64);
      ssk += __shfl_xor(ssk, 2, 64);
      const float rk = rsqrtf(ssk + 1e-6f);
      const float ekr = __expf(gc[r]) * bet[r];
#pragma unroll
      for (int j = 0; j < 32; ++j) {
        float kn = kv[j] * rk;
        ktb[r * 136 + q4 * 32 + j] = f2bf(kn);
        ktT[(q4 * 32 + j) * 88 + r] = f2bf(kn);
        XK[r * 132 + q4 * 32 + j] = kn * ekr;
      }
      const unsigned short* vp = QKV + grow + 4096 + h * 128 + vq * 32 + q4 * 8;
      const float brow = bet[r];
#pragma unroll
      for (int j = 0; j < 8; j += 4) {
        ushort4 vm = *(const ushort4*)(vp + j);
        XV[r * 36 + q4 * 8 + j]     = bf2f(vm.x) * brow;
        XV[r * 36 + q4 * 8 + j + 1] = bf2f(vm.y) * brow;
        XV[r * 36 + q4 * 8 + j + 2] = bf2f(vm.z) * brow;
        XV[r * 36 + q4 * 8 + j + 3] = bf2f(vm.w) * brow;
      }
      // q for this wave's 16 rows, frag layout, into registers
      const int qrow = w * 16 + rlo;
      const unsigned short* qsrc = QKV + (rowbase + row0 + qrow) * (size_t)CONVD + hq * 128 + khi * 8;
      float qv[32]; float ssq = 0.f;
#pragma unroll
      for (int ks = 0; ks < 4; ++ks) {
        ushort4 qa = *(const ushort4*)(qsrc + ks * 32);
        ushort4 qb2 = *(const ushort4*)(qsrc + ks * 32 + 4);
        qv[ks*8+0] = bf2f(qa.x); qv[ks*8+1] = bf2f(qa.y); qv[ks*8+2] = bf2f(qa.z); qv[ks*8+3] = bf2f(qa.w);
        qv[ks*8+4] = bf2f(qb2.x); qv[ks*8+5] = bf2f(qb2.y); qv[ks*8+6] = bf2f(qb2.z); qv[ks*8+7] = bf2f(qb2.w);
#pragma unroll
        for (int e = 0; e < 8; ++e) ssq += qv[ks*8+e] * qv[ks*8+e];
      }
      ssq += __shfl_xor(ssq, 16, 64);
      ssq += __shfl_xor(ssq, 32, 64);
      const float rq = rsqrtf(ssq + 1e-6f) * 0.08838834764831845f;  // * DK^-0.5
#pragma unroll
      for (int ks = 0; ks < 4; ++ks) {
        bf16x8 tv;
#pragma unroll
        for (int e = 0; e < 8; ++e) tv[e] = (short)f2bf(qv[ks*8+e] * rq);
        qf[ks] = tv;
      }
    }
    __syncthreads();

    // ---- P2: S = kn@kn^T -> Amat (masked); attn = q@kn^T -> attnb (masked) ----
    {
      static const signed char SJ[10][2] = {{0,0},{1,0},{1,1},{2,0},{2,1},{2,2},{3,0},{3,1},{3,2},{3,3}};
      static const signed char SB[5] = {0, 4, 7, 9, 10};
      for (int sj = SB[w]; sj < SB[w + 1]; ++sj) {
        const int mt = SJ[sj][0], nt = SJ[sj][1];
        f32x4v acc = (f32x4v){0.f, 0.f, 0.f, 0.f};
#pragma unroll
        for (int ks = 0; ks < 4; ++ks) {
          bf16x8 af = *(const bf16x8*)&ktb[(mt * 16 + rlo) * 136 + ks * 32 + khi * 8];
          bf16x8 bf_ = *(const bf16x8*)&ktb[(nt * 16 + rlo) * 136 + ks * 32 + khi * 8];
          acc = __builtin_amdgcn_mfma_f32_16x16x32_bf16(af, bf_, acc, 0, 0, 0);
        }
        const int j = nt * 16 + rlo;
#pragma unroll
        for (int r2 = 0; r2 < 4; ++r2) {
          const int i = mt * 16 + khi * 4 + r2;
          Amat[i * 68 + j] = (j < i) ? -bet[i] * __expf(gc[i] - gc[j]) * acc[r2] : 0.f;
        }
      }
#pragma unroll
      for (int nt = 0; nt < 4; ++nt) {
        const int j = nt * 16 + rlo;
        if (nt <= w) {
          f32x4v acc = (f32x4v){0.f, 0.f, 0.f, 0.f};
#pragma unroll
          for (int ks = 0; ks < 4; ++ks) {
            bf16x8 bf_ = *(const bf16x8*)&ktb[(nt * 16 + rlo) * 136 + ks * 32 + khi * 8];
            acc = __builtin_amdgcn_mfma_f32_16x16x32_bf16(qf[ks], bf_, acc, 0, 0, 0);
          }
#pragma unroll
          for (int r2 = 0; r2 < 4; ++r2) {
            const int i = w * 16 + khi * 4 + r2;
            float v = (j <= i) ? __expf(gc[i] - gc[j]) * acc[r2] : 0.f;
            attnb[i * 88 + j] = f2bf(v);
          }
        } else {
#pragma unroll
          for (int r2 = 0; r2 < 4; ++r2) {
            const int i = w * 16 + khi * 4 + r2;
            attnb[i * 88 + j] = 0;
          }
        }
      }
    }
    __syncthreads();

    // ---- P3: forward substitution (I-A)X = rhs; 128 XK cols + 32 XV cols ----
#pragma unroll 1
    for (int ib = 0; ib < 8; ++ib) {
      const int i0 = ib * 8;
      if (t < 160) {
        float* Xc; int st;
        if (t < 128) { Xc = XK + t; st = 132; }
        else         { Xc = XV + (t - 128); st = 36; }
        float p[8] = {0, 0, 0, 0, 0, 0, 0, 0};
        for (int j = 0; j < i0; ++j) {
          float xj = Xc[(size_t)j * st];
#pragma unroll
          for (int r2 = 0; r2 < 8; ++r2) p[r2] += Amat[(i0 + r2) * 68 + j] * xj;
        }
        float xi[8];
#pragma unroll
        for (int r2 = 0; r2 < 8; ++r2) {
          float v = Xc[(size_t)(i0 + r2) * st] + p[r2];
#pragma unroll
          for (int r3 = 0; r3 < r2; ++r3) v += Amat[(i0 + r2) * 68 + i0 + r3] * xi[r3];
          xi[r2] = v;
          Xc[(size_t)(i0 + r2) * st] = v;
        }
      }
      __syncthreads();
    }

    // ---- P3.5: XK fp32 -> wvb bf16 (overwrites Amat space) ----
    {
      const int r = t >> 2, q4 = t & 3;
#pragma unroll
      for (int j = 0; j < 32; ++j)
        wvb[r * 136 + q4 * 32 + j] = f2bf(XK[r * 132 + q4 * 32 + j]);
    }
    __syncthreads();

    // ---- P4: P = wvb@stateTb^T ; out1 = q@stateTb^T ; v_new = XV - P ----
    f32x4v oacc[2];
    {
      f32x4v pacc[2];
      pacc[0] = (f32x4v){0.f,0.f,0.f,0.f}; pacc[1] = (f32x4v){0.f,0.f,0.f,0.f};
      oacc[0] = (f32x4v){0.f,0.f,0.f,0.f}; oacc[1] = (f32x4v){0.f,0.f,0.f,0.f};
#pragma unroll
      for (int ks = 0; ks < 4; ++ks) {
        bf16x8 aw = *(const bf16x8*)&wvb[(w * 16 + rlo) * 136 + ks * 32 + khi * 8];
#pragma unroll
        for (int nt = 0; nt < 2; ++nt) {
          bf16x8 bs = *(const bf16x8*)&stateTb[(nt * 16 + rlo) * 136 + ks * 32 + khi * 8];
          pacc[nt] = __builtin_amdgcn_mfma_f32_16x16x32_bf16(aw, bs, pacc[nt], 0, 0, 0);
          oacc[nt] = __builtin_amdgcn_mfma_f32_16x16x32_bf16(qf[ks], bs, oacc[nt], 0, 0, 0);
        }
      }
#pragma unroll
      for (int nt = 0; nt < 2; ++nt) {
        const int v = nt * 16 + rlo;
#pragma unroll
        for (int r2 = 0; r2 < 4; ++r2) {
          const int i = w * 16 + khi * 4 + r2;
          float vn = XV[i * 36 + v] - pacc[nt][r2];
          vnTb[v * 88 + i] = f2bf(vn);
          vdTb[v * 88 + i] = f2bf(vn * edec[i]);
          oacc[nt][r2] *= __expf(gc[i]);
        }
      }
    }
    __syncthreads();

    // ---- P5a: out += attn @ v_new^T^T ; store CORE ----
    {
#pragma unroll
      for (int ks = 0; ks < 2; ++ks) {
        bf16x8 aa = *(const bf16x8*)&attnb[(w * 16 + rlo) * 88 + ks * 32 + khi * 8];
#pragma unroll
        for (int nt = 0; nt < 2; ++nt) {
          bf16x8 bv = *(const bf16x8*)&vnTb[(nt * 16 + rlo) * 88 + ks * 32 + khi * 8];
          oacc[nt] = __builtin_amdgcn_mfma_f32_16x16x32_bf16(aa, bv, oacc[nt], 0, 0, 0);
        }
      }
#pragma unroll
      for (int nt = 0; nt < 2; ++nt) {
        const int col = h * 128 + vq * 32 + nt * 16 + rlo;
#pragma unroll
        for (int r2 = 0; r2 < 4; ++r2) {
          const int i = w * 16 + khi * 4 + r2;
          CORE[(rowbase + row0 + i) * (size_t)4096 + col] = f2bf(oacc[nt][r2]);
        }
      }
    }
    // ---- P5b: stateT = stateT*e^gl + vdT @ ktT^T^T ----
    {
      const int mt2 = w & 1;
      const int ntb = (w >> 1) * 4;
      f32x4v sacc[4];
#pragma unroll
      for (int n2 = 0; n2 < 4; ++n2) sacc[n2] = (f32x4v){0.f, 0.f, 0.f, 0.f};
#pragma unroll
      for (int ks = 0; ks < 2; ++ks) {
        bf16x8 av = *(const bf16x8*)&vdTb[(mt2 * 16 + rlo) * 88 + ks * 32 + khi * 8];
#pragma unroll
        for (int n2 = 0; n2 < 4; ++n2) {
          bf16x8 bk = *(const bf16x8*)&ktT[((ntb + n2) * 16 + rlo) * 88 + ks * 32 + khi * 8];
          sacc[n2] = __builtin_amdgcn_mfma_f32_16x16x32_bf16(av, bk, sacc[n2], 0, 0, 0);
        }
      }
      const float egl = __expf(gc[63]);
#pragma unroll
      for (int n2 = 0; n2 < 4; ++n2) {
#pragma unroll
        for (int r2 = 0; r2 < 4; ++r2) {
          const int v = mt2 * 16 + khi * 4 + r2;
          const int d = (ntb + n2) * 16 + rlo;
          float ns = stateT[v * 136 + d] * egl + sacc[n2][r2];
          stateT[v * 136 + d] = ns;
          stateTb[v * 136 + d] = f2bf(ns);
        }
      }
    }
    __syncthreads();
  }
}

// ---------------------------------------------------------------- gate * silu(z) + RMS-norm
__global__ __launch_bounds__(256) void gatenorm_kernel(const unsigned short* __restrict__ CORE,
                                                       const unsigned short* __restrict__ C1,
                                                       const float* __restrict__ norm_w,
                                                       unsigned short* __restrict__ NRM) {
  const int wid = blockIdx.x * 4 + (threadIdx.x >> 6);
  const int lane = threadIdx.x & 63;
  const int row = wid >> 5, h = wid & 31;
  const int c = lane * 2;
  const size_t cidx = (size_t)row * 4096 + h * 128 + c;
  const size_t zidx = (size_t)row * NWP + 8192 + h * 128 + c;
  float g0 = bf2f(CORE[cidx]), g1 = bf2f(CORE[cidx + 1]);
  float z0 = bf2f(C1[zidx]), z1 = bf2f(C1[zidx + 1]);
  g0 *= z0 / (1.f + __expf(-z0));
  g1 *= z1 / (1.f + __expf(-z1));
  float ss = g0 * g0 + g1 * g1;
#pragma unroll
  for (int m = 1; m < 64; m <<= 1) ss += __shfl_xor(ss, m, 64);
  const float rr = rsqrtf(ss * (1.f / 128.f) + 1e-6f);
  unsigned int o = ((unsigned int)f2bf(g1 * rr * norm_w[c + 1]) << 16) | (unsigned int)f2bf(g0 * rr * norm_w[c]);
  *(unsigned int*)(NRM + cidx) = o;
}

// ---------------------------------------------------------------------------
extern "C" void kernel_launch(void* const* d_in, const int* in_sizes, int n_in,
                              void* d_out, int out_size, void* d_ws, size_t ws_size,
                              hipStream_t stream) {
  const float* hs      = (const float*)d_in[0];
  const float* W_qkv   = (const float*)d_in[1];
  const float* W_z     = (const float*)d_in[2];
  const float* W_b     = (const float*)d_in[3];
  const float* W_a     = (const float*)d_in[4];
  const float* conv_w  = (const float*)d_in[5];
  const float* dt_bias = (const float*)d_in[6];
  const float* A_log   = (const float*)d_in[7];
  const float* norm_w  = (const float*)d_in[8];
  const float* W_out   = (const float*)d_in[9];
  float* out = (float*)d_out;
  char* ws = (char*)d_ws;

  const size_t OFF_HSB = 0;
  const size_t OFF_WT  = OFF_HSB + (size_t)ROWS * HIDN * 2;
  const size_t OFF_WOT = OFF_WT + (size_t)NWP * HIDN * 2;
  const size_t OFF_C1  = OFF_WOT + (size_t)HIDN * 4096 * 2;
  const size_t OFF_QKV = OFF_C1 + (size_t)ROWS * NWP * 2;
  const size_t OFF_G   = OFF_QKV + (size_t)ROWS * CONVD * 2;
  const size_t OFF_B   = OFF_G + (size_t)ROWS * NUMV * 4;
  const size_t OFF_CORE = OFF_WT;    // alias: WT dead after GEMM1
  const size_t OFF_NRM  = OFF_QKV;   // alias: QKV dead after core

  unsigned short* hsb = (unsigned short*)(ws + OFF_HSB);
  unsigned short* WT  = (unsigned short*)(ws + OFF_WT);
  unsigned short* WoT = (unsigned short*)(ws + OFF_WOT);
  unsigned short* C1  = (unsigned short*)(ws + OFF_C1);
  unsigned short* QKV = (unsigned short*)(ws + OFF_QKV);
  float* Gb = (float*)(ws + OFF_G);
  float* Bb = (float*)(ws + OFF_B);
  unsigned short* COREb = (unsigned short*)(ws + OFF_CORE);
  unsigned short* NRMb  = (unsigned short*)(ws + OFF_NRM);

  cast_kernel<<<ROWS * HIDN / 4 / 256, 256, 0, stream>>>(hs, hsb, ROWS * HIDN / 4);
  transpose_kernel<<<dim3(8192 / 64, 2048 / 64), 256, 0, stream>>>(W_qkv, WT, 2048, 8192, HIDN, 0);
  transpose_kernel<<<dim3(4096 / 64, 2048 / 64), 256, 0, stream>>>(W_z, WT, 2048, 4096, HIDN, 8192);
  transpose_kernel<<<dim3(1, 2048 / 64), 256, 0, stream>>>(W_b, WT, 2048, 32, HIDN, 12288);
  transpose_kernel<<<dim3(1, 2048 / 64), 256, 0, stream>>>(W_a, WT, 2048, 32, HIDN, 12320);
  hipMemsetAsync(ws + OFF_WT + (size_t)12352 * HIDN * 2, 0, (size_t)64 * HIDN * 2, stream);
  transpose_kernel<<<dim3(2048 / 64, 4096 / 64), 256, 0, stream>>>(W_out, WoT, 4096, 2048, 4096, 0);

  gemm_bt_kernel<1><<<dim3(NWP / 128, ROWS / 128), 256, 0, stream>>>(hsb, WT, C1, ROWS, NWP, HIDN);
  conv_silu_kernel<<<ROWS * (CONVD / 4) / 256, 256, 0, stream>>>(C1, conv_w, QKV);
  gbeta_kernel<<<ROWS * NUMV / 256, 256, 0, stream>>>(C1, dt_bias, A_log, Gb, Bb);

  hipFuncSetAttribute((const void*)core_kernel, hipFuncAttributeMaxDynamicSharedMemorySize,
                      CORE_SMEM_BYTES);
  core_kernel<<<256, 256, CORE_SMEM_BYTES, stream>>>(QKV, Gb, Bb, COREb);

  gatenorm_kernel<<<ROWS * NUMV / 4, 256, 0, stream>>>(COREb, C1, norm_w, NRMb);
  gemm_bt_kernel<0><<<dim3(2048 / 128, ROWS / 128), 256, 0, stream>>>(NRMb, WoT, out, ROWS, 2048, 4096);
}

// Round 3
// 1010.502 us; speedup vs baseline: 3.4823x; 1.6205x over previous
//
#include <hip/hip_runtime.h>
#include <cstdint>
#include <cstddef>

// ---------------------------------------------------------------------------
// GatedDeltaNet forward, MI355X/gfx950.
//  1. cast hs -> bf16 ; transpose weights -> bf16 [N][K]
//  2. GEMM1: C1[4096][12416] = hs @ [W_qkv|W_z|W_b|W_a]   (bf16 MFMA, global_load_lds)
//  3. causal conv(K=4)+SiLU -> QKV bf16 ; beta/g
//  4. INTRA (chunk-parallel, 2048 WGs): A build + solve -> w,u (into C1 dead cols), attn (hsb region)
//  5. SEQ (512 WGs: b x h x 8 v-slices): state recurrence, MFMA
//  6. gate + RMS-norm -> NRM bf16 ; GEMM2: out = NRM @ W_out (fp32)
// ---------------------------------------------------------------------------

#define ROWS  4096
#define SEQ   2048
#define HIDN  2048
#define CONVD 8192
#define NWP   12416
#define NUMV  32

using bf16x8 = __attribute__((ext_vector_type(8))) short;
using f32x4v = __attribute__((ext_vector_type(4))) float;

__device__ __forceinline__ float bf2f(unsigned short u) {
  union { unsigned int i; float f; } x; x.i = ((unsigned int)u) << 16; return x.f;
}
__device__ __forceinline__ unsigned short f2bf(float f) {
  union { float f; unsigned int u; } x; x.f = f;
  unsigned int u = x.u;
  unsigned int r = (u + 0x7FFFu + ((u >> 16) & 1u)) >> 16;  // RNE
  return (unsigned short)r;
}

// global -> LDS direct (16B/lane). LDS dest must be wave-uniform base + lane*16.
typedef const __attribute__((address_space(1))) unsigned int GU32;
typedef __attribute__((address_space(3))) unsigned int LU32;
__device__ __forceinline__ void gld_lds16(const void* g, void* l) {
  GU32* gp = (GU32*)(unsigned long long)(uintptr_t)g;
  LU32* lp = (LU32*)(unsigned int)(uintptr_t)l;  // flat-LDS low32 = LDS offset
  __builtin_amdgcn_global_load_lds(gp, lp, 16, 0, 0);
}

// ---------------------------------------------------------------- cast fp32->bf16
__global__ __launch_bounds__(256) void cast_kernel(const float* __restrict__ in,
                                                   unsigned short* __restrict__ out, int n4) {
  int i = blockIdx.x * 256 + threadIdx.x;
  if (i >= n4) return;
  float4 v = ((const float4*)in)[i];
  ushort4 o;
  o.x = f2bf(v.x); o.y = f2bf(v.y); o.z = f2bf(v.z); o.w = f2bf(v.w);
  ((ushort4*)out)[i] = o;
}

// ------------------------------------------------- transpose W[K][N] -> WT[roff+N][K] bf16
__global__ __launch_bounds__(256) void transpose_kernel(const float* __restrict__ W,
                                                        unsigned short* __restrict__ WT,
                                                        int K, int N, int ld, int roff) {
  __shared__ float tile[64][65];
  const int t = threadIdx.x;
  const int kb = blockIdx.y * 64, nb = blockIdx.x * 64;
  const int r = t >> 2, c0 = (t & 3) * 16;
#pragma unroll
  for (int i = 0; i < 16; ++i) {
    int c = c0 + i;
    float v = 0.f;
    if (nb + c < N) v = W[(size_t)(kb + r) * N + nb + c];
    tile[r][c] = v;
  }
  __syncthreads();
  const int bn = t >> 2;
  if (nb + bn < N) {
#pragma unroll
    for (int i = 0; i < 16; ++i)
      WT[(size_t)(roff + nb + bn) * ld + kb + c0 + i] = f2bf(tile[c0 + i][bn]);
  }
}

// ---------------------------------------------------------------- bf16 MFMA GEMM (B^T input)
template <int OUT_BF16>
__global__ __launch_bounds__(256) void gemm_bt_kernel(const unsigned short* __restrict__ Ag,
                                                      const unsigned short* __restrict__ Bg,
                                                      void* __restrict__ Cg, int M, int N, int K) {
  __shared__ __align__(16) unsigned short As[128 * 32];
  __shared__ __align__(16) unsigned short Bs[128 * 32];
  const int t = threadIdx.x;
  const int lane = t & 63, w = t >> 6;
  const int wm = w >> 1, wn = w & 1;
  const int m0 = blockIdx.y * 128, n0 = blockIdx.x * 128;

  f32x4v acc[4][4];
#pragma unroll
  for (int i = 0; i < 4; ++i)
#pragma unroll
    for (int j = 0; j < 4; ++j) acc[i][j] = (f32x4v){0.f, 0.f, 0.f, 0.f};

  const int sr = t >> 2;            // row within 64-row half
  const int sk = (t & 3) * 8;       // k element offset
  const unsigned short* ap0 = Ag + (size_t)(m0 + sr) * K + sk;
  const unsigned short* ap1 = Ag + (size_t)(m0 + 64 + sr) * K + sk;
  const unsigned short* bp0 = Bg + (size_t)(n0 + sr) * K + sk;
  const unsigned short* bp1 = Bg + (size_t)(n0 + 64 + sr) * K + sk;
  unsigned short* As16 = As + t * 8;       // byte offset 16*t (wave-uniform + lane*16)
  unsigned short* Bs16 = Bs + t * 8;

  const int rlo = lane & 15;
  const int kh8 = (lane >> 4) * 8;

  for (int k0 = 0; k0 < K; k0 += 32) {
    __syncthreads();
    gld_lds16(ap0 + k0, As16);
    gld_lds16(ap1 + k0, As16 + 2048);
    gld_lds16(bp0 + k0, Bs16);
    gld_lds16(bp1 + k0, Bs16 + 2048);
    __syncthreads();
    bf16x8 af[4], bfv[4];
#pragma unroll
    for (int i = 0; i < 4; ++i) af[i] = *(const bf16x8*)&As[(wm * 64 + i * 16 + rlo) * 32 + kh8];
#pragma unroll
    for (int j = 0; j < 4; ++j) bfv[j] = *(const bf16x8*)&Bs[(wn * 64 + j * 16 + rlo) * 32 + kh8];
#pragma unroll
    for (int i = 0; i < 4; ++i)
#pragma unroll
      for (int j = 0; j < 4; ++j)
        acc[i][j] = __builtin_amdgcn_mfma_f32_16x16x32_bf16(af[i], bfv[j], acc[i][j], 0, 0, 0);
  }

  const int mrb = (lane >> 4) * 4;
  const int ncc = lane & 15;
#pragma unroll
  for (int i = 0; i < 4; ++i)
#pragma unroll
    for (int j = 0; j < 4; ++j)
#pragma unroll
      for (int r = 0; r < 4; ++r) {
        int mm = m0 + wm * 64 + i * 16 + mrb + r;
        int nn = n0 + wn * 64 + j * 16 + ncc;
        float v = acc[i][j][r];
        if (OUT_BF16) ((unsigned short*)Cg)[(size_t)mm * N + nn] = f2bf(v);
        else          ((float*)Cg)[(size_t)mm * N + nn] = v;
      }
}

// ---------------------------------------------------------------- causal conv K=4 + SiLU
__global__ __launch_bounds__(256) void conv_silu_kernel(const unsigned short* __restrict__ C1,
                                                        const float* __restrict__ conv_w,
                                                        unsigned short* __restrict__ QKV) {
  int idx = blockIdx.x * 256 + threadIdx.x;
  int row = idx >> 11;
  int c4 = (idx & 2047) << 2;
  int s = row & 2047;
  float4 w0 = *(const float4*)(conv_w + (size_t)(c4 + 0) * 4);
  float4 w1 = *(const float4*)(conv_w + (size_t)(c4 + 1) * 4);
  float4 w2 = *(const float4*)(conv_w + (size_t)(c4 + 2) * 4);
  float4 w3 = *(const float4*)(conv_w + (size_t)(c4 + 3) * 4);
  const float* pw0 = (const float*)&w0;
  const float* pw1 = (const float*)&w1;
  const float* pw2 = (const float*)&w2;
  const float* pw3 = (const float*)&w3;
  float a0 = 0.f, a1 = 0.f, a2 = 0.f, a3 = 0.f;
#pragma unroll
  for (int j = 0; j < 4; ++j) {
    int sr = s - 3 + j;
    if (sr < 0) continue;
    ushort4 mv = *(const ushort4*)(C1 + (size_t)(row - 3 + j) * NWP + c4);
    a0 += bf2f(mv.x) * pw0[j];
    a1 += bf2f(mv.y) * pw1[j];
    a2 += bf2f(mv.z) * pw2[j];
    a3 += bf2f(mv.w) * pw3[j];
  }
  ushort4 o;
  o.x = f2bf(a0 / (1.f + __expf(-a0)));
  o.y = f2bf(a1 / (1.f + __expf(-a1)));
  o.z = f2bf(a2 / (1.f + __expf(-a2)));
  o.w = f2bf(a3 / (1.f + __expf(-a3)));
  *(ushort4*)(QKV + (size_t)row * CONVD + c4) = o;
}

// ---------------------------------------------------------------- beta / g
__global__ __launch_bounds__(256) void gbeta_kernel(const unsigned short* __restrict__ C1,
                                                    const float* __restrict__ dt_bias,
                                                    const float* __restrict__ A_log,
                                                    float* __restrict__ G, float* __restrict__ BETA) {
  int idx = blockIdx.x * 256 + threadIdx.x;
  int row = idx >> 5, h = idx & 31;
  float bp = bf2f(C1[(size_t)row * NWP + 12288 + h]);
  float ap = bf2f(C1[(size_t)row * NWP + 12320 + h]);
  BETA[idx] = 1.f / (1.f + __expf(-bp));
  float x = ap + dt_bias[h];
  float sp = (x > 15.f) ? x : log1pf(__expf(x));
  G[idx] = -__expf(A_log[h]) * sp;
}

// ---------------------------------------------------------------- INTRA: per-chunk solve
// grid 2048 = b(2) x h(32) x chunk(32). 256 threads. LDS 70144 B -> 2 WG/CU.
//   ktb  [64][136] bf16  17408   l2-normed k
//   Amat [64][68]  f32   17408   strictly-lower A (with -beta, decay)
//   Xt   [128][68] f32   34816   solve columns, TRANSPOSED [col][row]; qb bf16 alias
//   gc, bet                 512
#define INTRA_SMEM 70144
__global__ __launch_bounds__(256) void intra_kernel(const unsigned short* __restrict__ QKV,
                                                    const float* __restrict__ G,
                                                    const float* __restrict__ BETA,
                                                    unsigned short* __restrict__ WU,
                                                    unsigned short* __restrict__ ATTN) {
  extern __shared__ char smem[];
  unsigned short* ktb = (unsigned short*)smem;        // [64][136]
  float* Amat = (float*)(smem + 17408);               // [64][68]
  float* Xt   = (float*)(smem + 34816);               // [128][68]
  unsigned short* qb = (unsigned short*)Xt;           // [64][136] alias (after solves)
  float* gc  = (float*)(smem + 69632);                // [64]
  float* bet = gc + 64;                               // [64]

  const int t = threadIdx.x;
  const int lane = t & 63, w = t >> 6;
  const int rlo = lane & 15, khi = lane >> 4;
  const int cix = blockIdx.x & 31;
  const int h = (blockIdx.x >> 5) & 31;
  const int b = blockIdx.x >> 10;
  const int hq = h >> 1;
  const int row0 = cix * 64;
  const size_t rowbase = (size_t)b * SEQ;

  // P0: g scan
  if (t < 64) {
    float gv = G[(rowbase + row0 + t) * NUMV + h];
    bet[t] = BETA[(rowbase + row0 + t) * NUMV + h];
#pragma unroll
    for (int off = 1; off < 64; off <<= 1) {
      float u = __shfl_up(gv, off, 64);
      if (t >= off) gv += u;
    }
    gc[t] = gv;
  }
  __syncthreads();

  const int r = t >> 2, q4 = t & 3;
  const size_t grow = (rowbase + row0 + r) * (size_t)CONVD;

  // P1: k load + l2norm -> ktb ; w-rhs = kn*e^gc*beta -> Xt
  {
    const unsigned short* kp = QKV + grow + 2048 + hq * 128 + q4 * 32;
    float kv[32]; float ssk = 0.f;
#pragma unroll
    for (int j = 0; j < 32; j += 4) {
      ushort4 km = *(const ushort4*)(kp + j);
      kv[j] = bf2f(km.x); kv[j + 1] = bf2f(km.y); kv[j + 2] = bf2f(km.z); kv[j + 3] = bf2f(km.w);
      ssk += kv[j]*kv[j] + kv[j+1]*kv[j+1] + kv[j+2]*kv[j+2] + kv[j+3]*kv[j+3];
    }
    ssk += __shfl_xor(ssk, 1, 64);
    ssk += __shfl_xor(ssk, 2, 64);
    const float rk = rsqrtf(ssk + 1e-6f);
    const float ekr = __expf(gc[r]) * bet[r];
#pragma unroll
    for (int j = 0; j < 32; ++j) {
      float kn = kv[j] * rk;
      ktb[r * 136 + q4 * 32 + j] = f2bf(kn);
      Xt[(q4 * 32 + j) * 68 + r] = kn * ekr;
    }
  }
  __syncthreads();

  // P2: A = -(k_beta@k^T)*decay strictly-lower -> Amat (10 lower tiles over 4 waves)
  {
    static const signed char SJ[10][2] = {{0,0},{1,0},{1,1},{2,0},{2,1},{2,2},{3,0},{3,1},{3,2},{3,3}};
    static const signed char SB[5] = {0, 4, 7, 9, 10};
    for (int sj = SB[w]; sj < SB[w + 1]; ++sj) {
      const int mt = SJ[sj][0], nt = SJ[sj][1];
      f32x4v acc = (f32x4v){0.f, 0.f, 0.f, 0.f};
#pragma unroll
      for (int ks = 0; ks < 4; ++ks) {
        bf16x8 af = *(const bf16x8*)&ktb[(mt * 16 + rlo) * 136 + ks * 32 + khi * 8];
        bf16x8 bf_ = *(const bf16x8*)&ktb[(nt * 16 + rlo) * 136 + ks * 32 + khi * 8];
        acc = __builtin_amdgcn_mfma_f32_16x16x32_bf16(af, bf_, acc, 0, 0, 0);
      }
      const int j = nt * 16 + rlo;
#pragma unroll
      for (int r2 = 0; r2 < 4; ++r2) {
        const int i = mt * 16 + khi * 4 + r2;
        if (j < i) Amat[i * 68 + j] = -bet[i] * __expf(gc[i] - gc[j]) * acc[r2];
      }
    }
  }
  __syncthreads();

  // P3: solve (I-A)X = rhs, pass A (w). Thread c<128 owns column c (register p, LDS Xt col).
#pragma unroll 1
  for (int ib = 0; ib < 8; ++ib) {
    const int i0 = ib * 8;
    if (t < 128) {
      float* Xc = Xt + t * 68;
      float p[8] = {0, 0, 0, 0, 0, 0, 0, 0};
      for (int j = 0; j < i0; j += 4) {
        f32x4v xj = *(const f32x4v*)&Xc[j];
#pragma unroll
        for (int r2 = 0; r2 < 8; ++r2) {
          f32x4v ar = *(const f32x4v*)&Amat[(i0 + r2) * 68 + j];
          p[r2] += ar[0] * xj[0] + ar[1] * xj[1] + ar[2] * xj[2] + ar[3] * xj[3];
        }
      }
      float xi[8];
#pragma unroll
      for (int r2 = 0; r2 < 8; ++r2) {
        float v = Xc[i0 + r2] + p[r2];
#pragma unroll
        for (int r3 = 0; r3 < r2; ++r3) v += Amat[(i0 + r2) * 68 + i0 + r3] * xi[r3];
        xi[r2] = v;
        Xc[i0 + r2] = v;
      }
    }
    __syncthreads();
  }

  // store w (cols [0,4096)) ; load v rhs into Xt (same thread->same slots, no race)
  {
    unsigned short* wdst = WU + (rowbase + row0 + r) * (size_t)NWP + h * 128 + q4 * 32;
#pragma unroll
    for (int j = 0; j < 32; ++j) wdst[j] = f2bf(Xt[(q4 * 32 + j) * 68 + r]);
    const unsigned short* vp = QKV + grow + 4096 + h * 128 + q4 * 32;
    const float brow = bet[r];
#pragma unroll
    for (int j = 0; j < 32; j += 4) {
      ushort4 vm = *(const ushort4*)(vp + j);
      Xt[(q4 * 32 + j + 0) * 68 + r] = bf2f(vm.x) * brow;
      Xt[(q4 * 32 + j + 1) * 68 + r] = bf2f(vm.y) * brow;
      Xt[(q4 * 32 + j + 2) * 68 + r] = bf2f(vm.z) * brow;
      Xt[(q4 * 32 + j + 3) * 68 + r] = bf2f(vm.w) * brow;
    }
  }
  __syncthreads();

  // P4: solve pass B (u)
#pragma unroll 1
  for (int ib = 0; ib < 8; ++ib) {
    const int i0 = ib * 8;
    if (t < 128) {
      float* Xc = Xt + t * 68;
      float p[8] = {0, 0, 0, 0, 0, 0, 0, 0};
      for (int j = 0; j < i0; j += 4) {
        f32x4v xj = *(const f32x4v*)&Xc[j];
#pragma unroll
        for (int r2 = 0; r2 < 8; ++r2) {
          f32x4v ar = *(const f32x4v*)&Amat[(i0 + r2) * 68 + j];
          p[r2] += ar[0] * xj[0] + ar[1] * xj[1] + ar[2] * xj[2] + ar[3] * xj[3];
        }
      }
      float xi[8];
#pragma unroll
      for (int r2 = 0; r2 < 8; ++r2) {
        float v = Xc[i0 + r2] + p[r2];
#pragma unroll
        for (int r3 = 0; r3 < r2; ++r3) v += Amat[(i0 + r2) * 68 + i0 + r3] * xi[r3];
        xi[r2] = v;
        Xc[i0 + r2] = v;
      }
    }
    __syncthreads();
  }

  // store u (cols [4096,8192))
  {
    unsigned short* udst = WU + (rowbase + row0 + r) * (size_t)NWP + 4096 + h * 128 + q4 * 32;
#pragma unroll
    for (int j = 0; j < 32; ++j) udst[j] = f2bf(Xt[(q4 * 32 + j) * 68 + r]);
  }
  __syncthreads();

  // P5: q load+norm -> qb (aliases Xt; all u-store reads drained by barrier above)
  {
    const unsigned short* qp = QKV + grow + hq * 128 + q4 * 32;
    float qv[32]; float ssq = 0.f;
#pragma unroll
    for (int j = 0; j < 32; j += 4) {
      ushort4 qm = *(const ushort4*)(qp + j);
      qv[j] = bf2f(qm.x); qv[j + 1] = bf2f(qm.y); qv[j + 2] = bf2f(qm.z); qv[j + 3] = bf2f(qm.w);
      ssq += qv[j]*qv[j] + qv[j+1]*qv[j+1] + qv[j+2]*qv[j+2] + qv[j+3]*qv[j+3];
    }
    ssq += __shfl_xor(ssq, 1, 64);
    ssq += __shfl_xor(ssq, 2, 64);
    const float rq = rsqrtf(ssq + 1e-6f) * 0.08838834764831845f;  // * DK^-0.5
#pragma unroll
    for (int j = 0; j < 32; ++j) qb[r * 136 + q4 * 32 + j] = f2bf(qv[j] * rq);
  }
  __syncthreads();

  // P6: attn = (q@k^T)*decay, masked j<=i; store (wave w owns row-band mt=w)
  {
    const size_t abase = (((size_t)b * 32 + h) * 32 + cix) * 4096;
#pragma unroll 1
    for (int nt = 0; nt < 4; ++nt) {
      const int j = nt * 16 + rlo;
      float vals[4] = {0.f, 0.f, 0.f, 0.f};
      if (nt <= w) {
        f32x4v acc = (f32x4v){0.f, 0.f, 0.f, 0.f};
#pragma unroll
        for (int ks = 0; ks < 4; ++ks) {
          bf16x8 af = *(const bf16x8*)&qb[(w * 16 + rlo) * 136 + ks * 32 + khi * 8];
          bf16x8 bf_ = *(const bf16x8*)&ktb[(nt * 16 + rlo) * 136 + ks * 32 + khi * 8];
          acc = __builtin_amdgcn_mfma_f32_16x16x32_bf16(af, bf_, acc, 0, 0, 0);
        }
#pragma unroll
        for (int r2 = 0; r2 < 4; ++r2) {
          const int i = w * 16 + khi * 4 + r2;
          if (j <= i) vals[r2] = __expf(gc[i] - gc[j]) * acc[r2];
        }
      }
#pragma unroll
      for (int r2 = 0; r2 < 4; ++r2)
        ATTN[abase + (w * 16 + khi * 4 + r2) * 64 + j] = f2bf(vals[r2]);
    }
  }
}

// ---------------------------------------------------------------- SEQ: state recurrence
// grid 512 = b(2) x h(32) x vslice(8). 256 threads. DVH=16. LDS 70400 B -> 2 WG/CU.
#define SEQ_SMEM 70400
__global__ __launch_bounds__(256) void seq_kernel(const unsigned short* __restrict__ QKV,
                                                  const float* __restrict__ G,
                                                  const unsigned short* __restrict__ WU,
                                                  const unsigned short* __restrict__ ATTN,
                                                  unsigned short* __restrict__ CORE) {
  extern __shared__ char smem[];
  unsigned short* ktT    = (unsigned short*)smem;        // [128][88]  kn transposed [d][i]
  unsigned short* wb     = (unsigned short*)(smem + 22528);  // [64][136]
  unsigned short* attnb  = (unsigned short*)(smem + 39936);  // [64][88]
  float* stateT          = (float*)(smem + 51200);       // [16][136]  S^T [v][d] fp32
  unsigned short* stateTb = (unsigned short*)(smem + 59904); // [16][136] bf16 shadow
  unsigned short* vnTb   = (unsigned short*)(smem + 64256); // [16][88]  v_new^T
  unsigned short* vdTb   = (unsigned short*)(smem + 67072); // [16][88]  (v_new*edec)^T
  float* gc   = (float*)(smem + 69888);                  // [64]
  float* edec = (float*)(smem + 70144);                  // [64]

  const int t = threadIdx.x;
  const int lane = t & 63, w = t >> 6;
  const int rlo = lane & 15, khi = lane >> 4;
  const int vq = blockIdx.x & 7;
  const int h = (blockIdx.x >> 3) & 31;
  const int b = blockIdx.x >> 8;
  const int hq = h >> 1;
  const size_t rowbase = (size_t)b * SEQ;
  const size_t ahead = ((size_t)b * 32 + h) * 32;

  for (int i = t; i < 16 * 136; i += 256) { stateT[i] = 0.f; stateTb[i] = 0; }
  __syncthreads();

  bf16x8 qf[4];

#pragma unroll 1
  for (int ncb = 0; ncb < 32; ++ncb) {
    const int row0 = ncb * 64;

    // P0: g scan
    if (t < 64) {
      float gv = G[(rowbase + row0 + t) * NUMV + h];
#pragma unroll
      for (int off = 1; off < 64; off <<= 1) {
        float u = __shfl_up(gv, off, 64);
        if (t >= off) gv += u;
      }
      gc[t] = gv;
      float tot = __shfl(gv, 63, 64);
      edec[t] = __expf(tot - gv);
    }
    __syncthreads();

    // P1: loads
    {
      const int r = t >> 2, q4 = t & 3;
      const size_t grow = (rowbase + row0 + r) * (size_t)CONVD;
      // k -> ktT (transposed)
      const unsigned short* kp = QKV + grow + 2048 + hq * 128 + q4 * 32;
      float kv[32]; float ssk = 0.f;
#pragma unroll
      for (int j = 0; j < 32; j += 4) {
        ushort4 km = *(const ushort4*)(kp + j);
        kv[j] = bf2f(km.x); kv[j + 1] = bf2f(km.y); kv[j + 2] = bf2f(km.z); kv[j + 3] = bf2f(km.w);
        ssk += kv[j]*kv[j] + kv[j+1]*kv[j+1] + kv[j+2]*kv[j+2] + kv[j+3]*kv[j+3];
      }
      ssk += __shfl_xor(ssk, 1, 64);
      ssk += __shfl_xor(ssk, 2, 64);
      const float rk = rsqrtf(ssk + 1e-6f);
#pragma unroll
      for (int j = 0; j < 32; ++j) ktT[(q4 * 32 + j) * 88 + r] = f2bf(kv[j] * rk);
      // w tile copy
      const unsigned short* wsrc = WU + (rowbase + row0 + r) * (size_t)NWP + h * 128 + q4 * 32;
#pragma unroll
      for (int u2 = 0; u2 < 4; ++u2)
        *(uint4*)&wb[r * 136 + q4 * 32 + u2 * 8] = *(const uint4*)(wsrc + u2 * 8);
      // attn tile copy
      const unsigned short* asrc = ATTN + (ahead + ncb) * 4096 + r * 64 + q4 * 16;
      *(uint4*)&attnb[r * 88 + q4 * 16] = *(const uint4*)(asrc);
      *(uint4*)&attnb[r * 88 + q4 * 16 + 8] = *(const uint4*)(asrc + 8);
      // q -> frag regs (rows w*16+rlo)
      const unsigned short* qsrc = QKV + (rowbase + row0 + w * 16 + rlo) * (size_t)CONVD + hq * 128 + khi * 8;
      float qv[32]; float ssq = 0.f;
#pragma unroll
      for (int ks = 0; ks < 4; ++ks) {
        ushort4 qa = *(const ushort4*)(qsrc + ks * 32);
        ushort4 qb2 = *(const ushort4*)(qsrc + ks * 32 + 4);
        qv[ks*8+0] = bf2f(qa.x); qv[ks*8+1] = bf2f(qa.y); qv[ks*8+2] = bf2f(qa.z); qv[ks*8+3] = bf2f(qa.w);
        qv[ks*8+4] = bf2f(qb2.x); qv[ks*8+5] = bf2f(qb2.y); qv[ks*8+6] = bf2f(qb2.z); qv[ks*8+7] = bf2f(qb2.w);
#pragma unroll
        for (int e = 0; e < 8; ++e) ssq += qv[ks*8+e] * qv[ks*8+e];
      }
      ssq += __shfl_xor(ssq, 16, 64);
      ssq += __shfl_xor(ssq, 32, 64);
      const float rq = rsqrtf(ssq + 1e-6f) * 0.08838834764831845f;
#pragma unroll
      for (int ks = 0; ks < 4; ++ks) {
        bf16x8 tv;
#pragma unroll
        for (int e = 0; e < 8; ++e) tv[e] = (short)f2bf(qv[ks*8+e] * rq);
        qf[ks] = tv;
      }
    }
    __syncthreads();

    // P2: pacc = w@S^T, oacc = q@S^T ; v_new = u - pacc -> vnTb/vdTb ; oacc *= e^gc
    f32x4v oacc;
    {
      f32x4v pacc = (f32x4v){0.f, 0.f, 0.f, 0.f};
      oacc = (f32x4v){0.f, 0.f, 0.f, 0.f};
#pragma unroll
      for (int ks = 0; ks < 4; ++ks) {
        bf16x8 aw = *(const bf16x8*)&wb[(w * 16 + rlo) * 136 + ks * 32 + khi * 8];
        bf16x8 bs = *(const bf16x8*)&stateTb[rlo * 136 + ks * 32 + khi * 8];
        pacc = __builtin_amdgcn_mfma_f32_16x16x32_bf16(aw, bs, pacc, 0, 0, 0);
        oacc = __builtin_amdgcn_mfma_f32_16x16x32_bf16(qf[ks], bs, oacc, 0, 0, 0);
      }
#pragma unroll
      for (int r2 = 0; r2 < 4; ++r2) {
        const int i = w * 16 + khi * 4 + r2;
        float uv = bf2f(WU[(rowbase + row0 + i) * (size_t)NWP + 4096 + h * 128 + vq * 16 + rlo]);
        float vn = uv - pacc[r2];
        vnTb[rlo * 88 + i] = f2bf(vn);
        vdTb[rlo * 88 + i] = f2bf(vn * edec[i]);
        oacc[r2] *= __expf(gc[i]);
      }
    }
    __syncthreads();

    // P3: oacc += attn@vn^T ; store CORE ; state update
    {
#pragma unroll
      for (int ks = 0; ks < 2; ++ks) {
        bf16x8 aa = *(const bf16x8*)&attnb[(w * 16 + rlo) * 88 + ks * 32 + khi * 8];
        bf16x8 bv = *(const bf16x8*)&vnTb[rlo * 88 + ks * 32 + khi * 8];
        oacc = __builtin_amdgcn_mfma_f32_16x16x32_bf16(aa, bv, oacc, 0, 0, 0);
      }
      const int col = h * 128 + vq * 16 + rlo;
#pragma unroll
      for (int r2 = 0; r2 < 4; ++r2) {
        const int i = w * 16 + khi * 4 + r2;
        CORE[(rowbase + row0 + i) * (size_t)4096 + col] = f2bf(oacc[r2]);
      }
      // state: S^T[v][d] = S^T*e^gl + (kn*edec)^T @ vn  (8 d-tiles over 4 waves, 2 each)
      const float egl = __expf(gc[63]);
#pragma unroll
      for (int n2 = 0; n2 < 2; ++n2) {
        const int dt = w * 2 + n2;
        f32x4v sacc = (f32x4v){0.f, 0.f, 0.f, 0.f};
#pragma unroll
        for (int ks = 0; ks < 2; ++ks) {
          bf16x8 ak = *(const bf16x8*)&ktT[(dt * 16 + rlo) * 88 + ks * 32 + khi * 8];
          bf16x8 bv2 = *(const bf16x8*)&vdTb[rlo * 88 + ks * 32 + khi * 8];
          sacc = __builtin_amdgcn_mfma_f32_16x16x32_bf16(ak, bv2, sacc, 0, 0, 0);
        }
#pragma unroll
        for (int r2 = 0; r2 < 4; ++r2) {
          const int d = dt * 16 + khi * 4 + r2;
          float ns = stateT[rlo * 136 + d] * egl + sacc[r2];
          stateT[rlo * 136 + d] = ns;
          stateTb[rlo * 136 + d] = f2bf(ns);
        }
      }
    }
    __syncthreads();
  }
}

// ---------------------------------------------------------------- gate * silu(z) + RMS-norm
__global__ __launch_bounds__(256) void gatenorm_kernel(const unsigned short* __restrict__ CORE,
                                                       const unsigned short* __restrict__ C1,
                                                       const float* __restrict__ norm_w,
                                                       unsigned short* __restrict__ NRM) {
  const int wid = blockIdx.x * 4 + (threadIdx.x >> 6);
  const int lane = threadIdx.x & 63;
  const int row = wid >> 5, h = wid & 31;
  const int c = lane * 2;
  const size_t cidx = (size_t)row * 4096 + h * 128 + c;
  const size_t zidx = (size_t)row * NWP + 8192 + h * 128 + c;
  float g0 = bf2f(CORE[cidx]), g1 = bf2f(CORE[cidx + 1]);
  float z0 = bf2f(C1[zidx]), z1 = bf2f(C1[zidx + 1]);
  g0 *= z0 / (1.f + __expf(-z0));
  g1 *= z1 / (1.f + __expf(-z1));
  float ss = g0 * g0 + g1 * g1;
#pragma unroll
  for (int m = 1; m < 64; m <<= 1) ss += __shfl_xor(ss, m, 64);
  const float rr = rsqrtf(ss * (1.f / 128.f) + 1e-6f);
  unsigned int o = ((unsigned int)f2bf(g1 * rr * norm_w[c + 1]) << 16) | (unsigned int)f2bf(g0 * rr * norm_w[c]);
  *(unsigned int*)(NRM + cidx) = o;
}

// ---------------------------------------------------------------------------
extern "C" void kernel_launch(void* const* d_in, const int* in_sizes, int n_in,
                              void* d_out, int out_size, void* d_ws, size_t ws_size,
                              hipStream_t stream) {
  const float* hs      = (const float*)d_in[0];
  const float* W_qkv   = (const float*)d_in[1];
  const float* W_z     = (const float*)d_in[2];
  const float* W_b     = (const float*)d_in[3];
  const float* W_a     = (const float*)d_in[4];
  const float* conv_w  = (const float*)d_in[5];
  const float* dt_bias = (const float*)d_in[6];
  const float* A_log   = (const float*)d_in[7];
  const float* norm_w  = (const float*)d_in[8];
  const float* W_out   = (const float*)d_in[9];
  float* out = (float*)d_out;
  char* ws = (char*)d_ws;

  const size_t OFF_HSB = 0;                                     // hs bf16; later ATTN (16.77MB exact)
  const size_t OFF_WT  = OFF_HSB + (size_t)ROWS * HIDN * 2;     // WT; later CORE
  const size_t OFF_WOT = OFF_WT + (size_t)NWP * HIDN * 2;
  const size_t OFF_C1  = OFF_WOT + (size_t)HIDN * 4096 * 2;     // C1; cols [0,8192) -> w,u after conv
  const size_t OFF_QKV = OFF_C1 + (size_t)ROWS * NWP * 2;       // QKV; later NRM
  const size_t OFF_G   = OFF_QKV + (size_t)ROWS * CONVD * 2;
  const size_t OFF_B   = OFF_G + (size_t)ROWS * NUMV * 4;

  unsigned short* hsb = (unsigned short*)(ws + OFF_HSB);
  unsigned short* WT  = (unsigned short*)(ws + OFF_WT);
  unsigned short* WoT = (unsigned short*)(ws + OFF_WOT);
  unsigned short* C1  = (unsigned short*)(ws + OFF_C1);
  unsigned short* QKV = (unsigned short*)(ws + OFF_QKV);
  float* Gb = (float*)(ws + OFF_G);
  float* Bb = (float*)(ws + OFF_B);
  unsigned short* ATTNb = (unsigned short*)(ws + OFF_HSB);
  unsigned short* COREb = (unsigned short*)(ws + OFF_WT);
  unsigned short* NRMb  = (unsigned short*)(ws + OFF_QKV);

  cast_kernel<<<ROWS * HIDN / 4 / 256, 256, 0, stream>>>(hs, hsb, ROWS * HIDN / 4);
  transpose_kernel<<<dim3(8192 / 64, 2048 / 64), 256, 0, stream>>>(W_qkv, WT, 2048, 8192, HIDN, 0);
  transpose_kernel<<<dim3(4096 / 64, 2048 / 64), 256, 0, stream>>>(W_z, WT, 2048, 4096, HIDN, 8192);
  transpose_kernel<<<dim3(1, 2048 / 64), 256, 0, stream>>>(W_b, WT, 2048, 32, HIDN, 12288);
  transpose_kernel<<<dim3(1, 2048 / 64), 256, 0, stream>>>(W_a, WT, 2048, 32, HIDN, 12320);
  hipMemsetAsync(ws + OFF_WT + (size_t)12352 * HIDN * 2, 0, (size_t)64 * HIDN * 2, stream);
  transpose_kernel<<<dim3(2048 / 64, 4096 / 64), 256, 0, stream>>>(W_out, WoT, 4096, 2048, 4096, 0);

  gemm_bt_kernel<1><<<dim3(NWP / 128, ROWS / 128), 256, 0, stream>>>(hsb, WT, C1, ROWS, NWP, HIDN);
  conv_silu_kernel<<<ROWS * (CONVD / 4) / 256, 256, 0, stream>>>(C1, conv_w, QKV);
  gbeta_kernel<<<ROWS * NUMV / 256, 256, 0, stream>>>(C1, dt_bias, A_log, Gb, Bb);

  hipFuncSetAttribute((const void*)intra_kernel, hipFuncAttributeMaxDynamicSharedMemorySize,
                      INTRA_SMEM);
  intra_kernel<<<2048, 256, INTRA_SMEM, stream>>>(QKV, Gb, Bb, C1, ATTNb);

  hipFuncSetAttribute((const void*)seq_kernel, hipFuncAttributeMaxDynamicSharedMemorySize,
                      SEQ_SMEM);
  seq_kernel<<<512, 256, SEQ_SMEM, stream>>>(QKV, Gb, C1, ATTNb, COREb);

  gatenorm_kernel<<<ROWS * NUMV / 4, 256, 0, stream>>>(COREb, C1, norm_w, NRMb);
  gemm_bt_kernel<0><<<dim3(2048 / 128, ROWS / 128), 256, 0, stream>>>(NRMb, WoT, out, ROWS, 2048, 4096);
}

// Round 4
// 960.184 us; speedup vs baseline: 3.6648x; 1.0524x over previous
//
#include <hip/hip_runtime.h>
#include <cstdint>
#include <cstddef>

// ---------------------------------------------------------------------------
// GatedDeltaNet forward, MI355X/gfx950.
//  1. cast hs -> bf16 ; transpose weights -> bf16 [N][K]
//  2. GEMM1 (256x256/BK64, 8-phase-style, T1/T2/T4/T5): C1 = hs @ [W_qkv|W_z|W_b|W_a]
//  3. causal conv(K=4)+SiLU -> QKV bf16 ; beta/g
//  4. INTRA (chunk-parallel): A build + solve -> w,u (C1 dead cols), attn
//  5. SEQ: state recurrence, MFMA
//  6. gate + RMS-norm -> NRM bf16 ; GEMM2: out = NRM @ W_out (fp32)
// ---------------------------------------------------------------------------

#define ROWS  4096
#define SEQ   2048
#define HIDN  2048
#define CONVD 8192
#define NWP   12544     // 8192 qkv + 4096 z + 32 b + 32 a + 192 pad (49*256)
#define NUMV  32

using bf16x8 = __attribute__((ext_vector_type(8))) short;
using f32x4v = __attribute__((ext_vector_type(4))) float;

__device__ __forceinline__ float bf2f(unsigned short u) {
  union { unsigned int i; float f; } x; x.i = ((unsigned int)u) << 16; return x.f;
}
__device__ __forceinline__ unsigned short f2bf(float f) {
  union { float f; unsigned int u; } x; x.f = f;
  unsigned int u = x.u;
  unsigned int r = (u + 0x7FFFu + ((u >> 16) & 1u)) >> 16;  // RNE
  return (unsigned short)r;
}

typedef const __attribute__((address_space(1))) unsigned int GU32;
typedef __attribute__((address_space(3))) unsigned int LU32;
__device__ __forceinline__ void gld_lds16(const void* g, void* l) {
  __builtin_amdgcn_global_load_lds((GU32*)g, (LU32*)l, 16, 0, 0);
}

// ---------------------------------------------------------------- cast fp32->bf16
__global__ __launch_bounds__(256) void cast_kernel(const float* __restrict__ in,
                                                   unsigned short* __restrict__ out, int n4) {
  int i = blockIdx.x * 256 + threadIdx.x;
  if (i >= n4) return;
  float4 v = ((const float4*)in)[i];
  ushort4 o;
  o.x = f2bf(v.x); o.y = f2bf(v.y); o.z = f2bf(v.z); o.w = f2bf(v.w);
  ((ushort4*)out)[i] = o;
}

// ------------------------------------------------- transpose W[K][N] -> WT[roff+N][K] bf16
__global__ __launch_bounds__(256) void transpose_kernel(const float* __restrict__ W,
                                                        unsigned short* __restrict__ WT,
                                                        int K, int N, int ld, int roff) {
  __shared__ float tile[64][65];
  const int t = threadIdx.x;
  const int kb = blockIdx.y * 64, nb = blockIdx.x * 64;
  const int r = t >> 2, c0 = (t & 3) * 16;
#pragma unroll
  for (int i = 0; i < 16; ++i) {
    int c = c0 + i;
    float v = 0.f;
    if (nb + c < N) v = W[(size_t)(kb + r) * N + nb + c];
    tile[r][c] = v;
  }
  __syncthreads();
  const int bn = t >> 2;
  if (nb + bn < N) {
#pragma unroll
    for (int i = 0; i < 16; ++i)
      WT[(size_t)(roff + nb + bn) * ld + kb + c0 + i] = f2bf(tile[c0 + i][bn]);
  }
}

// ---------------------------------------------------------------- 256x256 bf16 GEMM (B^T)
// 512 threads = 8 waves (2M x 4N). BK=64. Per-wave C: 128x64 (8x4 frags 16x16x32).
// LDS 128 KiB: 2 buffers x (A[256][64] + B[256][64]) bf16. st_16x32 swizzle.
// Counted vmcnt(8) + raw s_barrier: staged loads stay in flight across barriers.
#define G256_LDS 131072
template <int OUT_BF16>
__global__ __launch_bounds__(512) void gemm256_kernel(const unsigned short* __restrict__ Ag,
                                                      const unsigned short* __restrict__ Bg,
                                                      void* __restrict__ Cg, int M, int N, int K) {
  extern __shared__ char lds[];
  const int t = threadIdx.x;
  const int lane = t & 63, wid = t >> 6;
  const int wm = wid >> 2, wn = wid & 3;
  const int rlo = lane & 15, khi = lane >> 4;

  // T1: bijective XCD swizzle (grids here are multiples of 8)
  const int gx = gridDim.x, nwg = gx * gridDim.y;
  int id = blockIdx.y * gx + blockIdx.x;
  int sid = (id & 7) * (nwg >> 3) + (id >> 3);
  const int m0 = (sid / gx) * 256, n0 = (sid % gx) * 256;

  const int NT = K >> 6;

  // staging source (pre-swizzled global so linear LDS dest + swizzled read match)
  const int srow = t >> 3;
  const int scb = ((t & 7) * 16) ^ (((t >> 5) & 1) << 5);
  const char* Abase = (const char*)Ag + ((size_t)(m0 + srow) * K) * 2 + scb;
  const char* Bbase = (const char*)Bg + ((size_t)(n0 + srow) * K) * 2 + scb;
  const size_t rstride = (size_t)64 * K * 2;
  char* dbase = lds + t * 16;

  // swizzled ds_read byte offsets (within a 32KB tile)
  int offA[8][2], offB[4][2];
#pragma unroll
  for (int mi = 0; mi < 8; ++mi)
#pragma unroll
    for (int ks = 0; ks < 2; ++ks) {
      int o = (wm * 128 + mi * 16 + rlo) * 128 + ks * 64 + khi * 16;
      o ^= ((o >> 9) & 1) << 5;
      offA[mi][ks] = o;
    }
#pragma unroll
  for (int ni = 0; ni < 4; ++ni)
#pragma unroll
    for (int ks = 0; ks < 2; ++ks) {
      int o = (wn * 64 + ni * 16 + rlo) * 128 + ks * 64 + khi * 16;
      o ^= ((o >> 9) & 1) << 5;
      offB[ni][ks] = o + 32768;
    }

  f32x4v acc[8][4];
#pragma unroll
  for (int mi = 0; mi < 8; ++mi)
#pragma unroll
    for (int ni = 0; ni < 4; ++ni) acc[mi][ni] = (f32x4v){0.f, 0.f, 0.f, 0.f};

#define STAGE(KT, P)                                                        \
  do {                                                                      \
    const char* a_ = Abase + (size_t)(KT) * 128;                            \
    const char* b_ = Bbase + (size_t)(KT) * 128;                            \
    char* d_ = dbase + ((P) << 16);                                         \
    gld_lds16(a_, d_);                 gld_lds16(a_ + rstride, d_ + 8192);  \
    gld_lds16(a_ + 2 * rstride, d_ + 16384); gld_lds16(a_ + 3 * rstride, d_ + 24576); \
    gld_lds16(b_, d_ + 32768);         gld_lds16(b_ + rstride, d_ + 40960); \
    gld_lds16(b_ + 2 * rstride, d_ + 49152); gld_lds16(b_ + 3 * rstride, d_ + 57344); \
  } while (0)

  // prologue: stage kt=0 -> buf0, kt=1 -> buf1; wait kt0 (kt1's 8 stay in flight)
  STAGE(0, 0);
  STAGE(1, 1);
  asm volatile("s_waitcnt vmcnt(8)" ::: "memory");
  __builtin_amdgcn_s_barrier();
  __builtin_amdgcn_sched_barrier(0);

  for (int kt = 0; kt < NT; ++kt) {
    const char* base = lds + ((kt & 1) << 16);
#pragma unroll
    for (int ks = 0; ks < 2; ++ks) {
      bf16x8 af[8], bv[4];
#pragma unroll
      for (int mi = 0; mi < 8; ++mi) af[mi] = *(const bf16x8*)(base + offA[mi][ks]);
#pragma unroll
      for (int ni = 0; ni < 4; ++ni) bv[ni] = *(const bf16x8*)(base + offB[ni][ks]);
      __builtin_amdgcn_s_setprio(1);
#pragma unroll
      for (int mi = 0; mi < 8; ++mi)
#pragma unroll
        for (int ni = 0; ni < 4; ++ni)
          acc[mi][ni] = __builtin_amdgcn_mfma_f32_16x16x32_bf16(af[mi], bv[ni], acc[mi][ni], 0, 0, 0);
      __builtin_amdgcn_s_setprio(0);
    }
    if (kt + 1 < NT) {
      __builtin_amdgcn_s_barrier();     // all waves done reading buf[kt&1]
      if (kt + 2 < NT) {
        STAGE(kt + 2, kt & 1);          // re-stage freed buffer
        asm volatile("s_waitcnt vmcnt(8)" ::: "memory");  // kt+1 landed; kt+2 in flight
      } else {
        asm volatile("s_waitcnt vmcnt(0)" ::: "memory");
      }
      __builtin_amdgcn_s_barrier();     // kt+1 resident for every wave
      __builtin_amdgcn_sched_barrier(0);
    }
  }
#undef STAGE

  // epilogue: C/D map col=lane&15 (N), row=4*(lane>>4)+reg (M)
  const int mrb = khi * 4;
#pragma unroll
  for (int mi = 0; mi < 8; ++mi)
#pragma unroll
    for (int ni = 0; ni < 4; ++ni)
#pragma unroll
      for (int r = 0; r < 4; ++r) {
        int mm = m0 + wm * 128 + mi * 16 + mrb + r;
        int nn = n0 + wn * 64 + ni * 16 + rlo;
        float v = acc[mi][ni][r];
        if (OUT_BF16) ((unsigned short*)Cg)[(size_t)mm * N + nn] = f2bf(v);
        else          ((float*)Cg)[(size_t)mm * N + nn] = v;
      }
}

// ---------------------------------------------------------------- causal conv K=4 + SiLU
__global__ __launch_bounds__(256) void conv_silu_kernel(const unsigned short* __restrict__ C1,
                                                        const float* __restrict__ conv_w,
                                                        unsigned short* __restrict__ QKV) {
  int idx = blockIdx.x * 256 + threadIdx.x;
  int row = idx >> 11;
  int c4 = (idx & 2047) << 2;
  int s = row & 2047;
  float4 w0 = *(const float4*)(conv_w + (size_t)(c4 + 0) * 4);
  float4 w1 = *(const float4*)(conv_w + (size_t)(c4 + 1) * 4);
  float4 w2 = *(const float4*)(conv_w + (size_t)(c4 + 2) * 4);
  float4 w3 = *(const float4*)(conv_w + (size_t)(c4 + 3) * 4);
  const float* pw0 = (const float*)&w0;
  const float* pw1 = (const float*)&w1;
  const float* pw2 = (const float*)&w2;
  const float* pw3 = (const float*)&w3;
  float a0 = 0.f, a1 = 0.f, a2 = 0.f, a3 = 0.f;
#pragma unroll
  for (int j = 0; j < 4; ++j) {
    int sr = s - 3 + j;
    if (sr < 0) continue;
    ushort4 mv = *(const ushort4*)(C1 + (size_t)(row - 3 + j) * NWP + c4);
    a0 += bf2f(mv.x) * pw0[j];
    a1 += bf2f(mv.y) * pw1[j];
    a2 += bf2f(mv.z) * pw2[j];
    a3 += bf2f(mv.w) * pw3[j];
  }
  ushort4 o;
  o.x = f2bf(a0 / (1.f + __expf(-a0)));
  o.y = f2bf(a1 / (1.f + __expf(-a1)));
  o.z = f2bf(a2 / (1.f + __expf(-a2)));
  o.w = f2bf(a3 / (1.f + __expf(-a3)));
  *(ushort4*)(QKV + (size_t)row * CONVD + c4) = o;
}

// ---------------------------------------------------------------- beta / g
__global__ __launch_bounds__(256) void gbeta_kernel(const unsigned short* __restrict__ C1,
                                                    const float* __restrict__ dt_bias,
                                                    const float* __restrict__ A_log,
                                                    float* __restrict__ G, float* __restrict__ BETA) {
  int idx = blockIdx.x * 256 + threadIdx.x;
  int row = idx >> 5, h = idx & 31;
  float bp = bf2f(C1[(size_t)row * NWP + 12288 + h]);
  float ap = bf2f(C1[(size_t)row * NWP + 12320 + h]);
  BETA[idx] = 1.f / (1.f + __expf(-bp));
  float x = ap + dt_bias[h];
  float sp = (x > 15.f) ? x : log1pf(__expf(x));
  G[idx] = -__expf(A_log[h]) * sp;
}

// ---------------------------------------------------------------- INTRA: per-chunk solve
#define INTRA_SMEM 70144
__global__ __launch_bounds__(256) void intra_kernel(const unsigned short* __restrict__ QKV,
                                                    const float* __restrict__ G,
                                                    const float* __restrict__ BETA,
                                                    unsigned short* __restrict__ WU,
                                                    unsigned short* __restrict__ ATTN) {
  extern __shared__ char smem[];
  unsigned short* ktb = (unsigned short*)smem;        // [64][136]
  float* Amat = (float*)(smem + 17408);               // [64][68]
  float* Xt   = (float*)(smem + 34816);               // [128][68]
  unsigned short* qb = (unsigned short*)Xt;           // [64][136] alias
  float* gc  = (float*)(smem + 69632);                // [64]
  float* bet = gc + 64;                               // [64]

  const int t = threadIdx.x;
  const int lane = t & 63, w = t >> 6;
  const int rlo = lane & 15, khi = lane >> 4;
  const int cix = blockIdx.x & 31;
  const int h = (blockIdx.x >> 5) & 31;
  const int b = blockIdx.x >> 10;
  const int hq = h >> 1;
  const int row0 = cix * 64;
  const size_t rowbase = (size_t)b * SEQ;

  if (t < 64) {
    float gv = G[(rowbase + row0 + t) * NUMV + h];
    bet[t] = BETA[(rowbase + row0 + t) * NUMV + h];
#pragma unroll
    for (int off = 1; off < 64; off <<= 1) {
      float u = __shfl_up(gv, off, 64);
      if (t >= off) gv += u;
    }
    gc[t] = gv;
  }
  __syncthreads();

  const int r = t >> 2, q4 = t & 3;
  const size_t grow = (rowbase + row0 + r) * (size_t)CONVD;

  {
    const unsigned short* kp = QKV + grow + 2048 + hq * 128 + q4 * 32;
    float kv[32]; float ssk = 0.f;
#pragma unroll
    for (int j = 0; j < 32; j += 4) {
      ushort4 km = *(const ushort4*)(kp + j);
      kv[j] = bf2f(km.x); kv[j + 1] = bf2f(km.y); kv[j + 2] = bf2f(km.z); kv[j + 3] = bf2f(km.w);
      ssk += kv[j]*kv[j] + kv[j+1]*kv[j+1] + kv[j+2]*kv[j+2] + kv[j+3]*kv[j+3];
    }
    ssk += __shfl_xor(ssk, 1, 64);
    ssk += __shfl_xor(ssk, 2, 64);
    const float rk = rsqrtf(ssk + 1e-6f);
    const float ekr = __expf(gc[r]) * bet[r];
#pragma unroll
    for (int j = 0; j < 32; ++j) {
      float kn = kv[j] * rk;
      ktb[r * 136 + q4 * 32 + j] = f2bf(kn);
      Xt[(q4 * 32 + j) * 68 + r] = kn * ekr;
    }
  }
  __syncthreads();

  {
    static const signed char SJ[10][2] = {{0,0},{1,0},{1,1},{2,0},{2,1},{2,2},{3,0},{3,1},{3,2},{3,3}};
    static const signed char SB[5] = {0, 4, 7, 9, 10};
    for (int sj = SB[w]; sj < SB[w + 1]; ++sj) {
      const int mt = SJ[sj][0], nt = SJ[sj][1];
      f32x4v acc = (f32x4v){0.f, 0.f, 0.f, 0.f};
#pragma unroll
      for (int ks = 0; ks < 4; ++ks) {
        bf16x8 af = *(const bf16x8*)&ktb[(mt * 16 + rlo) * 136 + ks * 32 + khi * 8];
        bf16x8 bf_ = *(const bf16x8*)&ktb[(nt * 16 + rlo) * 136 + ks * 32 + khi * 8];
        acc = __builtin_amdgcn_mfma_f32_16x16x32_bf16(af, bf_, acc, 0, 0, 0);
      }
      const int j = nt * 16 + rlo;
#pragma unroll
      for (int r2 = 0; r2 < 4; ++r2) {
        const int i = mt * 16 + khi * 4 + r2;
        if (j < i) Amat[i * 68 + j] = -bet[i] * __expf(gc[i] - gc[j]) * acc[r2];
      }
    }
  }
  __syncthreads();

#pragma unroll 1
  for (int ib = 0; ib < 8; ++ib) {
    const int i0 = ib * 8;
    if (t < 128) {
      float* Xc = Xt + t * 68;
      float p[8] = {0, 0, 0, 0, 0, 0, 0, 0};
      for (int j = 0; j < i0; j += 4) {
        f32x4v xj = *(const f32x4v*)&Xc[j];
#pragma unroll
        for (int r2 = 0; r2 < 8; ++r2) {
          f32x4v ar = *(const f32x4v*)&Amat[(i0 + r2) * 68 + j];
          p[r2] += ar[0] * xj[0] + ar[1] * xj[1] + ar[2] * xj[2] + ar[3] * xj[3];
        }
      }
      float xi[8];
#pragma unroll
      for (int r2 = 0; r2 < 8; ++r2) {
        float v = Xc[i0 + r2] + p[r2];
#pragma unroll
        for (int r3 = 0; r3 < r2; ++r3) v += Amat[(i0 + r2) * 68 + i0 + r3] * xi[r3];
        xi[r2] = v;
        Xc[i0 + r2] = v;
      }
    }
    __syncthreads();
  }

  {
    unsigned short* wdst = WU + (rowbase + row0 + r) * (size_t)NWP + h * 128 + q4 * 32;
#pragma unroll
    for (int j = 0; j < 32; ++j) wdst[j] = f2bf(Xt[(q4 * 32 + j) * 68 + r]);
    const unsigned short* vp = QKV + grow + 4096 + h * 128 + q4 * 32;
    const float brow = bet[r];
#pragma unroll
    for (int j = 0; j < 32; j += 4) {
      ushort4 vm = *(const ushort4*)(vp + j);
      Xt[(q4 * 32 + j + 0) * 68 + r] = bf2f(vm.x) * brow;
      Xt[(q4 * 32 + j + 1) * 68 + r] = bf2f(vm.y) * brow;
      Xt[(q4 * 32 + j + 2) * 68 + r] = bf2f(vm.z) * brow;
      Xt[(q4 * 32 + j + 3) * 68 + r] = bf2f(vm.w) * brow;
    }
  }
  __syncthreads();

#pragma unroll 1
  for (int ib = 0; ib < 8; ++ib) {
    const int i0 = ib * 8;
    if (t < 128) {
      float* Xc = Xt + t * 68;
      float p[8] = {0, 0, 0, 0, 0, 0, 0, 0};
      for (int j = 0; j < i0; j += 4) {
        f32x4v xj = *(const f32x4v*)&Xc[j];
#pragma unroll
        for (int r2 = 0; r2 < 8; ++r2) {
          f32x4v ar = *(const f32x4v*)&Amat[(i0 + r2) * 68 + j];
          p[r2] += ar[0] * xj[0] + ar[1] * xj[1] + ar[2] * xj[2] + ar[3] * xj[3];
        }
      }
      float xi[8];
#pragma unroll
      for (int r2 = 0; r2 < 8; ++r2) {
        float v = Xc[i0 + r2] + p[r2];
#pragma unroll
        for (int r3 = 0; r3 < r2; ++r3) v += Amat[(i0 + r2) * 68 + i0 + r3] * xi[r3];
        xi[r2] = v;
        Xc[i0 + r2] = v;
      }
    }
    __syncthreads();
  }

  {
    unsigned short* udst = WU + (rowbase + row0 + r) * (size_t)NWP + 4096 + h * 128 + q4 * 32;
#pragma unroll
    for (int j = 0; j < 32; ++j) udst[j] = f2bf(Xt[(q4 * 32 + j) * 68 + r]);
  }
  __syncthreads();

  {
    const unsigned short* qp = QKV + grow + hq * 128 + q4 * 32;
    float qv[32]; float ssq = 0.f;
#pragma unroll
    for (int j = 0; j < 32; j += 4) {
      ushort4 qm = *(const ushort4*)(qp + j);
      qv[j] = bf2f(qm.x); qv[j + 1] = bf2f(qm.y); qv[j + 2] = bf2f(qm.z); qv[j + 3] = bf2f(qm.w);
      ssq += qv[j]*qv[j] + qv[j+1]*qv[j+1] + qv[j+2]*qv[j+2] + qv[j+3]*qv[j+3];
    }
    ssq += __shfl_xor(ssq, 1, 64);
    ssq += __shfl_xor(ssq, 2, 64);
    const float rq = rsqrtf(ssq + 1e-6f) * 0.08838834764831845f;
#pragma unroll
    for (int j = 0; j < 32; ++j) qb[r * 136 + q4 * 32 + j] = f2bf(qv[j] * rq);
  }
  __syncthreads();

  {
    const size_t abase = (((size_t)b * 32 + h) * 32 + cix) * 4096;
#pragma unroll 1
    for (int nt = 0; nt < 4; ++nt) {
      const int j = nt * 16 + rlo;
      float vals[4] = {0.f, 0.f, 0.f, 0.f};
      if (nt <= w) {
        f32x4v acc = (f32x4v){0.f, 0.f, 0.f, 0.f};
#pragma unroll
        for (int ks = 0; ks < 4; ++ks) {
          bf16x8 af = *(const bf16x8*)&qb[(w * 16 + rlo) * 136 + ks * 32 + khi * 8];
          bf16x8 bf_ = *(const bf16x8*)&ktb[(nt * 16 + rlo) * 136 + ks * 32 + khi * 8];
          acc = __builtin_amdgcn_mfma_f32_16x16x32_bf16(af, bf_, acc, 0, 0, 0);
        }
#pragma unroll
        for (int r2 = 0; r2 < 4; ++r2) {
          const int i = w * 16 + khi * 4 + r2;
          if (j <= i) vals[r2] = __expf(gc[i] - gc[j]) * acc[r2];
        }
      }
#pragma unroll
      for (int r2 = 0; r2 < 4; ++r2)
        ATTN[abase + (w * 16 + khi * 4 + r2) * 64 + j] = f2bf(vals[r2]);
    }
  }
}

// ---------------------------------------------------------------- SEQ: state recurrence
#define SEQ_SMEM 70400
__global__ __launch_bounds__(256) void seq_kernel(const unsigned short* __restrict__ QKV,
                                                  const float* __restrict__ G,
                                                  const unsigned short* __restrict__ WU,
                                                  const unsigned short* __restrict__ ATTN,
                                                  unsigned short* __restrict__ CORE) {
  extern __shared__ char smem[];
  unsigned short* ktT    = (unsigned short*)smem;            // [128][88]
  unsigned short* wb     = (unsigned short*)(smem + 22528);  // [64][136]
  unsigned short* attnb  = (unsigned short*)(smem + 39936);  // [64][88]
  float* stateT          = (float*)(smem + 51200);           // [16][136]
  unsigned short* stateTb = (unsigned short*)(smem + 59904); // [16][136]
  unsigned short* vnTb   = (unsigned short*)(smem + 64256);  // [16][88]
  unsigned short* vdTb   = (unsigned short*)(smem + 67072);  // [16][88]
  float* gc   = (float*)(smem + 69888);                      // [64]
  float* edec = (float*)(smem + 70144);                      // [64]

  const int t = threadIdx.x;
  const int lane = t & 63, w = t >> 6;
  const int rlo = lane & 15, khi = lane >> 4;
  const int vq = blockIdx.x & 7;
  const int h = (blockIdx.x >> 3) & 31;
  const int b = blockIdx.x >> 8;
  const int hq = h >> 1;
  const size_t rowbase = (size_t)b * SEQ;
  const size_t ahead = ((size_t)b * 32 + h) * 32;

  for (int i = t; i < 16 * 136; i += 256) { stateT[i] = 0.f; stateTb[i] = 0; }
  __syncthreads();

  bf16x8 qf[4];

#pragma unroll 1
  for (int ncb = 0; ncb < 32; ++ncb) {
    const int row0 = ncb * 64;

    if (t < 64) {
      float gv = G[(rowbase + row0 + t) * NUMV + h];
#pragma unroll
      for (int off = 1; off < 64; off <<= 1) {
        float u = __shfl_up(gv, off, 64);
        if (t >= off) gv += u;
      }
      gc[t] = gv;
      float tot = __shfl(gv, 63, 64);
      edec[t] = __expf(tot - gv);
    }
    __syncthreads();

    {
      const int r = t >> 2, q4 = t & 3;
      const size_t grow = (rowbase + row0 + r) * (size_t)CONVD;
      const unsigned short* kp = QKV + grow + 2048 + hq * 128 + q4 * 32;
      float kv[32]; float ssk = 0.f;
#pragma unroll
      for (int j = 0; j < 32; j += 4) {
        ushort4 km = *(const ushort4*)(kp + j);
        kv[j] = bf2f(km.x); kv[j + 1] = bf2f(km.y); kv[j + 2] = bf2f(km.z); kv[j + 3] = bf2f(km.w);
        ssk += kv[j]*kv[j] + kv[j+1]*kv[j+1] + kv[j+2]*kv[j+2] + kv[j+3]*kv[j+3];
      }
      ssk += __shfl_xor(ssk, 1, 64);
      ssk += __shfl_xor(ssk, 2, 64);
      const float rk = rsqrtf(ssk + 1e-6f);
#pragma unroll
      for (int j = 0; j < 32; ++j) ktT[(q4 * 32 + j) * 88 + r] = f2bf(kv[j] * rk);
      const unsigned short* wsrc = WU + (rowbase + row0 + r) * (size_t)NWP + h * 128 + q4 * 32;
#pragma unroll
      for (int u2 = 0; u2 < 4; ++u2)
        *(uint4*)&wb[r * 136 + q4 * 32 + u2 * 8] = *(const uint4*)(wsrc + u2 * 8);
      const unsigned short* asrc = ATTN + (ahead + ncb) * 4096 + r * 64 + q4 * 16;
      *(uint4*)&attnb[r * 88 + q4 * 16] = *(const uint4*)(asrc);
      *(uint4*)&attnb[r * 88 + q4 * 16 + 8] = *(const uint4*)(asrc + 8);
      const unsigned short* qsrc = QKV + (rowbase + row0 + w * 16 + rlo) * (size_t)CONVD + hq * 128 + khi * 8;
      float qv[32]; float ssq = 0.f;
#pragma unroll
      for (int ks = 0; ks < 4; ++ks) {
        ushort4 qa = *(const ushort4*)(qsrc + ks * 32);
        ushort4 qb2 = *(const ushort4*)(qsrc + ks * 32 + 4);
        qv[ks*8+0] = bf2f(qa.x); qv[ks*8+1] = bf2f(qa.y); qv[ks*8+2] = bf2f(qa.z); qv[ks*8+3] = bf2f(qa.w);
        qv[ks*8+4] = bf2f(qb2.x); qv[ks*8+5] = bf2f(qb2.y); qv[ks*8+6] = bf2f(qb2.z); qv[ks*8+7] = bf2f(qb2.w);
#pragma unroll
        for (int e = 0; e < 8; ++e) ssq += qv[ks*8+e] * qv[ks*8+e];
      }
      ssq += __shfl_xor(ssq, 16, 64);
      ssq += __shfl_xor(ssq, 32, 64);
      const float rq = rsqrtf(ssq + 1e-6f) * 0.08838834764831845f;
#pragma unroll
      for (int ks = 0; ks < 4; ++ks) {
        bf16x8 tv;
#pragma unroll
        for (int e = 0; e < 8; ++e) tv[e] = (short)f2bf(qv[ks*8+e] * rq);
        qf[ks] = tv;
      }
    }
    __syncthreads();

    f32x4v oacc;
    {
      f32x4v pacc = (f32x4v){0.f, 0.f, 0.f, 0.f};
      oacc = (f32x4v){0.f, 0.f, 0.f, 0.f};
#pragma unroll
      for (int ks = 0; ks < 4; ++ks) {
        bf16x8 aw = *(const bf16x8*)&wb[(w * 16 + rlo) * 136 + ks * 32 + khi * 8];
        bf16x8 bs = *(const bf16x8*)&stateTb[rlo * 136 + ks * 32 + khi * 8];
        pacc = __builtin_amdgcn_mfma_f32_16x16x32_bf16(aw, bs, pacc, 0, 0, 0);
        oacc = __builtin_amdgcn_mfma_f32_16x16x32_bf16(qf[ks], bs, oacc, 0, 0, 0);
      }
#pragma unroll
      for (int r2 = 0; r2 < 4; ++r2) {
        const int i = w * 16 + khi * 4 + r2;
        float uv = bf2f(WU[(rowbase + row0 + i) * (size_t)NWP + 4096 + h * 128 + vq * 16 + rlo]);
        float vn = uv - pacc[r2];
        vnTb[rlo * 88 + i] = f2bf(vn);
        vdTb[rlo * 88 + i] = f2bf(vn * edec[i]);
        oacc[r2] *= __expf(gc[i]);
      }
    }
    __syncthreads();

    {
#pragma unroll
      for (int ks = 0; ks < 2; ++ks) {
        bf16x8 aa = *(const bf16x8*)&attnb[(w * 16 + rlo) * 88 + ks * 32 + khi * 8];
        bf16x8 bv = *(const bf16x8*)&vnTb[rlo * 88 + ks * 32 + khi * 8];
        oacc = __builtin_amdgcn_mfma_f32_16x16x32_bf16(aa, bv, oacc, 0, 0, 0);
      }
      const int col = h * 128 + vq * 16 + rlo;
#pragma unroll
      for (int r2 = 0; r2 < 4; ++r2) {
        const int i = w * 16 + khi * 4 + r2;
        CORE[(rowbase + row0 + i) * (size_t)4096 + col] = f2bf(oacc[r2]);
      }
      const float egl = __expf(gc[63]);
#pragma unroll
      for (int n2 = 0; n2 < 2; ++n2) {
        const int dt = w * 2 + n2;
        f32x4v sacc = (f32x4v){0.f, 0.f, 0.f, 0.f};
#pragma unroll
        for (int ks = 0; ks < 2; ++ks) {
          bf16x8 ak = *(const bf16x8*)&ktT[(dt * 16 + rlo) * 88 + ks * 32 + khi * 8];
          bf16x8 bv2 = *(const bf16x8*)&vdTb[rlo * 88 + ks * 32 + khi * 8];
          sacc = __builtin_amdgcn_mfma_f32_16x16x32_bf16(ak, bv2, sacc, 0, 0, 0);
        }
#pragma unroll
        for (int r2 = 0; r2 < 4; ++r2) {
          const int d = dt * 16 + khi * 4 + r2;
          float ns = stateT[rlo * 136 + d] * egl + sacc[r2];
          stateT[rlo * 136 + d] = ns;
          stateTb[rlo * 136 + d] = f2bf(ns);
        }
      }
    }
    __syncthreads();
  }
}

// ---------------------------------------------------------------- gate * silu(z) + RMS-norm
__global__ __launch_bounds__(256) void gatenorm_kernel(const unsigned short* __restrict__ CORE,
                                                       const unsigned short* __restrict__ C1,
                                                       const float* __restrict__ norm_w,
                                                       unsigned short* __restrict__ NRM) {
  const int wid = blockIdx.x * 4 + (threadIdx.x >> 6);
  const int lane = threadIdx.x & 63;
  const int row = wid >> 5, h = wid & 31;
  const int c = lane * 2;
  const size_t cidx = (size_t)row * 4096 + h * 128 + c;
  const size_t zidx = (size_t)row * NWP + 8192 + h * 128 + c;
  float g0 = bf2f(CORE[cidx]), g1 = bf2f(CORE[cidx + 1]);
  float z0 = bf2f(C1[zidx]), z1 = bf2f(C1[zidx + 1]);
  g0 *= z0 / (1.f + __expf(-z0));
  g1 *= z1 / (1.f + __expf(-z1));
  float ss = g0 * g0 + g1 * g1;
#pragma unroll
  for (int m = 1; m < 64; m <<= 1) ss += __shfl_xor(ss, m, 64);
  const float rr = rsqrtf(ss * (1.f / 128.f) + 1e-6f);
  unsigned int o = ((unsigned int)f2bf(g1 * rr * norm_w[c + 1]) << 16) | (unsigned int)f2bf(g0 * rr * norm_w[c]);
  *(unsigned int*)(NRM + cidx) = o;
}

// ---------------------------------------------------------------------------
extern "C" void kernel_launch(void* const* d_in, const int* in_sizes, int n_in,
                              void* d_out, int out_size, void* d_ws, size_t ws_size,
                              hipStream_t stream) {
  const float* hs      = (const float*)d_in[0];
  const float* W_qkv   = (const float*)d_in[1];
  const float* W_z     = (const float*)d_in[2];
  const float* W_b     = (const float*)d_in[3];
  const float* W_a     = (const float*)d_in[4];
  const float* conv_w  = (const float*)d_in[5];
  const float* dt_bias = (const float*)d_in[6];
  const float* A_log   = (const float*)d_in[7];
  const float* norm_w  = (const float*)d_in[8];
  const float* W_out   = (const float*)d_in[9];
  float* out = (float*)d_out;
  char* ws = (char*)d_ws;

  const size_t OFF_HSB = 0;                                     // hs bf16; later ATTN (16.78MB exact)
  const size_t OFF_WT  = OFF_HSB + (size_t)ROWS * HIDN * 2;     // WT; later CORE
  const size_t OFF_WOT = OFF_WT + (size_t)NWP * HIDN * 2;
  const size_t OFF_C1  = OFF_WOT + (size_t)HIDN * 4096 * 2;     // C1; cols [0,8192) -> w,u after conv
  const size_t OFF_QKV = OFF_C1 + (size_t)ROWS * NWP * 2;       // QKV; later NRM
  const size_t OFF_G   = OFF_QKV + (size_t)ROWS * CONVD * 2;
  const size_t OFF_B   = OFF_G + (size_t)ROWS * NUMV * 4;

  unsigned short* hsb = (unsigned short*)(ws + OFF_HSB);
  unsigned short* WT  = (unsigned short*)(ws + OFF_WT);
  unsigned short* WoT = (unsigned short*)(ws + OFF_WOT);
  unsigned short* C1  = (unsigned short*)(ws + OFF_C1);
  unsigned short* QKV = (unsigned short*)(ws + OFF_QKV);
  float* Gb = (float*)(ws + OFF_G);
  float* Bb = (float*)(ws + OFF_B);
  unsigned short* ATTNb = (unsigned short*)(ws + OFF_HSB);
  unsigned short* COREb = (unsigned short*)(ws + OFF_WT);
  unsigned short* NRMb  = (unsigned short*)(ws + OFF_QKV);

  cast_kernel<<<ROWS * HIDN / 4 / 256, 256, 0, stream>>>(hs, hsb, ROWS * HIDN / 4);
  transpose_kernel<<<dim3(8192 / 64, 2048 / 64), 256, 0, stream>>>(W_qkv, WT, 2048, 8192, HIDN, 0);
  transpose_kernel<<<dim3(4096 / 64, 2048 / 64), 256, 0, stream>>>(W_z, WT, 2048, 4096, HIDN, 8192);
  transpose_kernel<<<dim3(1, 2048 / 64), 256, 0, stream>>>(W_b, WT, 2048, 32, HIDN, 12288);
  transpose_kernel<<<dim3(1, 2048 / 64), 256, 0, stream>>>(W_a, WT, 2048, 32, HIDN, 12320);
  hipMemsetAsync(ws + OFF_WT + (size_t)12352 * HIDN * 2, 0, (size_t)192 * HIDN * 2, stream);
  transpose_kernel<<<dim3(2048 / 64, 4096 / 64), 256, 0, stream>>>(W_out, WoT, 4096, 2048, 4096, 0);

  void (*g1p)(const unsigned short*, const unsigned short*, void*, int, int, int) = gemm256_kernel<1>;
  void (*g0p)(const unsigned short*, const unsigned short*, void*, int, int, int) = gemm256_kernel<0>;
  hipFuncSetAttribute((const void*)g1p, hipFuncAttributeMaxDynamicSharedMemorySize, G256_LDS);
  hipFuncSetAttribute((const void*)g0p, hipFuncAttributeMaxDynamicSharedMemorySize, G256_LDS);

  gemm256_kernel<1><<<dim3(NWP / 256, ROWS / 256), 512, G256_LDS, stream>>>(hsb, WT, C1, ROWS, NWP, HIDN);
  conv_silu_kernel<<<ROWS * (CONVD / 4) / 256, 256, 0, stream>>>(C1, conv_w, QKV);
  gbeta_kernel<<<ROWS * NUMV / 256, 256, 0, stream>>>(C1, dt_bias, A_log, Gb, Bb);

  hipFuncSetAttribute((const void*)intra_kernel, hipFuncAttributeMaxDynamicSharedMemorySize,
                      INTRA_SMEM);
  intra_kernel<<<2048, 256, INTRA_SMEM, stream>>>(QKV, Gb, Bb, C1, ATTNb);

  hipFuncSetAttribute((const void*)seq_kernel, hipFuncAttributeMaxDynamicSharedMemorySize,
                      SEQ_SMEM);
  seq_kernel<<<512, 256, SEQ_SMEM, stream>>>(QKV, Gb, C1, ATTNb, COREb);

  gatenorm_kernel<<<ROWS * NUMV / 4, 256, 0, stream>>>(COREb, C1, norm_w, NRMb);
  gemm256_kernel<0><<<dim3(2048 / 256, ROWS / 256), 512, G256_LDS, stream>>>(NRMb, WoT, out, ROWS, 2048, 4096);
}

// Round 5
// 941.535 us; speedup vs baseline: 3.7374x; 1.0198x over previous
//
#include <hip/hip_runtime.h>
#include <cstdint>
#include <cstddef>

// ---------------------------------------------------------------------------
// GatedDeltaNet forward, MI355X/gfx950.
//  1. cast hs -> bf16 ; transpose weights -> bf16 [N][K]
//  2. GEMM1 (256x256/BK64, counted-vmcnt pipeline, T1/T2/T4/T5): C1 = hs @ [W_qkv|W_z|W_b|W_a]
//  3. causal conv(K=4)+SiLU -> QKV bf16 ; beta/g
//  4. INTRA (chunk-parallel): A build + solve -> w,u (C1 dead cols), attn
//  5. SEQ: state recurrence, MFMA
//  6. gate + RMS-norm -> NRM bf16 ; GEMM2: out = NRM @ W_out (fp32)
// ---------------------------------------------------------------------------

#define ROWS  4096
#define SEQ   2048
#define HIDN  2048
#define CONVD 8192
#define NWP   12544     // 8192 qkv + 4096 z + 32 b + 32 a + 192 pad (49*256)
#define NUMV  32

using bf16x8 = __attribute__((ext_vector_type(8))) short;
using f32x4v = __attribute__((ext_vector_type(4))) float;

__device__ __forceinline__ float bf2f(unsigned short u) {
  union { unsigned int i; float f; } x; x.i = ((unsigned int)u) << 16; return x.f;
}
__device__ __forceinline__ unsigned short f2bf(float f) {
  union { float f; unsigned int u; } x; x.f = f;
  unsigned int u = x.u;
  unsigned int r = (u + 0x7FFFu + ((u >> 16) & 1u)) >> 16;  // RNE
  return (unsigned short)r;
}

typedef const __attribute__((address_space(1))) unsigned int GU32;
typedef __attribute__((address_space(3))) unsigned int LU32;
__device__ __forceinline__ void gld_lds16(const void* g, void* l) {
  __builtin_amdgcn_global_load_lds((GU32*)g, (LU32*)l, 16, 0, 0);
}

// ---------------------------------------------------------------- cast fp32->bf16
__global__ __launch_bounds__(256) void cast_kernel(const float* __restrict__ in,
                                                   unsigned short* __restrict__ out, int n4) {
  int i = blockIdx.x * 256 + threadIdx.x;
  if (i >= n4) return;
  float4 v = ((const float4*)in)[i];
  ushort4 o;
  o.x = f2bf(v.x); o.y = f2bf(v.y); o.z = f2bf(v.z); o.w = f2bf(v.w);
  ((ushort4*)out)[i] = o;
}

// ------------------------------------------------- transpose W[K][N] -> WT[roff+N][K] bf16
__global__ __launch_bounds__(256) void transpose_kernel(const float* __restrict__ W,
                                                        unsigned short* __restrict__ WT,
                                                        int K, int N, int ld, int roff) {
  __shared__ float tile[64][65];
  const int t = threadIdx.x;
  const int kb = blockIdx.y * 64, nb = blockIdx.x * 64;
  const int r = t >> 2, c0 = (t & 3) * 16;
#pragma unroll
  for (int i = 0; i < 16; ++i) {
    int c = c0 + i;
    float v = 0.f;
    if (nb + c < N) v = W[(size_t)(kb + r) * N + nb + c];
    tile[r][c] = v;
  }
  __syncthreads();
  const int bn = t >> 2;
  if (nb + bn < N) {
#pragma unroll
    for (int i = 0; i < 16; ++i)
      WT[(size_t)(roff + nb + bn) * ld + kb + c0 + i] = f2bf(tile[c0 + i][bn]);
  }
}

// ---------------------------------------------------------------- 256x256 bf16 GEMM (B^T)
// 512 threads = 8 waves (2M x 4N). BK=64. Per-wave C: 128x64 (8x4 frags 16x16x32).
// LDS 128 KiB: 2 buffers x (A[256][64] + B[256][64]) bf16.
// T2 swizzle: byte ^= ((byte>>7)&7)<<4  (row&7 -> 16B-slot bits; 16B reads @128B stride
// become 2 lanes/bank = free). Staging keeps LDS dest linear, pre-swizzles global source
// with the same involution (rule #21). Counted vmcnt(8) + raw s_barrier pipeline.
#define G256_LDS 131072
template <int OUT_BF16>
__global__ __launch_bounds__(512) void gemm256_kernel(const unsigned short* __restrict__ Ag,
                                                      const unsigned short* __restrict__ Bg,
                                                      void* __restrict__ Cg, int M, int N, int K) {
  extern __shared__ char lds[];
  const int t = threadIdx.x;
  const int lane = t & 63, wid = t >> 6;
  const int wm = wid >> 2, wn = wid & 3;
  const int rlo = lane & 15, khi = lane >> 4;

  // T1: bijective XCD swizzle (grids here are multiples of 8)
  const int gx = gridDim.x, nwg = gx * gridDim.y;
  int id = blockIdx.y * gx + blockIdx.x;
  int sid = (id & 7) * (nwg >> 3) + (id >> 3);
  const int m0 = (sid / gx) * 256, n0 = (sid % gx) * 256;

  const int NT = K >> 6;

  // staging source: row = t>>3, col byte = ((t&7)*16) ^ ((row&7)<<4)  [pre-swizzled]
  const int srow = t >> 3;
  const int scb = ((t & 7) * 16) ^ (((t >> 3) & 7) << 4);
  const char* Abase = (const char*)Ag + ((size_t)(m0 + srow) * K) * 2 + scb;
  const char* Bbase = (const char*)Bg + ((size_t)(n0 + srow) * K) * 2 + scb;
  const size_t rstride = (size_t)64 * K * 2;
  char* dbase = lds + t * 16;

  // swizzled ds_read byte offsets (within a 32KB tile-half)
  int offA[8][2], offB[4][2];
#pragma unroll
  for (int mi = 0; mi < 8; ++mi)
#pragma unroll
    for (int ks = 0; ks < 2; ++ks) {
      int o = (wm * 128 + mi * 16 + rlo) * 128 + ks * 64 + khi * 16;
      o ^= ((o >> 7) & 7) << 4;
      offA[mi][ks] = o;
    }
#pragma unroll
  for (int ni = 0; ni < 4; ++ni)
#pragma unroll
    for (int ks = 0; ks < 2; ++ks) {
      int o = (wn * 64 + ni * 16 + rlo) * 128 + ks * 64 + khi * 16;
      o ^= ((o >> 7) & 7) << 4;
      offB[ni][ks] = o + 32768;
    }

  f32x4v acc[8][4];
#pragma unroll
  for (int mi = 0; mi < 8; ++mi)
#pragma unroll
    for (int ni = 0; ni < 4; ++ni) acc[mi][ni] = (f32x4v){0.f, 0.f, 0.f, 0.f};

#define STAGE(KT, P)                                                        \
  do {                                                                      \
    const char* a_ = Abase + (size_t)(KT) * 128;                            \
    const char* b_ = Bbase + (size_t)(KT) * 128;                            \
    char* d_ = dbase + ((P) << 16);                                         \
    gld_lds16(a_, d_);                 gld_lds16(a_ + rstride, d_ + 8192);  \
    gld_lds16(a_ + 2 * rstride, d_ + 16384); gld_lds16(a_ + 3 * rstride, d_ + 24576); \
    gld_lds16(b_, d_ + 32768);         gld_lds16(b_ + rstride, d_ + 40960); \
    gld_lds16(b_ + 2 * rstride, d_ + 49152); gld_lds16(b_ + 3 * rstride, d_ + 57344); \
  } while (0)

  // prologue: stage kt=0 -> buf0, kt=1 -> buf1; wait kt0 (kt1's 8 stay in flight)
  STAGE(0, 0);
  STAGE(1, 1);
  asm volatile("s_waitcnt vmcnt(8)" ::: "memory");
  __builtin_amdgcn_s_barrier();
  __builtin_amdgcn_sched_barrier(0);

  for (int kt = 0; kt < NT; ++kt) {
    const char* base = lds + ((kt & 1) << 16);
#pragma unroll
    for (int ks = 0; ks < 2; ++ks) {
      bf16x8 af[8], bv[4];
#pragma unroll
      for (int mi = 0; mi < 8; ++mi) af[mi] = *(const bf16x8*)(base + offA[mi][ks]);
#pragma unroll
      for (int ni = 0; ni < 4; ++ni) bv[ni] = *(const bf16x8*)(base + offB[ni][ks]);
      __builtin_amdgcn_s_setprio(1);
#pragma unroll
      for (int mi = 0; mi < 8; ++mi)
#pragma unroll
        for (int ni = 0; ni < 4; ++ni)
          acc[mi][ni] = __builtin_amdgcn_mfma_f32_16x16x32_bf16(af[mi], bv[ni], acc[mi][ni], 0, 0, 0);
      __builtin_amdgcn_s_setprio(0);
    }
    if (kt + 1 < NT) {
      __builtin_amdgcn_s_barrier();     // all waves done reading buf[kt&1]
      if (kt + 2 < NT) {
        STAGE(kt + 2, kt & 1);          // re-stage freed buffer
        asm volatile("s_waitcnt vmcnt(8)" ::: "memory");  // kt+1 landed; kt+2 in flight
      } else {
        asm volatile("s_waitcnt vmcnt(0)" ::: "memory");
      }
      __builtin_amdgcn_s_barrier();     // kt+1 resident for every wave
      __builtin_amdgcn_sched_barrier(0);
    }
  }
#undef STAGE

  // epilogue: C/D map col=lane&15 (N), row=4*(lane>>4)+reg (M)
  const int mrb = khi * 4;
#pragma unroll
  for (int mi = 0; mi < 8; ++mi)
#pragma unroll
    for (int ni = 0; ni < 4; ++ni)
#pragma unroll
      for (int r = 0; r < 4; ++r) {
        int mm = m0 + wm * 128 + mi * 16 + mrb + r;
        int nn = n0 + wn * 64 + ni * 16 + rlo;
        float v = acc[mi][ni][r];
        if (OUT_BF16) ((unsigned short*)Cg)[(size_t)mm * N + nn] = f2bf(v);
        else          ((float*)Cg)[(size_t)mm * N + nn] = v;
      }
}

// ---------------------------------------------------------------- causal conv K=4 + SiLU
__global__ __launch_bounds__(256) void conv_silu_kernel(const unsigned short* __restrict__ C1,
                                                        const float* __restrict__ conv_w,
                                                        unsigned short* __restrict__ QKV) {
  int idx = blockIdx.x * 256 + threadIdx.x;
  int row = idx >> 11;
  int c4 = (idx & 2047) << 2;
  int s = row & 2047;
  float4 w0 = *(const float4*)(conv_w + (size_t)(c4 + 0) * 4);
  float4 w1 = *(const float4*)(conv_w + (size_t)(c4 + 1) * 4);
  float4 w2 = *(const float4*)(conv_w + (size_t)(c4 + 2) * 4);
  float4 w3 = *(const float4*)(conv_w + (size_t)(c4 + 3) * 4);
  const float* pw0 = (const float*)&w0;
  const float* pw1 = (const float*)&w1;
  const float* pw2 = (const float*)&w2;
  const float* pw3 = (const float*)&w3;
  float a0 = 0.f, a1 = 0.f, a2 = 0.f, a3 = 0.f;
#pragma unroll
  for (int j = 0; j < 4; ++j) {
    int sr = s - 3 + j;
    if (sr < 0) continue;
    ushort4 mv = *(const ushort4*)(C1 + (size_t)(row - 3 + j) * NWP + c4);
    a0 += bf2f(mv.x) * pw0[j];
    a1 += bf2f(mv.y) * pw1[j];
    a2 += bf2f(mv.z) * pw2[j];
    a3 += bf2f(mv.w) * pw3[j];
  }
  ushort4 o;
  o.x = f2bf(a0 / (1.f + __expf(-a0)));
  o.y = f2bf(a1 / (1.f + __expf(-a1)));
  o.z = f2bf(a2 / (1.f + __expf(-a2)));
  o.w = f2bf(a3 / (1.f + __expf(-a3)));
  *(ushort4*)(QKV + (size_t)row * CONVD + c4) = o;
}

// ---------------------------------------------------------------- beta / g
__global__ __launch_bounds__(256) void gbeta_kernel(const unsigned short* __restrict__ C1,
                                                    const float* __restrict__ dt_bias,
                                                    const float* __restrict__ A_log,
                                                    float* __restrict__ G, float* __restrict__ BETA) {
  int idx = blockIdx.x * 256 + threadIdx.x;
  int row = idx >> 5, h = idx & 31;
  float bp = bf2f(C1[(size_t)row * NWP + 12288 + h]);
  float ap = bf2f(C1[(size_t)row * NWP + 12320 + h]);
  BETA[idx] = 1.f / (1.f + __expf(-bp));
  float x = ap + dt_bias[h];
  float sp = (x > 15.f) ? x : log1pf(__expf(x));
  G[idx] = -__expf(A_log[h]) * sp;
}

// ---------------------------------------------------------------- INTRA: per-chunk solve
#define INTRA_SMEM 70144
__global__ __launch_bounds__(256) void intra_kernel(const unsigned short* __restrict__ QKV,
                                                    const float* __restrict__ G,
                                                    const float* __restrict__ BETA,
                                                    unsigned short* __restrict__ WU,
                                                    unsigned short* __restrict__ ATTN) {
  extern __shared__ char smem[];
  unsigned short* ktb = (unsigned short*)smem;        // [64][136]
  float* Amat = (float*)(smem + 17408);               // [64][68]
  float* Xt   = (float*)(smem + 34816);               // [128][68]
  unsigned short* qb = (unsigned short*)Xt;           // [64][136] alias
  float* gc  = (float*)(smem + 69632);                // [64]
  float* bet = gc + 64;                               // [64]

  const int t = threadIdx.x;
  const int lane = t & 63, w = t >> 6;
  const int rlo = lane & 15, khi = lane >> 4;
  const int cix = blockIdx.x & 31;
  const int h = (blockIdx.x >> 5) & 31;
  const int b = blockIdx.x >> 10;
  const int hq = h >> 1;
  const int row0 = cix * 64;
  const size_t rowbase = (size_t)b * SEQ;

  if (t < 64) {
    float gv = G[(rowbase + row0 + t) * NUMV + h];
    bet[t] = BETA[(rowbase + row0 + t) * NUMV + h];
#pragma unroll
    for (int off = 1; off < 64; off <<= 1) {
      float u = __shfl_up(gv, off, 64);
      if (t >= off) gv += u;
    }
    gc[t] = gv;
  }
  __syncthreads();

  const int r = t >> 2, q4 = t & 3;
  const size_t grow = (rowbase + row0 + r) * (size_t)CONVD;

  {
    const unsigned short* kp = QKV + grow + 2048 + hq * 128 + q4 * 32;
    float kv[32]; float ssk = 0.f;
#pragma unroll
    for (int j = 0; j < 32; j += 4) {
      ushort4 km = *(const ushort4*)(kp + j);
      kv[j] = bf2f(km.x); kv[j + 1] = bf2f(km.y); kv[j + 2] = bf2f(km.z); kv[j + 3] = bf2f(km.w);
      ssk += kv[j]*kv[j] + kv[j+1]*kv[j+1] + kv[j+2]*kv[j+2] + kv[j+3]*kv[j+3];
    }
    ssk += __shfl_xor(ssk, 1, 64);
    ssk += __shfl_xor(ssk, 2, 64);
    const float rk = rsqrtf(ssk + 1e-6f);
    const float ekr = __expf(gc[r]) * bet[r];
#pragma unroll
    for (int j = 0; j < 32; ++j) {
      float kn = kv[j] * rk;
      ktb[r * 136 + q4 * 32 + j] = f2bf(kn);
      Xt[(q4 * 32 + j) * 68 + r] = kn * ekr;
    }
  }
  __syncthreads();

  {
    static const signed char SJ[10][2] = {{0,0},{1,0},{1,1},{2,0},{2,1},{2,2},{3,0},{3,1},{3,2},{3,3}};
    static const signed char SB[5] = {0, 4, 7, 9, 10};
    for (int sj = SB[w]; sj < SB[w + 1]; ++sj) {
      const int mt = SJ[sj][0], nt = SJ[sj][1];
      f32x4v acc = (f32x4v){0.f, 0.f, 0.f, 0.f};
#pragma unroll
      for (int ks = 0; ks < 4; ++ks) {
        bf16x8 af = *(const bf16x8*)&ktb[(mt * 16 + rlo) * 136 + ks * 32 + khi * 8];
        bf16x8 bf_ = *(const bf16x8*)&ktb[(nt * 16 + rlo) * 136 + ks * 32 + khi * 8];
        acc = __builtin_amdgcn_mfma_f32_16x16x32_bf16(af, bf_, acc, 0, 0, 0);
      }
      const int j = nt * 16 + rlo;
#pragma unroll
      for (int r2 = 0; r2 < 4; ++r2) {
        const int i = mt * 16 + khi * 4 + r2;
        if (j < i) Amat[i * 68 + j] = -bet[i] * __expf(gc[i] - gc[j]) * acc[r2];
      }
    }
  }
  __syncthreads();

#pragma unroll 1
  for (int ib = 0; ib < 8; ++ib) {
    const int i0 = ib * 8;
    if (t < 128) {
      float* Xc = Xt + t * 68;
      float p[8] = {0, 0, 0, 0, 0, 0, 0, 0};
      for (int j = 0; j < i0; j += 4) {
        f32x4v xj = *(const f32x4v*)&Xc[j];
#pragma unroll
        for (int r2 = 0; r2 < 8; ++r2) {
          f32x4v ar = *(const f32x4v*)&Amat[(i0 + r2) * 68 + j];
          p[r2] += ar[0] * xj[0] + ar[1] * xj[1] + ar[2] * xj[2] + ar[3] * xj[3];
        }
      }
      float xi[8];
#pragma unroll
      for (int r2 = 0; r2 < 8; ++r2) {
        float v = Xc[i0 + r2] + p[r2];
#pragma unroll
        for (int r3 = 0; r3 < r2; ++r3) v += Amat[(i0 + r2) * 68 + i0 + r3] * xi[r3];
        xi[r2] = v;
        Xc[i0 + r2] = v;
      }
    }
    __syncthreads();
  }

  {
    unsigned short* wdst = WU + (rowbase + row0 + r) * (size_t)NWP + h * 128 + q4 * 32;
#pragma unroll
    for (int j = 0; j < 32; ++j) wdst[j] = f2bf(Xt[(q4 * 32 + j) * 68 + r]);
    const unsigned short* vp = QKV + grow + 4096 + h * 128 + q4 * 32;
    const float brow = bet[r];
#pragma unroll
    for (int j = 0; j < 32; j += 4) {
      ushort4 vm = *(const ushort4*)(vp + j);
      Xt[(q4 * 32 + j + 0) * 68 + r] = bf2f(vm.x) * brow;
      Xt[(q4 * 32 + j + 1) * 68 + r] = bf2f(vm.y) * brow;
      Xt[(q4 * 32 + j + 2) * 68 + r] = bf2f(vm.z) * brow;
      Xt[(q4 * 32 + j + 3) * 68 + r] = bf2f(vm.w) * brow;
    }
  }
  __syncthreads();

#pragma unroll 1
  for (int ib = 0; ib < 8; ++ib) {
    const int i0 = ib * 8;
    if (t < 128) {
      float* Xc = Xt + t * 68;
      float p[8] = {0, 0, 0, 0, 0, 0, 0, 0};
      for (int j = 0; j < i0; j += 4) {
        f32x4v xj = *(const f32x4v*)&Xc[j];
#pragma unroll
        for (int r2 = 0; r2 < 8; ++r2) {
          f32x4v ar = *(const f32x4v*)&Amat[(i0 + r2) * 68 + j];
          p[r2] += ar[0] * xj[0] + ar[1] * xj[1] + ar[2] * xj[2] + ar[3] * xj[3];
        }
      }
      float xi[8];
#pragma unroll
      for (int r2 = 0; r2 < 8; ++r2) {
        float v = Xc[i0 + r2] + p[r2];
#pragma unroll
        for (int r3 = 0; r3 < r2; ++r3) v += Amat[(i0 + r2) * 68 + i0 + r3] * xi[r3];
        xi[r2] = v;
        Xc[i0 + r2] = v;
      }
    }
    __syncthreads();
  }

  {
    unsigned short* udst = WU + (rowbase + row0 + r) * (size_t)NWP + 4096 + h * 128 + q4 * 32;
#pragma unroll
    for (int j = 0; j < 32; ++j) udst[j] = f2bf(Xt[(q4 * 32 + j) * 68 + r]);
  }
  __syncthreads();

  {
    const unsigned short* qp = QKV + grow + hq * 128 + q4 * 32;
    float qv[32]; float ssq = 0.f;
#pragma unroll
    for (int j = 0; j < 32; j += 4) {
      ushort4 qm = *(const ushort4*)(qp + j);
      qv[j] = bf2f(qm.x); qv[j + 1] = bf2f(qm.y); qv[j + 2] = bf2f(qm.z); qv[j + 3] = bf2f(qm.w);
      ssq += qv[j]*qv[j] + qv[j+1]*qv[j+1] + qv[j+2]*qv[j+2] + qv[j+3]*qv[j+3];
    }
    ssq += __shfl_xor(ssq, 1, 64);
    ssq += __shfl_xor(ssq, 2, 64);
    const float rq = rsqrtf(ssq + 1e-6f) * 0.08838834764831845f;
#pragma unroll
    for (int j = 0; j < 32; ++j) qb[r * 136 + q4 * 32 + j] = f2bf(qv[j] * rq);
  }
  __syncthreads();

  {
    const size_t abase = (((size_t)b * 32 + h) * 32 + cix) * 4096;
#pragma unroll 1
    for (int nt = 0; nt < 4; ++nt) {
      const int j = nt * 16 + rlo;
      float vals[4] = {0.f, 0.f, 0.f, 0.f};
      if (nt <= w) {
        f32x4v acc = (f32x4v){0.f, 0.f, 0.f, 0.f};
#pragma unroll
        for (int ks = 0; ks < 4; ++ks) {
          bf16x8 af = *(const bf16x8*)&qb[(w * 16 + rlo) * 136 + ks * 32 + khi * 8];
          bf16x8 bf_ = *(const bf16x8*)&ktb[(nt * 16 + rlo) * 136 + ks * 32 + khi * 8];
          acc = __builtin_amdgcn_mfma_f32_16x16x32_bf16(af, bf_, acc, 0, 0, 0);
        }
#pragma unroll
        for (int r2 = 0; r2 < 4; ++r2) {
          const int i = w * 16 + khi * 4 + r2;
          if (j <= i) vals[r2] = __expf(gc[i] - gc[j]) * acc[r2];
        }
      }
#pragma unroll
      for (int r2 = 0; r2 < 4; ++r2)
        ATTN[abase + (w * 16 + khi * 4 + r2) * 64 + j] = f2bf(vals[r2]);
    }
  }
}

// ---------------------------------------------------------------- SEQ: state recurrence
#define SEQ_SMEM 70400
__global__ __launch_bounds__(256) void seq_kernel(const unsigned short* __restrict__ QKV,
                                                  const float* __restrict__ G,
                                                  const unsigned short* __restrict__ WU,
                                                  const unsigned short* __restrict__ ATTN,
                                                  unsigned short* __restrict__ CORE) {
  extern __shared__ char smem[];
  unsigned short* ktT    = (unsigned short*)smem;            // [128][88]
  unsigned short* wb     = (unsigned short*)(smem + 22528);  // [64][136]
  unsigned short* attnb  = (unsigned short*)(smem + 39936);  // [64][88]
  float* stateT          = (float*)(smem + 51200);           // [16][136]
  unsigned short* stateTb = (unsigned short*)(smem + 59904); // [16][136]
  unsigned short* vnTb   = (unsigned short*)(smem + 64256);  // [16][88]
  unsigned short* vdTb   = (unsigned short*)(smem + 67072);  // [16][88]
  float* gc   = (float*)(smem + 69888);                      // [64]
  float* edec = (float*)(smem + 70144);                      // [64]

  const int t = threadIdx.x;
  const int lane = t & 63, w = t >> 6;
  const int rlo = lane & 15, khi = lane >> 4;
  const int vq = blockIdx.x & 7;
  const int h = (blockIdx.x >> 3) & 31;
  const int b = blockIdx.x >> 8;
  const int hq = h >> 1;
  const size_t rowbase = (size_t)b * SEQ;
  const size_t ahead = ((size_t)b * 32 + h) * 32;

  for (int i = t; i < 16 * 136; i += 256) { stateT[i] = 0.f; stateTb[i] = 0; }
  __syncthreads();

  bf16x8 qf[4];

#pragma unroll 1
  for (int ncb = 0; ncb < 32; ++ncb) {
    const int row0 = ncb * 64;

    if (t < 64) {
      float gv = G[(rowbase + row0 + t) * NUMV + h];
#pragma unroll
      for (int off = 1; off < 64; off <<= 1) {
        float u = __shfl_up(gv, off, 64);
        if (t >= off) gv += u;
      }
      gc[t] = gv;
      float tot = __shfl(gv, 63, 64);
      edec[t] = __expf(tot - gv);
    }
    __syncthreads();

    {
      const int r = t >> 2, q4 = t & 3;
      const size_t grow = (rowbase + row0 + r) * (size_t)CONVD;
      const unsigned short* kp = QKV + grow + 2048 + hq * 128 + q4 * 32;
      float kv[32]; float ssk = 0.f;
#pragma unroll
      for (int j = 0; j < 32; j += 4) {
        ushort4 km = *(const ushort4*)(kp + j);
        kv[j] = bf2f(km.x); kv[j + 1] = bf2f(km.y); kv[j + 2] = bf2f(km.z); kv[j + 3] = bf2f(km.w);
        ssk += kv[j]*kv[j] + kv[j+1]*kv[j+1] + kv[j+2]*kv[j+2] + kv[j+3]*kv[j+3];
      }
      ssk += __shfl_xor(ssk, 1, 64);
      ssk += __shfl_xor(ssk, 2, 64);
      const float rk = rsqrtf(ssk + 1e-6f);
#pragma unroll
      for (int j = 0; j < 32; ++j) ktT[(q4 * 32 + j) * 88 + r] = f2bf(kv[j] * rk);
      const unsigned short* wsrc = WU + (rowbase + row0 + r) * (size_t)NWP + h * 128 + q4 * 32;
#pragma unroll
      for (int u2 = 0; u2 < 4; ++u2)
        *(uint4*)&wb[r * 136 + q4 * 32 + u2 * 8] = *(const uint4*)(wsrc + u2 * 8);
      const unsigned short* asrc = ATTN + (ahead + ncb) * 4096 + r * 64 + q4 * 16;
      *(uint4*)&attnb[r * 88 + q4 * 16] = *(const uint4*)(asrc);
      *(uint4*)&attnb[r * 88 + q4 * 16 + 8] = *(const uint4*)(asrc + 8);
      const unsigned short* qsrc = QKV + (rowbase + row0 + w * 16 + rlo) * (size_t)CONVD + hq * 128 + khi * 8;
      float qv[32]; float ssq = 0.f;
#pragma unroll
      for (int ks = 0; ks < 4; ++ks) {
        ushort4 qa = *(const ushort4*)(qsrc + ks * 32);
        ushort4 qb2 = *(const ushort4*)(qsrc + ks * 32 + 4);
        qv[ks*8+0] = bf2f(qa.x); qv[ks*8+1] = bf2f(qa.y); qv[ks*8+2] = bf2f(qa.z); qv[ks*8+3] = bf2f(qa.w);
        qv[ks*8+4] = bf2f(qb2.x); qv[ks*8+5] = bf2f(qb2.y); qv[ks*8+6] = bf2f(qb2.z); qv[ks*8+7] = bf2f(qb2.w);
#pragma unroll
        for (int e = 0; e < 8; ++e) ssq += qv[ks*8+e] * qv[ks*8+e];
      }
      ssq += __shfl_xor(ssq, 16, 64);
      ssq += __shfl_xor(ssq, 32, 64);
      const float rq = rsqrtf(ssq + 1e-6f) * 0.08838834764831845f;
#pragma unroll
      for (int ks = 0; ks < 4; ++ks) {
        bf16x8 tv;
#pragma unroll
        for (int e = 0; e < 8; ++e) tv[e] = (short)f2bf(qv[ks*8+e] * rq);
        qf[ks] = tv;
      }
    }
    __syncthreads();

    f32x4v oacc;
    {
      f32x4v pacc = (f32x4v){0.f, 0.f, 0.f, 0.f};
      oacc = (f32x4v){0.f, 0.f, 0.f, 0.f};
#pragma unroll
      for (int ks = 0; ks < 4; ++ks) {
        bf16x8 aw = *(const bf16x8*)&wb[(w * 16 + rlo) * 136 + ks * 32 + khi * 8];
        bf16x8 bs = *(const bf16x8*)&stateTb[rlo * 136 + ks * 32 + khi * 8];
        pacc = __builtin_amdgcn_mfma_f32_16x16x32_bf16(aw, bs, pacc, 0, 0, 0);
        oacc = __builtin_amdgcn_mfma_f32_16x16x32_bf16(qf[ks], bs, oacc, 0, 0, 0);
      }
#pragma unroll
      for (int r2 = 0; r2 < 4; ++r2) {
        const int i = w * 16 + khi * 4 + r2;
        float uv = bf2f(WU[(rowbase + row0 + i) * (size_t)NWP + 4096 + h * 128 + vq * 16 + rlo]);
        float vn = uv - pacc[r2];
        vnTb[rlo * 88 + i] = f2bf(vn);
        vdTb[rlo * 88 + i] = f2bf(vn * edec[i]);
        oacc[r2] *= __expf(gc[i]);
      }
    }
    __syncthreads();

    {
#pragma unroll
      for (int ks = 0; ks < 2; ++ks) {
        bf16x8 aa = *(const bf16x8*)&attnb[(w * 16 + rlo) * 88 + ks * 32 + khi * 8];
        bf16x8 bv = *(const bf16x8*)&vnTb[rlo * 88 + ks * 32 + khi * 8];
        oacc = __builtin_amdgcn_mfma_f32_16x16x32_bf16(aa, bv, oacc, 0, 0, 0);
      }
      const int col = h * 128 + vq * 16 + rlo;
#pragma unroll
      for (int r2 = 0; r2 < 4; ++r2) {
        const int i = w * 16 + khi * 4 + r2;
        CORE[(rowbase + row0 + i) * (size_t)4096 + col] = f2bf(oacc[r2]);
      }
      const float egl = __expf(gc[63]);
#pragma unroll
      for (int n2 = 0; n2 < 2; ++n2) {
        const int dt = w * 2 + n2;
        f32x4v sacc = (f32x4v){0.f, 0.f, 0.f, 0.f};
#pragma unroll
        for (int ks = 0; ks < 2; ++ks) {
          bf16x8 ak = *(const bf16x8*)&ktT[(dt * 16 + rlo) * 88 + ks * 32 + khi * 8];
          bf16x8 bv2 = *(const bf16x8*)&vdTb[rlo * 88 + ks * 32 + khi * 8];
          sacc = __builtin_amdgcn_mfma_f32_16x16x32_bf16(ak, bv2, sacc, 0, 0, 0);
        }
#pragma unroll
        for (int r2 = 0; r2 < 4; ++r2) {
          const int d = dt * 16 + khi * 4 + r2;
          float ns = stateT[rlo * 136 + d] * egl + sacc[r2];
          stateT[rlo * 136 + d] = ns;
          stateTb[rlo * 136 + d] = f2bf(ns);
        }
      }
    }
    __syncthreads();
  }
}

// ---------------------------------------------------------------- gate * silu(z) + RMS-norm
__global__ __launch_bounds__(256) void gatenorm_kernel(const unsigned short* __restrict__ CORE,
                                                       const unsigned short* __restrict__ C1,
                                                       const float* __restrict__ norm_w,
                                                       unsigned short* __restrict__ NRM) {
  const int wid = blockIdx.x * 4 + (threadIdx.x >> 6);
  const int lane = threadIdx.x & 63;
  const int row = wid >> 5, h = wid & 31;
  const int c = lane * 2;
  const size_t cidx = (size_t)row * 4096 + h * 128 + c;
  const size_t zidx = (size_t)row * NWP + 8192 + h * 128 + c;
  float g0 = bf2f(CORE[cidx]), g1 = bf2f(CORE[cidx + 1]);
  float z0 = bf2f(C1[zidx]), z1 = bf2f(C1[zidx + 1]);
  g0 *= z0 / (1.f + __expf(-z0));
  g1 *= z1 / (1.f + __expf(-z1));
  float ss = g0 * g0 + g1 * g1;
#pragma unroll
  for (int m = 1; m < 64; m <<= 1) ss += __shfl_xor(ss, m, 64);
  const float rr = rsqrtf(ss * (1.f / 128.f) + 1e-6f);
  unsigned int o = ((unsigned int)f2bf(g1 * rr * norm_w[c + 1]) << 16) | (unsigned int)f2bf(g0 * rr * norm_w[c]);
  *(unsigned int*)(NRM + cidx) = o;
}

// ---------------------------------------------------------------------------
extern "C" void kernel_launch(void* const* d_in, const int* in_sizes, int n_in,
                              void* d_out, int out_size, void* d_ws, size_t ws_size,
                              hipStream_t stream) {
  const float* hs      = (const float*)d_in[0];
  const float* W_qkv   = (const float*)d_in[1];
  const float* W_z     = (const float*)d_in[2];
  const float* W_b     = (const float*)d_in[3];
  const float* W_a     = (const float*)d_in[4];
  const float* conv_w  = (const float*)d_in[5];
  const float* dt_bias = (const float*)d_in[6];
  const float* A_log   = (const float*)d_in[7];
  const float* norm_w  = (const float*)d_in[8];
  const float* W_out   = (const float*)d_in[9];
  float* out = (float*)d_out;
  char* ws = (char*)d_ws;

  const size_t OFF_HSB = 0;                                     // hs bf16; later ATTN
  const size_t OFF_WT  = OFF_HSB + (size_t)ROWS * HIDN * 2;     // WT; later CORE
  const size_t OFF_WOT = OFF_WT + (size_t)NWP * HIDN * 2;
  const size_t OFF_C1  = OFF_WOT + (size_t)HIDN * 4096 * 2;     // C1; cols [0,8192) -> w,u after conv
  const size_t OFF_QKV = OFF_C1 + (size_t)ROWS * NWP * 2;       // QKV; later NRM
  const size_t OFF_G   = OFF_QKV + (size_t)ROWS * CONVD * 2;
  const size_t OFF_B   = OFF_G + (size_t)ROWS * NUMV * 4;

  unsigned short* hsb = (unsigned short*)(ws + OFF_HSB);
  unsigned short* WT  = (unsigned short*)(ws + OFF_WT);
  unsigned short* WoT = (unsigned short*)(ws + OFF_WOT);
  unsigned short* C1  = (unsigned short*)(ws + OFF_C1);
  unsigned short* QKV = (unsigned short*)(ws + OFF_QKV);
  float* Gb = (float*)(ws + OFF_G);
  float* Bb = (float*)(ws + OFF_B);
  unsigned short* ATTNb = (unsigned short*)(ws + OFF_HSB);
  unsigned short* COREb = (unsigned short*)(ws + OFF_WT);
  unsigned short* NRMb  = (unsigned short*)(ws + OFF_QKV);

  cast_kernel<<<ROWS * HIDN / 4 / 256, 256, 0, stream>>>(hs, hsb, ROWS * HIDN / 4);
  transpose_kernel<<<dim3(8192 / 64, 2048 / 64), 256, 0, stream>>>(W_qkv, WT, 2048, 8192, HIDN, 0);
  transpose_kernel<<<dim3(4096 / 64, 2048 / 64), 256, 0, stream>>>(W_z, WT, 2048, 4096, HIDN, 8192);
  transpose_kernel<<<dim3(1, 2048 / 64), 256, 0, stream>>>(W_b, WT, 2048, 32, HIDN, 12288);
  transpose_kernel<<<dim3(1, 2048 / 64), 256, 0, stream>>>(W_a, WT, 2048, 32, HIDN, 12320);
  hipMemsetAsync(ws + OFF_WT + (size_t)12352 * HIDN * 2, 0, (size_t)192 * HIDN * 2, stream);
  transpose_kernel<<<dim3(2048 / 64, 4096 / 64), 256, 0, stream>>>(W_out, WoT, 4096, 2048, 4096, 0);

  void (*g1p)(const unsigned short*, const unsigned short*, void*, int, int, int) = gemm256_kernel<1>;
  void (*g0p)(const unsigned short*, const unsigned short*, void*, int, int, int) = gemm256_kernel<0>;
  hipFuncSetAttribute((const void*)g1p, hipFuncAttributeMaxDynamicSharedMemorySize, G256_LDS);
  hipFuncSetAttribute((const void*)g0p, hipFuncAttributeMaxDynamicSharedMemorySize, G256_LDS);

  gemm256_kernel<1><<<dim3(NWP / 256, ROWS / 256), 512, G256_LDS, stream>>>(hsb, WT, C1, ROWS, NWP, HIDN);
  conv_silu_kernel<<<ROWS * (CONVD / 4) / 256, 256, 0, stream>>>(C1, conv_w, QKV);
  gbeta_kernel<<<ROWS * NUMV / 256, 256, 0, stream>>>(C1, dt_bias, A_log, Gb, Bb);

  hipFuncSetAttribute((const void*)intra_kernel, hipFuncAttributeMaxDynamicSharedMemorySize,
                      INTRA_SMEM);
  intra_kernel<<<2048, 256, INTRA_SMEM, stream>>>(QKV, Gb, Bb, C1, ATTNb);

  hipFuncSetAttribute((const void*)seq_kernel, hipFuncAttributeMaxDynamicSharedMemorySize,
                      SEQ_SMEM);
  seq_kernel<<<512, 256, SEQ_SMEM, stream>>>(QKV, Gb, C1, ATTNb, COREb);

  gatenorm_kernel<<<ROWS * NUMV / 4, 256, 0, stream>>>(COREb, C1, norm_w, NRMb);
  gemm256_kernel<0><<<dim3(2048 / 256, ROWS / 256), 512, G256_LDS, stream>>>(NRMb, WoT, out, ROWS, 2048, 4096);
}

// Round 8
// 901.931 us; speedup vs baseline: 3.9015x; 1.0439x over previous
//
#include <hip/hip_runtime.h>
#include <cstdint>
#include <cstddef>

// ---------------------------------------------------------------------------
// GatedDeltaNet forward, MI355X/gfx950.
//  1. cast hs -> bf16 ; transpose weights -> bf16 [N][K]
//  2. GEMM1 (256x256/BK64, proven single-phase counted-vmcnt pipeline, T1/T2/T4/T5)
//  3. causal conv(K=4)+SiLU -> QKV bf16 ; beta/g
//  4. INTRA (chunk-parallel): A build + solve -> w,u ; attn
//  5. SEQ: state recurrence, MFMA
//  6. gate + RMS-norm ; GEMM2 (128x256, 256 WGs = 1/CU): out = NRM @ W_out
// ---------------------------------------------------------------------------

#define ROWS  4096
#define SEQ   2048
#define HIDN  2048
#define CONVD 8192
#define NWP   12544     // 8192 qkv + 4096 z + 32 b + 32 a + 192 pad (49*256)
#define NUMV  32

using bf16x8 = __attribute__((ext_vector_type(8))) short;
using f32x4v = __attribute__((ext_vector_type(4))) float;

__device__ __forceinline__ float bf2f(unsigned short u) {
  union { unsigned int i; float f; } x; x.i = ((unsigned int)u) << 16; return x.f;
}
__device__ __forceinline__ unsigned short f2bf(float f) {
  union { float f; unsigned int u; } x; x.f = f;
  unsigned int u = x.u;
  unsigned int r = (u + 0x7FFFu + ((u >> 16) & 1u)) >> 16;  // RNE
  return (unsigned short)r;
}

typedef const __attribute__((address_space(1))) unsigned int GU32;
typedef __attribute__((address_space(3))) unsigned int LU32;
__device__ __forceinline__ void gld_lds16(const void* g, void* l) {
  GU32* gp = (GU32*)(unsigned long long)(uintptr_t)g;
  LU32* lp = (LU32*)(unsigned int)(uintptr_t)l;  // flat-LDS low32 = LDS offset
  __builtin_amdgcn_global_load_lds(gp, lp, 16, 0, 0);
}
// counted VMEM wait — asm with "memory" clobber (compiler-level fence)
template <int N>
__device__ __forceinline__ void waitcnt_vm() {
  asm volatile("s_waitcnt vmcnt(%0)" ::"i"(N) : "memory");
}

// ---------------------------------------------------------------- cast fp32->bf16
__global__ __launch_bounds__(256) void cast_kernel(const float* __restrict__ in,
                                                   unsigned short* __restrict__ out, int n4) {
  int i = blockIdx.x * 256 + threadIdx.x;
  if (i >= n4) return;
  float4 v = ((const float4*)in)[i];
  ushort4 o;
  o.x = f2bf(v.x); o.y = f2bf(v.y); o.z = f2bf(v.z); o.w = f2bf(v.w);
  ((ushort4*)out)[i] = o;
}

// ------------------------------------------------- transpose W[K][N] -> WT[roff+N][K] bf16
__global__ __launch_bounds__(256) void transpose_kernel(const float* __restrict__ W,
                                                        unsigned short* __restrict__ WT,
                                                        int K, int N, int ld, int roff) {
  __shared__ float tile[64][65];
  const int t = threadIdx.x;
  const int kb = blockIdx.y * 64, nb = blockIdx.x * 64;
  const int r = t >> 2, c0 = (t & 3) * 16;
#pragma unroll
  for (int i = 0; i < 16; ++i) {
    int c = c0 + i;
    float v = 0.f;
    if (nb + c < N) v = W[(size_t)(kb + r) * N + nb + c];
    tile[r][c] = v;
  }
  __syncthreads();
  const int bn = t >> 2;
  if (nb + bn < N) {
#pragma unroll
    for (int i = 0; i < 16; ++i)
      WT[(size_t)(roff + nb + bn) * ld + kb + c0 + i] = f2bf(tile[c0 + i][bn]);
  }
}

// ---------------------------------------------------------------- tiled bf16 GEMM (B^T input)
// 512 threads = 8 waves (2M x 4N). BK=64. Per-wave C: (BM/2)x(BN/4).
// R5-proven single-phase schedule: per K-tile {read all frags; MFMA all; barrier;
// stage tile kt+2 into freed buffer; vmcnt(SL) -> tile kt+1 fully resident; barrier}.
// Invariant: each wave's vmcnt(SL)+barrier proves the ENTIRE next tile resident
// before any read of it (no partial-tile residency — the R6/R7 fine-phase variant
// raced and is abandoned pending disasm access).
// T2 swizzle byte^=((byte>>7)&7)<<4 both-sides (verified 0 bank conflicts in R5).
template <int BM, int BN, int OUT_BF16>
__global__ __launch_bounds__(512) void gemm_s_kernel(const unsigned short* __restrict__ Ag,
                                                     const unsigned short* __restrict__ Bg,
                                                     void* __restrict__ Cg, int M, int N, int K) {
  constexpr int PM = BM / 2, PN = BN / 4;      // per-wave output
  constexpr int MT = PM / 16, NTF = PN / 16;   // frag tiles per wave
  constexpr int LA = BM / 64, LB = BN / 64;    // gld_lds per thread per full tile
  constexpr int SL = LA + LB;                  // loads per STAGE
  constexpr int BUF = (BM + BN) * 128;         // bytes per LDS buffer
  extern __shared__ char lds[];
  const int t = threadIdx.x;
  const int lane = t & 63, wid = t >> 6;
  const int wm = wid >> 2, wn = wid & 3;
  const int rlo = lane & 15, khi = lane >> 4;

  // T1: bijective XCD swizzle (grid sizes used are multiples of 8)
  const int gx = gridDim.x, nwg = gx * gridDim.y;
  int id = blockIdx.y * gx + blockIdx.x;
  int sid = (id & 7) * (nwg >> 3) + (id >> 3);
  const int m0 = (sid / gx) * BM, n0 = (sid % gx) * BN;

  const int NT = K >> 6;

  // staging source: row-in-64-block = t>>3, pre-swizzled col slot (rule #21)
  const int srow = t >> 3;
  const int scb = ((t & 7) * 16) ^ ((srow & 7) << 4);
  const char* Abase = (const char*)Ag + ((size_t)(m0 + srow) * K) * 2 + scb;
  const char* Bbase = (const char*)Bg + ((size_t)(n0 + srow) * K) * 2 + scb;
  const size_t rstride = (size_t)64 * K * 2;

  // swizzled ds_read byte offsets
  int offA[MT][2], offB[NTF][2];
#pragma unroll
  for (int mi = 0; mi < MT; ++mi)
#pragma unroll
    for (int ks = 0; ks < 2; ++ks) {
      int o = (wm * PM + mi * 16 + rlo) * 128 + ks * 64 + khi * 16;
      o ^= ((o >> 7) & 7) << 4;
      offA[mi][ks] = o;
    }
#pragma unroll
  for (int ni = 0; ni < NTF; ++ni)
#pragma unroll
    for (int ks = 0; ks < 2; ++ks) {
      int o = (wn * PN + ni * 16 + rlo) * 128 + ks * 64 + khi * 16;
      o ^= ((o >> 7) & 7) << 4;
      offB[ni][ks] = o + BM * 128;
    }

  f32x4v acc[MT][NTF];
#pragma unroll
  for (int mi = 0; mi < MT; ++mi)
#pragma unroll
    for (int ni = 0; ni < NTF; ++ni) acc[mi][ni] = (f32x4v){0.f, 0.f, 0.f, 0.f};

#define STAGE(KT, P)                                                        \
  do {                                                                      \
    const char* a_ = Abase + (size_t)(KT) * 128;                            \
    const char* b_ = Bbase + (size_t)(KT) * 128;                            \
    char* da_ = lds + (P) * BUF + t * 16;                                   \
    char* db_ = lds + (P) * BUF + BM * 128 + t * 16;                        \
    _Pragma("unroll") for (int i_ = 0; i_ < LA; ++i_)                       \
        gld_lds16(a_ + i_ * rstride, da_ + i_ * 8192);                      \
    _Pragma("unroll") for (int i_ = 0; i_ < LB; ++i_)                       \
        gld_lds16(b_ + i_ * rstride, db_ + i_ * 8192);                      \
  } while (0)

  // prologue: stage kt=0 -> buf0, kt=1 -> buf1; wait kt0 (kt1's SL stay in flight)
  STAGE(0, 0);
  STAGE(1, 1);
  waitcnt_vm<SL>();
  __builtin_amdgcn_s_barrier();
  __builtin_amdgcn_sched_barrier(0);

#pragma unroll 1
  for (int kt = 0; kt < NT; ++kt) {
    const char* base = lds + (kt & 1) * BUF;
#pragma unroll
    for (int ks = 0; ks < 2; ++ks) {
      bf16x8 af[MT], bv[NTF];
#pragma unroll
      for (int mi = 0; mi < MT; ++mi) af[mi] = *(const bf16x8*)(base + offA[mi][ks]);
#pragma unroll
      for (int ni = 0; ni < NTF; ++ni) bv[ni] = *(const bf16x8*)(base + offB[ni][ks]);
      __builtin_amdgcn_s_setprio(1);
#pragma unroll
      for (int mi = 0; mi < MT; ++mi)
#pragma unroll
        for (int ni = 0; ni < NTF; ++ni)
          acc[mi][ni] = __builtin_amdgcn_mfma_f32_16x16x32_bf16(af[mi], bv[ni], acc[mi][ni], 0, 0, 0);
      __builtin_amdgcn_s_setprio(0);
    }
    if (kt + 1 < NT) {
      __builtin_amdgcn_s_barrier();     // all waves done reading buf[kt&1]
      if (kt + 2 < NT) {
        STAGE(kt + 2, kt & 1);          // re-stage freed buffer
        waitcnt_vm<SL>();               // tile kt+1 fully landed; kt+2 in flight
      } else {
        waitcnt_vm<0>();
      }
      __builtin_amdgcn_s_barrier();     // kt+1 resident for every wave
      __builtin_amdgcn_sched_barrier(0);
    }
  }
#undef STAGE

  // epilogue: C/D map col=lane&15 (N), row=4*(lane>>4)+reg (M)
  const int mrb = khi * 4;
#pragma unroll
  for (int mi = 0; mi < MT; ++mi)
#pragma unroll
    for (int ni = 0; ni < NTF; ++ni)
#pragma unroll
      for (int r = 0; r < 4; ++r) {
        int mm = m0 + wm * PM + mi * 16 + mrb + r;
        int nn = n0 + wn * PN + ni * 16 + rlo;
        float v = acc[mi][ni][r];
        if (OUT_BF16) ((unsigned short*)Cg)[(size_t)mm * N + nn] = f2bf(v);
        else          ((float*)Cg)[(size_t)mm * N + nn] = v;
      }
}

// ---------------------------------------------------------------- causal conv K=4 + SiLU
__global__ __launch_bounds__(256) void conv_silu_kernel(const unsigned short* __restrict__ C1,
                                                        const float* __restrict__ conv_w,
                                                        unsigned short* __restrict__ QKV) {
  int idx = blockIdx.x * 256 + threadIdx.x;
  int row = idx >> 11;
  int c4 = (idx & 2047) << 2;
  int s = row & 2047;
  float4 w0 = *(const float4*)(conv_w + (size_t)(c4 + 0) * 4);
  float4 w1 = *(const float4*)(conv_w + (size_t)(c4 + 1) * 4);
  float4 w2 = *(const float4*)(conv_w + (size_t)(c4 + 2) * 4);
  float4 w3 = *(const float4*)(conv_w + (size_t)(c4 + 3) * 4);
  const float* pw0 = (const float*)&w0;
  const float* pw1 = (const float*)&w1;
  const float* pw2 = (const float*)&w2;
  const float* pw3 = (const float*)&w3;
  float a0 = 0.f, a1 = 0.f, a2 = 0.f, a3 = 0.f;
#pragma unroll
  for (int j = 0; j < 4; ++j) {
    int sr = s - 3 + j;
    if (sr < 0) continue;
    ushort4 mv = *(const ushort4*)(C1 + (size_t)(row - 3 + j) * NWP + c4);
    a0 += bf2f(mv.x) * pw0[j];
    a1 += bf2f(mv.y) * pw1[j];
    a2 += bf2f(mv.z) * pw2[j];
    a3 += bf2f(mv.w) * pw3[j];
  }
  ushort4 o;
  o.x = f2bf(a0 / (1.f + __expf(-a0)));
  o.y = f2bf(a1 / (1.f + __expf(-a1)));
  o.z = f2bf(a2 / (1.f + __expf(-a2)));
  o.w = f2bf(a3 / (1.f + __expf(-a3)));
  *(ushort4*)(QKV + (size_t)row * CONVD + c4) = o;
}

// ---------------------------------------------------------------- beta / g
__global__ __launch_bounds__(256) void gbeta_kernel(const unsigned short* __restrict__ C1,
                                                    const float* __restrict__ dt_bias,
                                                    const float* __restrict__ A_log,
                                                    float* __restrict__ G, float* __restrict__ BETA) {
  int idx = blockIdx.x * 256 + threadIdx.x;
  int row = idx >> 5, h = idx & 31;
  float bp = bf2f(C1[(size_t)row * NWP + 12288 + h]);
  float ap = bf2f(C1[(size_t)row * NWP + 12320 + h]);
  BETA[idx] = 1.f / (1.f + __expf(-bp));
  float x = ap + dt_bias[h];
  float sp = (x > 15.f) ? x : log1pf(__expf(x));
  G[idx] = -__expf(A_log[h]) * sp;
}

// ---------------------------------------------------------------- INTRA: per-chunk solve
#define INTRA_SMEM 70144
__global__ __launch_bounds__(256) void intra_kernel(const unsigned short* __restrict__ QKV,
                                                    const float* __restrict__ G,
                                                    const float* __restrict__ BETA,
                                                    unsigned short* __restrict__ WU,
                                                    unsigned short* __restrict__ ATTN) {
  extern __shared__ char smem[];
  unsigned short* ktb = (unsigned short*)smem;        // [64][136]
  float* Amat = (float*)(smem + 17408);               // [64][68]
  float* Xt   = (float*)(smem + 34816);               // [128][68]
  unsigned short* qb = (unsigned short*)Xt;           // [64][136] alias
  float* gc  = (float*)(smem + 69632);                // [64]
  float* bet = gc + 64;                               // [64]

  const int t = threadIdx.x;
  const int lane = t & 63, w = t >> 6;
  const int rlo = lane & 15, khi = lane >> 4;
  const int cix = blockIdx.x & 31;
  const int h = (blockIdx.x >> 5) & 31;
  const int b = blockIdx.x >> 10;
  const int hq = h >> 1;
  const int row0 = cix * 64;
  const size_t rowbase = (size_t)b * SEQ;

  if (t < 64) {
    float gv = G[(rowbase + row0 + t) * NUMV + h];
    bet[t] = BETA[(rowbase + row0 + t) * NUMV + h];
#pragma unroll
    for (int off = 1; off < 64; off <<= 1) {
      float u = __shfl_up(gv, off, 64);
      if (t >= off) gv += u;
    }
    gc[t] = gv;
  }
  __syncthreads();

  const int r = t >> 2, q4 = t & 3;
  const size_t grow = (rowbase + row0 + r) * (size_t)CONVD;

  {
    const unsigned short* kp = QKV + grow + 2048 + hq * 128 + q4 * 32;
    float kv[32]; float ssk = 0.f;
#pragma unroll
    for (int j = 0; j < 32; j += 4) {
      ushort4 km = *(const ushort4*)(kp + j);
      kv[j] = bf2f(km.x); kv[j + 1] = bf2f(km.y); kv[j + 2] = bf2f(km.z); kv[j + 3] = bf2f(km.w);
      ssk += kv[j]*kv[j] + kv[j+1]*kv[j+1] + kv[j+2]*kv[j+2] + kv[j+3]*kv[j+3];
    }
    ssk += __shfl_xor(ssk, 1, 64);
    ssk += __shfl_xor(ssk, 2, 64);
    const float rk = rsqrtf(ssk + 1e-6f);
    const float ekr = __expf(gc[r]) * bet[r];
#pragma unroll
    for (int j = 0; j < 32; ++j) {
      float kn = kv[j] * rk;
      ktb[r * 136 + q4 * 32 + j] = f2bf(kn);
      Xt[(q4 * 32 + j) * 68 + r] = kn * ekr;
    }
  }
  __syncthreads();

  {
    static const signed char SJ[10][2] = {{0,0},{1,0},{1,1},{2,0},{2,1},{2,2},{3,0},{3,1},{3,2},{3,3}};
    static const signed char SB[5] = {0, 4, 7, 9, 10};
    for (int sj = SB[w]; sj < SB[w + 1]; ++sj) {
      const int mt = SJ[sj][0], nt = SJ[sj][1];
      f32x4v acc = (f32x4v){0.f, 0.f, 0.f, 0.f};
#pragma unroll
      for (int ks = 0; ks < 4; ++ks) {
        bf16x8 af = *(const bf16x8*)&ktb[(mt * 16 + rlo) * 136 + ks * 32 + khi * 8];
        bf16x8 bf_ = *(const bf16x8*)&ktb[(nt * 16 + rlo) * 136 + ks * 32 + khi * 8];
        acc = __builtin_amdgcn_mfma_f32_16x16x32_bf16(af, bf_, acc, 0, 0, 0);
      }
      const int j = nt * 16 + rlo;
#pragma unroll
      for (int r2 = 0; r2 < 4; ++r2) {
        const int i = mt * 16 + khi * 4 + r2;
        if (j < i) Amat[i * 68 + j] = -bet[i] * __expf(gc[i] - gc[j]) * acc[r2];
      }
    }
  }
  __syncthreads();

#pragma unroll 1
  for (int ib = 0; ib < 8; ++ib) {
    const int i0 = ib * 8;
    if (t < 128) {
      float* Xc = Xt + t * 68;
      float p[8] = {0, 0, 0, 0, 0, 0, 0, 0};
      for (int j = 0; j < i0; j += 4) {
        f32x4v xj = *(const f32x4v*)&Xc[j];
#pragma unroll
        for (int r2 = 0; r2 < 8; ++r2) {
          f32x4v ar = *(const f32x4v*)&Amat[(i0 + r2) * 68 + j];
          p[r2] += ar[0] * xj[0] + ar[1] * xj[1] + ar[2] * xj[2] + ar[3] * xj[3];
        }
      }
      float xi[8];
#pragma unroll
      for (int r2 = 0; r2 < 8; ++r2) {
        float v = Xc[i0 + r2] + p[r2];
#pragma unroll
        for (int r3 = 0; r3 < r2; ++r3) v += Amat[(i0 + r2) * 68 + i0 + r3] * xi[r3];
        xi[r2] = v;
        Xc[i0 + r2] = v;
      }
    }
    __syncthreads();
  }

  {
    unsigned short* wdst = WU + (rowbase + row0 + r) * (size_t)NWP + h * 128 + q4 * 32;
#pragma unroll
    for (int j = 0; j < 32; ++j) wdst[j] = f2bf(Xt[(q4 * 32 + j) * 68 + r]);
    const unsigned short* vp = QKV + grow + 4096 + h * 128 + q4 * 32;
    const float brow = bet[r];
#pragma unroll
    for (int j = 0; j < 32; j += 4) {
      ushort4 vm = *(const ushort4*)(vp + j);
      Xt[(q4 * 32 + j + 0) * 68 + r] = bf2f(vm.x) * brow;
      Xt[(q4 * 32 + j + 1) * 68 + r] = bf2f(vm.y) * brow;
      Xt[(q4 * 32 + j + 2) * 68 + r] = bf2f(vm.z) * brow;
      Xt[(q4 * 32 + j + 3) * 68 + r] = bf2f(vm.w) * brow;
    }
  }
  __syncthreads();

#pragma unroll 1
  for (int ib = 0; ib < 8; ++ib) {
    const int i0 = ib * 8;
    if (t < 128) {
      float* Xc = Xt + t * 68;
      float p[8] = {0, 0, 0, 0, 0, 0, 0, 0};
      for (int j = 0; j < i0; j += 4) {
        f32x4v xj = *(const f32x4v*)&Xc[j];
#pragma unroll
        for (int r2 = 0; r2 < 8; ++r2) {
          f32x4v ar = *(const f32x4v*)&Amat[(i0 + r2) * 68 + j];
          p[r2] += ar[0] * xj[0] + ar[1] * xj[1] + ar[2] * xj[2] + ar[3] * xj[3];
        }
      }
      float xi[8];
#pragma unroll
      for (int r2 = 0; r2 < 8; ++r2) {
        float v = Xc[i0 + r2] + p[r2];
#pragma unroll
        for (int r3 = 0; r3 < r2; ++r3) v += Amat[(i0 + r2) * 68 + i0 + r3] * xi[r3];
        xi[r2] = v;
        Xc[i0 + r2] = v;
      }
    }
    __syncthreads();
  }

  {
    unsigned short* udst = WU + (rowbase + row0 + r) * (size_t)NWP + 4096 + h * 128 + q4 * 32;
#pragma unroll
    for (int j = 0; j < 32; ++j) udst[j] = f2bf(Xt[(q4 * 32 + j) * 68 + r]);
  }
  __syncthreads();

  {
    const unsigned short* qp = QKV + grow + hq * 128 + q4 * 32;
    float qv[32]; float ssq = 0.f;
#pragma unroll
    for (int j = 0; j < 32; j += 4) {
      ushort4 qm = *(const ushort4*)(qp + j);
      qv[j] = bf2f(qm.x); qv[j + 1] = bf2f(qm.y); qv[j + 2] = bf2f(qm.z); qv[j + 3] = bf2f(qm.w);
      ssq += qv[j]*qv[j] + qv[j+1]*qv[j+1] + qv[j+2]*qv[j+2] + qv[j+3]*qv[j+3];
    }
    ssq += __shfl_xor(ssq, 1, 64);
    ssq += __shfl_xor(ssq, 2, 64);
    const float rq = rsqrtf(ssq + 1e-6f) * 0.08838834764831845f;
#pragma unroll
    for (int j = 0; j < 32; ++j) qb[r * 136 + q4 * 32 + j] = f2bf(qv[j] * rq);
  }
  __syncthreads();

  {
    const size_t abase = (((size_t)b * 32 + h) * 32 + cix) * 4096;
#pragma unroll 1
    for (int nt = 0; nt < 4; ++nt) {
      const int j = nt * 16 + rlo;
      float vals[4] = {0.f, 0.f, 0.f, 0.f};
      if (nt <= w) {
        f32x4v acc = (f32x4v){0.f, 0.f, 0.f, 0.f};
#pragma unroll
        for (int ks = 0; ks < 4; ++ks) {
          bf16x8 af = *(const bf16x8*)&qb[(w * 16 + rlo) * 136 + ks * 32 + khi * 8];
          bf16x8 bf_ = *(const bf16x8*)&ktb[(nt * 16 + rlo) * 136 + ks * 32 + khi * 8];
          acc = __builtin_amdgcn_mfma_f32_16x16x32_bf16(af, bf_, acc, 0, 0, 0);
        }
#pragma unroll
        for (int r2 = 0; r2 < 4; ++r2) {
          const int i = w * 16 + khi * 4 + r2;
          if (j <= i) vals[r2] = __expf(gc[i] - gc[j]) * acc[r2];
        }
      }
#pragma unroll
      for (int r2 = 0; r2 < 4; ++r2)
        ATTN[abase + (w * 16 + khi * 4 + r2) * 64 + j] = f2bf(vals[r2]);
    }
  }
}

// ---------------------------------------------------------------- SEQ: state recurrence
#define SEQ_SMEM 70400
__global__ __launch_bounds__(256) void seq_kernel(const unsigned short* __restrict__ QKV,
                                                  const float* __restrict__ G,
                                                  const unsigned short* __restrict__ WU,
                                                  const unsigned short* __restrict__ ATTN,
                                                  unsigned short* __restrict__ CORE) {
  extern __shared__ char smem[];
  unsigned short* ktT    = (unsigned short*)smem;            // [128][88]
  unsigned short* wb     = (unsigned short*)(smem + 22528);  // [64][136]
  unsigned short* attnb  = (unsigned short*)(smem + 39936);  // [64][88]
  float* stateT          = (float*)(smem + 51200);           // [16][136]
  unsigned short* stateTb = (unsigned short*)(smem + 59904); // [16][136]
  unsigned short* vnTb   = (unsigned short*)(smem + 64256);  // [16][88]
  unsigned short* vdTb   = (unsigned short*)(smem + 67072);  // [16][88]
  float* gc   = (float*)(smem + 69888);                      // [64]
  float* edec = (float*)(smem + 70144);                      // [64]

  const int t = threadIdx.x;
  const int lane = t & 63, w = t >> 6;
  const int rlo = lane & 15, khi = lane >> 4;
  const int vq = blockIdx.x & 7;
  const int h = (blockIdx.x >> 3) & 31;
  const int b = blockIdx.x >> 8;
  const int hq = h >> 1;
  const size_t rowbase = (size_t)b * SEQ;
  const size_t ahead = ((size_t)b * 32 + h) * 32;

  for (int i = t; i < 16 * 136; i += 256) { stateT[i] = 0.f; stateTb[i] = 0; }
  __syncthreads();

  bf16x8 qf[4];

#pragma unroll 1
  for (int ncb = 0; ncb < 32; ++ncb) {
    const int row0 = ncb * 64;

    if (t < 64) {
      float gv = G[(rowbase + row0 + t) * NUMV + h];
#pragma unroll
      for (int off = 1; off < 64; off <<= 1) {
        float u = __shfl_up(gv, off, 64);
        if (t >= off) gv += u;
      }
      gc[t] = gv;
      float tot = __shfl(gv, 63, 64);
      edec[t] = __expf(tot - gv);
    }
    __syncthreads();

    {
      const int r = t >> 2, q4 = t & 3;
      const size_t grow = (rowbase + row0 + r) * (size_t)CONVD;
      const unsigned short* kp = QKV + grow + 2048 + hq * 128 + q4 * 32;
      float kv[32]; float ssk = 0.f;
#pragma unroll
      for (int j = 0; j < 32; j += 4) {
        ushort4 km = *(const ushort4*)(kp + j);
        kv[j] = bf2f(km.x); kv[j + 1] = bf2f(km.y); kv[j + 2] = bf2f(km.z); kv[j + 3] = bf2f(km.w);
        ssk += kv[j]*kv[j] + kv[j+1]*kv[j+1] + kv[j+2]*kv[j+2] + kv[j+3]*kv[j+3];
      }
      ssk += __shfl_xor(ssk, 1, 64);
      ssk += __shfl_xor(ssk, 2, 64);
      const float rk = rsqrtf(ssk + 1e-6f);
#pragma unroll
      for (int j = 0; j < 32; ++j) ktT[(q4 * 32 + j) * 88 + r] = f2bf(kv[j] * rk);
      const unsigned short* wsrc = WU + (rowbase + row0 + r) * (size_t)NWP + h * 128 + q4 * 32;
#pragma unroll
      for (int u2 = 0; u2 < 4; ++u2)
        *(uint4*)&wb[r * 136 + q4 * 32 + u2 * 8] = *(const uint4*)(wsrc + u2 * 8);
      const unsigned short* asrc = ATTN + (ahead + ncb) * 4096 + r * 64 + q4 * 16;
      *(uint4*)&attnb[r * 88 + q4 * 16] = *(const uint4*)(asrc);
      *(uint4*)&attnb[r * 88 + q4 * 16 + 8] = *(const uint4*)(asrc + 8);
      const unsigned short* qsrc = QKV + (rowbase + row0 + w * 16 + rlo) * (size_t)CONVD + hq * 128 + khi * 8;
      float qv[32]; float ssq = 0.f;
#pragma unroll
      for (int ks = 0; ks < 4; ++ks) {
        ushort4 qa = *(const ushort4*)(qsrc + ks * 32);
        ushort4 qb2 = *(const ushort4*)(qsrc + ks * 32 + 4);
        qv[ks*8+0] = bf2f(qa.x); qv[ks*8+1] = bf2f(qa.y); qv[ks*8+2] = bf2f(qa.z); qv[ks*8+3] = bf2f(qa.w);
        qv[ks*8+4] = bf2f(qb2.x); qv[ks*8+5] = bf2f(qb2.y); qv[ks*8+6] = bf2f(qb2.z); qv[ks*8+7] = bf2f(qb2.w);
#pragma unroll
        for (int e = 0; e < 8; ++e) ssq += qv[ks*8+e] * qv[ks*8+e];
      }
      ssq += __shfl_xor(ssq, 16, 64);
      ssq += __shfl_xor(ssq, 32, 64);
      const float rq = rsqrtf(ssq + 1e-6f) * 0.08838834764831845f;
#pragma unroll
      for (int ks = 0; ks < 4; ++ks) {
        bf16x8 tv;
#pragma unroll
        for (int e = 0; e < 8; ++e) tv[e] = (short)f2bf(qv[ks*8+e] * rq);
        qf[ks] = tv;
      }
    }
    __syncthreads();

    f32x4v oacc;
    {
      f32x4v pacc = (f32x4v){0.f, 0.f, 0.f, 0.f};
      oacc = (f32x4v){0.f, 0.f, 0.f, 0.f};
#pragma unroll
      for (int ks = 0; ks < 4; ++ks) {
        bf16x8 aw = *(const bf16x8*)&wb[(w * 16 + rlo) * 136 + ks * 32 + khi * 8];
        bf16x8 bs = *(const bf16x8*)&stateTb[rlo * 136 + ks * 32 + khi * 8];
        pacc = __builtin_amdgcn_mfma_f32_16x16x32_bf16(aw, bs, pacc, 0, 0, 0);
        oacc = __builtin_amdgcn_mfma_f32_16x16x32_bf16(qf[ks], bs, oacc, 0, 0, 0);
      }
#pragma unroll
      for (int r2 = 0; r2 < 4; ++r2) {
        const int i = w * 16 + khi * 4 + r2;
        float uv = bf2f(WU[(rowbase + row0 + i) * (size_t)NWP + 4096 + h * 128 + vq * 16 + rlo]);
        float vn = uv - pacc[r2];
        vnTb[rlo * 88 + i] = f2bf(vn);
        vdTb[rlo * 88 + i] = f2bf(vn * edec[i]);
        oacc[r2] *= __expf(gc[i]);
      }
    }
    __syncthreads();

    {
#pragma unroll
      for (int ks = 0; ks < 2; ++ks) {
        bf16x8 aa = *(const bf16x8*)&attnb[(w * 16 + rlo) * 88 + ks * 32 + khi * 8];
        bf16x8 bv = *(const bf16x8*)&vnTb[rlo * 88 + ks * 32 + khi * 8];
        oacc = __builtin_amdgcn_mfma_f32_16x16x32_bf16(aa, bv, oacc, 0, 0, 0);
      }
      const int col = h * 128 + vq * 16 + rlo;
#pragma unroll
      for (int r2 = 0; r2 < 4; ++r2) {
        const int i = w * 16 + khi * 4 + r2;
        CORE[(rowbase + row0 + i) * (size_t)4096 + col] = f2bf(oacc[r2]);
      }
      const float egl = __expf(gc[63]);
#pragma unroll
      for (int n2 = 0; n2 < 2; ++n2) {
        const int dt = w * 2 + n2;
        f32x4v sacc = (f32x4v){0.f, 0.f, 0.f, 0.f};
#pragma unroll
        for (int ks = 0; ks < 2; ++ks) {
          bf16x8 ak = *(const bf16x8*)&ktT[(dt * 16 + rlo) * 88 + ks * 32 + khi * 8];
          bf16x8 bv2 = *(const bf16x8*)&vdTb[rlo * 88 + ks * 32 + khi * 8];
          sacc = __builtin_amdgcn_mfma_f32_16x16x32_bf16(ak, bv2, sacc, 0, 0, 0);
        }
#pragma unroll
        for (int r2 = 0; r2 < 4; ++r2) {
          const int d = dt * 16 + khi * 4 + r2;
          float ns = stateT[rlo * 136 + d] * egl + sacc[r2];
          stateT[rlo * 136 + d] = ns;
          stateTb[rlo * 136 + d] = f2bf(ns);
        }
      }
    }
    __syncthreads();
  }
}

// ---------------------------------------------------------------- gate * silu(z) + RMS-norm
__global__ __launch_bounds__(256) void gatenorm_kernel(const unsigned short* __restrict__ CORE,
                                                       const unsigned short* __restrict__ C1,
                                                       const float* __restrict__ norm_w,
                                                       unsigned short* __restrict__ NRM) {
  const int wid = blockIdx.x * 4 + (threadIdx.x >> 6);
  const int lane = threadIdx.x & 63;
  const int row = wid >> 5, h = wid & 31;
  const int c = lane * 2;
  const size_t cidx = (size_t)row * 4096 + h * 128 + c;
  const size_t zidx = (size_t)row * NWP + 8192 + h * 128 + c;
  float g0 = bf2f(CORE[cidx]), g1 = bf2f(CORE[cidx + 1]);
  float z0 = bf2f(C1[zidx]), z1 = bf2f(C1[zidx + 1]);
  g0 *= z0 / (1.f + __expf(-z0));
  g1 *= z1 / (1.f + __expf(-z1));
  float ss = g0 * g0 + g1 * g1;
#pragma unroll
  for (int m = 1; m < 64; m <<= 1) ss += __shfl_xor(ss, m, 64);
  const float rr = rsqrtf(ss * (1.f / 128.f) + 1e-6f);
  unsigned int o = ((unsigned int)f2bf(g1 * rr * norm_w[c + 1]) << 16) | (unsigned int)f2bf(g0 * rr * norm_w[c]);
  *(unsigned int*)(NRM + cidx) = o;
}

// ---------------------------------------------------------------------------
extern "C" void kernel_launch(void* const* d_in, const int* in_sizes, int n_in,
                              void* d_out, int out_size, void* d_ws, size_t ws_size,
                              hipStream_t stream) {
  const float* hs      = (const float*)d_in[0];
  const float* W_qkv   = (const float*)d_in[1];
  const float* W_z     = (const float*)d_in[2];
  const float* W_b     = (const float*)d_in[3];
  const float* W_a     = (const float*)d_in[4];
  const float* conv_w  = (const float*)d_in[5];
  const float* dt_bias = (const float*)d_in[6];
  const float* A_log   = (const float*)d_in[7];
  const float* norm_w  = (const float*)d_in[8];
  const float* W_out   = (const float*)d_in[9];
  float* out = (float*)d_out;
  char* ws = (char*)d_ws;

  const size_t OFF_HSB = 0;                                     // hs bf16; later ATTN
  const size_t OFF_WT  = OFF_HSB + (size_t)ROWS * HIDN * 2;     // WT; later CORE
  const size_t OFF_WOT = OFF_WT + (size_t)NWP * HIDN * 2;
  const size_t OFF_C1  = OFF_WOT + (size_t)HIDN * 4096 * 2;     // C1; cols [0,8192) -> w,u after conv
  const size_t OFF_QKV = OFF_C1 + (size_t)ROWS * NWP * 2;       // QKV; later NRM
  const size_t OFF_G   = OFF_QKV + (size_t)ROWS * CONVD * 2;
  const size_t OFF_B   = OFF_G + (size_t)ROWS * NUMV * 4;

  unsigned short* hsb = (unsigned short*)(ws + OFF_HSB);
  unsigned short* WT  = (unsigned short*)(ws + OFF_WT);
  unsigned short* WoT = (unsigned short*)(ws + OFF_WOT);
  unsigned short* C1  = (unsigned short*)(ws + OFF_C1);
  unsigned short* QKV = (unsigned short*)(ws + OFF_QKV);
  float* Gb = (float*)(ws + OFF_G);
  float* Bb = (float*)(ws + OFF_B);
  unsigned short* ATTNb = (unsigned short*)(ws + OFF_HSB);
  unsigned short* COREb = (unsigned short*)(ws + OFF_WT);
  unsigned short* NRMb  = (unsigned short*)(ws + OFF_QKV);

  cast_kernel<<<ROWS * HIDN / 4 / 256, 256, 0, stream>>>(hs, hsb, ROWS * HIDN / 4);
  transpose_kernel<<<dim3(8192 / 64, 2048 / 64), 256, 0, stream>>>(W_qkv, WT, 2048, 8192, HIDN, 0);
  transpose_kernel<<<dim3(4096 / 64, 2048 / 64), 256, 0, stream>>>(W_z, WT, 2048, 4096, HIDN, 8192);
  transpose_kernel<<<dim3(1, 2048 / 64), 256, 0, stream>>>(W_b, WT, 2048, 32, HIDN, 12288);
  transpose_kernel<<<dim3(1, 2048 / 64), 256, 0, stream>>>(W_a, WT, 2048, 32, HIDN, 12320);
  hipMemsetAsync(ws + OFF_WT + (size_t)12352 * HIDN * 2, 0, (size_t)192 * HIDN * 2, stream);
  transpose_kernel<<<dim3(2048 / 64, 4096 / 64), 256, 0, stream>>>(W_out, WoT, 4096, 2048, 4096, 0);

  void (*g1p)(const unsigned short*, const unsigned short*, void*, int, int, int) = gemm_s_kernel<256, 256, 1>;
  void (*g0p)(const unsigned short*, const unsigned short*, void*, int, int, int) = gemm_s_kernel<128, 256, 0>;
  hipFuncSetAttribute((const void*)g1p, hipFuncAttributeMaxDynamicSharedMemorySize, (256 + 256) * 128 * 2);
  hipFuncSetAttribute((const void*)g0p, hipFuncAttributeMaxDynamicSharedMemorySize, (128 + 256) * 128 * 2);

  gemm_s_kernel<256, 256, 1><<<dim3(NWP / 256, ROWS / 256), 512, (256 + 256) * 128 * 2, stream>>>(
      hsb, WT, C1, ROWS, NWP, HIDN);
  conv_silu_kernel<<<ROWS * (CONVD / 4) / 256, 256, 0, stream>>>(C1, conv_w, QKV);
  gbeta_kernel<<<ROWS * NUMV / 256, 256, 0, stream>>>(C1, dt_bias, A_log, Gb, Bb);

  hipFuncSetAttribute((const void*)intra_kernel, hipFuncAttributeMaxDynamicSharedMemorySize,
                      INTRA_SMEM);
  intra_kernel<<<2048, 256, INTRA_SMEM, stream>>>(QKV, Gb, Bb, C1, ATTNb);

  hipFuncSetAttribute((const void*)seq_kernel, hipFuncAttributeMaxDynamicSharedMemorySize,
                      SEQ_SMEM);
  seq_kernel<<<512, 256, SEQ_SMEM, stream>>>(QKV, Gb, C1, ATTNb, COREb);

  gatenorm_kernel<<<ROWS * NUMV / 4, 256, 0, stream>>>(COREb, C1, norm_w, NRMb);
  gemm_s_kernel<128, 256, 0><<<dim3(2048 / 256, ROWS / 128), 512, (128 + 256) * 128 * 2, stream>>>(
      NRMb, WoT, out, ROWS, 2048, 4096);
}